// Round 12
// baseline (386.622 us; speedup 1.0000x reference)
//
#include <hip/hip_runtime.h>
#include <hip/hip_bf16.h>
#include <stdint.h>

typedef __attribute__((ext_vector_type(8))) __bf16 bf16x8;
typedef __attribute__((ext_vector_type(4))) __bf16 bf16x4;
typedef __attribute__((ext_vector_type(4))) float f32x4;

#define DEV __device__ __forceinline__

static constexpr int S = 2048, F = 2048, H = 16, D = 128;
static constexpr int KDIM = F;            // 2048
static constexpr float QSCALE = 0.08838834764831845f;  // 1/sqrt(128)

DEV void gll16(const void* g, void* l) {
  __builtin_amdgcn_global_load_lds(
      (const __attribute__((address_space(1))) void*)g,
      (__attribute__((address_space(3))) void*)l, 16, 0, 0);
}

DEV f32x4 mfma16(bf16x8 a, bf16x8 b, f32x4 c) {
  return __builtin_amdgcn_mfma_f32_16x16x32_bf16(a, b, c, 0, 0, 0);
}

extern __shared__ char smem[];

// ---------------- elementwise f32 -> bf16 ----------------
__global__ void k_cvt(const float* __restrict__ in, __bf16* __restrict__ out) {
  int i = blockIdx.x * 256 + threadIdx.x;
  float4 v = reinterpret_cast<const float4*>(in)[i];
  bf16x4 o = {(__bf16)v.x, (__bf16)v.y, (__bf16)v.z, (__bf16)v.w};
  reinterpret_cast<bf16x4*>(out)[i] = o;
}

// ---------------- transpose f32 [rows][cols] -> bf16 [cols][rows] ----------------
__global__ void k_transpose(const float* __restrict__ in, __bf16* __restrict__ out,
                            int rows, int cols) {
  __shared__ float t[64][65];
  const int c0 = blockIdx.x * 64, r0 = blockIdx.y * 64;
  const int tx = threadIdx.x & 63, ty = threadIdx.x >> 6;
#pragma unroll
  for (int i = 0; i < 64; i += 4)
    t[ty + i][tx] = in[(size_t)(r0 + ty + i) * cols + c0 + tx];
  __syncthreads();
#pragma unroll
  for (int i = 0; i < 64; i += 4)
    out[(size_t)(c0 + ty + i) * rows + r0 + tx] = (__bf16)t[tx][ty + i];
}

// ================= pipelined GEMM: BMxBN tile, BK=64, dbuf + counted vmcnt =========
// C[M,N] = A[M,K]*Bt[N,K]^T + bias. 8 waves (2M x 4N), wave tile (BM/2)x(BN/4).
// LDS 2 bufs x (BM+BN)*128 B, chunk-XOR swizzled (source pre-swizzled, rule 21).
// R11: QKV tile 256x384 — wave tile 128x96, intensity MwNw/(Mw+Nw)=54.9 vs 38.4
// (r6/r9's 64x96 sat AT the LDS-BW wall: LDS clk ~= 96% of MFMA clk; 128x96 -> 65%).
// r4/r5 tried this tile but spilled (launch_bounds(512,2) capped VGPR at 128);
// (512,1) + unified AGPR file fits acc[8][6]=192 AGPR + ~130 VGPR at 2 waves/SIMD.
// Reads grouped R0..R3, MFMA quadrants M0..M3 (no forced lgkm drains mid-tile);
// per tile: 1 lgkm(0), 2 barriers, 1 counted vmcnt(NL). Stage(t+2) into cur after
// all reads of cur retired (WAR via barrier). Grid 16x16=256 = 1/CU, tail-free.
// EPI 0: route Q(scaled)/K/V^T bf16.  EPI 1: f32 +bias.
template <int BM, int BN, int NBXL, int EPI>
__global__ __launch_bounds__(512, 1) void k_gp(
    const __bf16* __restrict__ A, const __bf16* __restrict__ Bt,
    const float* __restrict__ bias,
    __bf16* __restrict__ qo, __bf16* __restrict__ ko, __bf16* __restrict__ vo,
    float* __restrict__ fo) {
  constexpr int MF = BM / 32;        // A frags per ks
  constexpr int NF = BN / 64;        // B frags per ks
  constexpr int NH = NF / 2;         // B half split
  constexpr int NLA = BM / 64;       // A stage loads (8 KB each)
  constexpr int NLB = BN / 64;       // B stage loads
  constexpr int NL = NLA + NLB;
  constexpr int AOFF = BM * 128;     // bytes: B region offset in a buffer
  constexpr int BUFSZ = (BM + BN) * 128;
  constexpr int NT = KDIM / 64;      // 32

  const int tid = threadIdx.x;
  const int lane = tid & 63, wid = tid >> 6;
  const int wm = wid >> 2, wn = wid & 3;
  const int ln = lane & 15, lm = lane >> 4;

  // T1: XCD-aware bijective swizzle (gridDim.x % 8 == 0)
  const int q8 = gridDim.x >> 3;
  const int lin = (blockIdx.x & 7) * q8 + (blockIdx.x >> 3);
  const int by = lin >> NBXL, bx = lin & ((1 << NBXL) - 1);
  const int mBase = by * BM, nBase = bx * BN;

  // stage source: chunk c = j*512+tid; row r = j*64 + (tid>>3); col-chunk cc = tid&7.
  const int r0 = tid >> 3, cc = tid & 7;
  const int src0 = r0 * KDIM + ((cc ^ (r0 & 7)) << 3);
  const __bf16* Ab = A + (size_t)mBase * KDIM + src0;
  const __bf16* Bb = Bt + (size_t)nBase * KDIM + src0;
  const int dstBase = wid * 1024;  // + lane*16 by HW

  auto stage = [&](char* buf, int t) {
    const __bf16* As = Ab + t * 64;
    const __bf16* Bs = Bb + t * 64;
#pragma unroll
    for (int j = 0; j < NLA; ++j)
      gll16(As + (size_t)j * 64 * KDIM, buf + j * 8192 + dstBase);
#pragma unroll
    for (int j = 0; j < NLB; ++j)
      gll16(Bs + (size_t)j * 64 * KDIM, buf + AOFF + j * 8192 + dstBase);
  };
  auto wait_nl = [&]() {  // vmcnt(NL): t+1's loads (issued a full tile ago) landed
    if constexpr (NL == 4)       asm volatile("s_waitcnt vmcnt(4)" ::: "memory");
    else if constexpr (NL == 6)  asm volatile("s_waitcnt vmcnt(6)" ::: "memory");
    else if constexpr (NL == 8)  asm volatile("s_waitcnt vmcnt(8)" ::: "memory");
    else                         asm volatile("s_waitcnt vmcnt(10)" ::: "memory");
  };

  // ds_read byte offsets (slot = logical chunk ^ (row&7); row&7 == ln&7)
  int rA[2], rB[2];
#pragma unroll
  for (int ks = 0; ks < 2; ++ks) {
    const int slot = (ks * 4 + lm) ^ (ln & 7);
    rA[ks] = (wm * (BM / 2) + ln) * 128 + slot * 16;
    rB[ks] = AOFF + (wn * (BN / 4) + ln) * 128 + slot * 16;
  }

  f32x4 acc[MF][NF] = {};

  // prologue: stage tiles 0 and 1
  stage(smem, 0);
  stage(smem + BUFSZ, 1);
  wait_nl();
  __builtin_amdgcn_s_barrier();
  __builtin_amdgcn_sched_barrier(0);

  for (int t = 0; t < NT; ++t) {
    char* cb = smem + (t & 1) * BUFSZ;
    bf16x8 a0[MF], a1[MF], b0[NF], b1[NF];

    // R0: A(ks0) + B(ks0, lower half)
#pragma unroll
    for (int mi = 0; mi < MF; ++mi)
      a0[mi] = *reinterpret_cast<const bf16x8*>(cb + rA[0] + mi * 2048);
#pragma unroll
    for (int ni = 0; ni < NH; ++ni)
      b0[ni] = *reinterpret_cast<const bf16x8*>(cb + rB[0] + ni * 2048);
    // R1: B(ks0, upper half)
#pragma unroll
    for (int ni = NH; ni < NF; ++ni)
      b0[ni] = *reinterpret_cast<const bf16x8*>(cb + rB[0] + ni * 2048);

    // M0: a0 x b0[0..NH)
    __builtin_amdgcn_s_setprio(1);
#pragma unroll
    for (int ni = 0; ni < NH; ++ni)
#pragma unroll
      for (int mi = 0; mi < MF; ++mi)
        acc[mi][ni] = mfma16(a0[mi], b0[ni], acc[mi][ni]);
    __builtin_amdgcn_s_setprio(0);

    // R2: A(ks1) + B(ks1, upper half)
#pragma unroll
    for (int mi = 0; mi < MF; ++mi)
      a1[mi] = *reinterpret_cast<const bf16x8*>(cb + rA[1] + mi * 2048);
#pragma unroll
    for (int ni = NH; ni < NF; ++ni)
      b1[ni] = *reinterpret_cast<const bf16x8*>(cb + rB[1] + ni * 2048);

    // M1: a0 x b0[NH..NF)
    __builtin_amdgcn_s_setprio(1);
#pragma unroll
    for (int ni = NH; ni < NF; ++ni)
#pragma unroll
      for (int mi = 0; mi < MF; ++mi)
        acc[mi][ni] = mfma16(a0[mi], b0[ni], acc[mi][ni]);
    __builtin_amdgcn_s_setprio(0);

    // R3: B(ks1, lower half)
#pragma unroll
    for (int ni = 0; ni < NH; ++ni)
      b1[ni] = *reinterpret_cast<const bf16x8*>(cb + rB[1] + ni * 2048);

    // M2: a1 x b1[NH..NF)
    __builtin_amdgcn_s_setprio(1);
#pragma unroll
    for (int ni = NH; ni < NF; ++ni)
#pragma unroll
      for (int mi = 0; mi < MF; ++mi)
        acc[mi][ni] = mfma16(a1[mi], b1[ni], acc[mi][ni]);
    __builtin_amdgcn_s_setprio(0);

    // all reads of cb issued; drain (R3 is ~24 MFMA old, cheap) then rendezvous
    asm volatile("s_waitcnt lgkmcnt(0)" ::: "memory");
    __builtin_amdgcn_s_barrier();           // all waves done reading cb
    __builtin_amdgcn_sched_barrier(0);      // keep stage below the barrier (WAR)
    if (t + 2 < NT) stage(cb, t + 2);

    // M3: a1 x b1[0..NH)
    __builtin_amdgcn_s_setprio(1);
#pragma unroll
    for (int ni = 0; ni < NH; ++ni)
#pragma unroll
      for (int mi = 0; mi < MF; ++mi)
        acc[mi][ni] = mfma16(a1[mi], b1[ni], acc[mi][ni]);
    __builtin_amdgcn_s_setprio(0);

    // boundary: t+1 landed (counted), rendezvous
    if (t + 2 < NT) {
      wait_nl();
    } else if (t + 1 < NT) {
      asm volatile("s_waitcnt vmcnt(0)" ::: "memory");
    }
    if (t + 1 < NT) {
      __builtin_amdgcn_s_barrier();
      __builtin_amdgcn_sched_barrier(0);
    }
  }

  if (EPI == 0) {
#pragma unroll
    for (int mi = 0; mi < MF; ++mi) {
      const int grow = mBase + wm * (BM / 2) + mi * 16 + lm * 4;
      const int b = grow >> 11, s0 = grow & 2047;
#pragma unroll
      for (int ni = 0; ni < NF; ++ni) {
        const int gcol = nBase + wn * (BN / 4) + ni * 16 + ln;
        const float bv = bias[gcol];
        const int sec = gcol >> 11;  // uniform across the 16-lane col group
        const int h = (gcol >> 7) & 15, d = gcol & 127;
        const int bh = b * H + h;
        if (sec == 0) {
#pragma unroll
          for (int r = 0; r < 4; ++r)
            qo[((size_t)bh * S + s0 + r) * D + d] = (__bf16)((acc[mi][ni][r] + bv) * QSCALE);
        } else if (sec == 1) {
#pragma unroll
          for (int r = 0; r < 4; ++r)
            ko[((size_t)bh * S + s0 + r) * D + d] = (__bf16)(acc[mi][ni][r] + bv);
        } else {
          bf16x4 pv = {(__bf16)(acc[mi][ni][0] + bv), (__bf16)(acc[mi][ni][1] + bv),
                       (__bf16)(acc[mi][ni][2] + bv), (__bf16)(acc[mi][ni][3] + bv)};
          *reinterpret_cast<bf16x4*>(vo + ((size_t)bh * D + d) * S + s0) = pv;  // V^T
        }
      }
    }
  } else {
#pragma unroll
    for (int mi = 0; mi < MF; ++mi) {
      const int grow = mBase + wm * (BM / 2) + mi * 16 + lm * 4;
#pragma unroll
      for (int ni = 0; ni < NF; ++ni) {
        const int gcol = nBase + wn * (BN / 4) + ni * 16 + ln;
        const float bv = bias[gcol];
#pragma unroll
        for (int r = 0; r < 4; ++r)
          fo[(size_t)(grow + r) * F + gcol] = acc[mi][ni][r] + bv;
      }
    }
  }
}

// ---------------- flash attention: 4 waves x 32 q-rows, KVBLK=64 ----------------
// 2 blocks/CU (80 KiB LDS each). Complementary-qt pairing + per-bh XCD affinity.
__global__ __launch_bounds__(256, 2) void k_attn(
    const __bf16* __restrict__ qb, const __bf16* __restrict__ kb,
    const __bf16* __restrict__ vtb, __bf16* __restrict__ zb) {
  const int lane = threadIdx.x & 63, w = threadIdx.x >> 6;
  const int lm = lane >> 4, ln = lane & 15;
  const int blk = blockIdx.x;
  const int u = blk & 255, v = blk >> 8;
  const int qt = v ? (u >> 4) : 15 - (u >> 4);
  const int bh = ((u & 15) << 1) | v;
  const int qw = qt * 128 + w * 32;

  const __bf16* qp = qb + (size_t)bh * S * D;
  const __bf16* kp = kb + (size_t)bh * S * D;
  const __bf16* vp = vtb + (size_t)bh * D * S;
  char* pw = smem + 65536 + w * 4096;

  int ksrc[4], kdst[4], vsrc[4], vdst[4];
#pragma unroll
  for (int j = 0; j < 4; ++j) {
    int c = (w * 4 + j) * 64 + lane;
    int kr = c >> 4, kps = (c & 15) ^ (kr & 7);
    ksrc[j] = kr * D + kps * 8;
    kdst[j] = (w * 4 + j) * 1024;
    int vr = c >> 3, vps = (c & 7) ^ (vr & 7);
    vsrc[j] = vr * S + vps * 8;
    vdst[j] = 16384 + (w * 4 + j) * 1024;
  }

  bf16x8 qf[2][4];
#pragma unroll
  for (int mi = 0; mi < 2; ++mi)
#pragma unroll
    for (int kf = 0; kf < 4; ++kf)
      qf[mi][kf] = *reinterpret_cast<const bf16x8*>(qp + (qw + mi * 16 + ln) * D + kf * 32 + lm * 8);

  f32x4 Oa[2][8] = {};
  float mrow[2][4], lrow[2][4];
#pragma unroll
  for (int mi = 0; mi < 2; ++mi)
#pragma unroll
    for (int r = 0; r < 4; ++r) { mrow[mi][r] = -3.0e38f; lrow[mi][r] = 0.0f; }

  const int ktEnd = 2 * qt + 1;

#pragma unroll
  for (int j = 0; j < 4; ++j) gll16(kp + ksrc[j], smem + kdst[j]);
#pragma unroll
  for (int j = 0; j < 4; ++j) gll16(vp + vsrc[j], smem + vdst[j]);
  asm volatile("s_waitcnt vmcnt(0)" ::: "memory");
  __builtin_amdgcn_s_barrier();
  __builtin_amdgcn_sched_barrier(0);

  for (int kt = 0; kt <= ktEnd; ++kt) {
    const int kv0 = kt * 64;
    const int cur = kt & 1;

    if (kt < ktEnd) {
      const int nk = (kt + 1) * 64;
      char* nbuf = smem + (cur ^ 1) * 32768;
#pragma unroll
      for (int j = 0; j < 4; ++j) gll16(kp + (size_t)nk * D + ksrc[j], nbuf + kdst[j]);
#pragma unroll
      for (int j = 0; j < 4; ++j) gll16(vp + nk + vsrc[j], nbuf + vdst[j]);
    }

    if (kv0 <= qw + 31) {
      const char* Kb = smem + cur * 32768;
      const char* Vb = Kb + 16384;
      const bool diag = (kv0 + 63 > qw);

      f32x4 sacc[2][4] = {};
#pragma unroll
      for (int kf = 0; kf < 4; ++kf) {
        bf16x8 kfr[4];
#pragma unroll
        for (int ni = 0; ni < 4; ++ni) {
          int row = ni * 16 + ln;
          int ch = (kf * 4 + lm) ^ (row & 7);
          kfr[ni] = *reinterpret_cast<const bf16x8*>(Kb + row * 256 + ch * 16);
        }
        __builtin_amdgcn_s_setprio(1);
#pragma unroll
        for (int mi = 0; mi < 2; ++mi)
#pragma unroll
          for (int ni = 0; ni < 4; ++ni)
            sacc[mi][ni] = mfma16(qf[mi][kf], kfr[ni], sacc[mi][ni]);
        __builtin_amdgcn_s_setprio(0);
      }

      if (diag) {
#pragma unroll
        for (int ni = 0; ni < 4; ++ni) {
          int c = kv0 + ni * 16 + ln;
#pragma unroll
          for (int mi = 0; mi < 2; ++mi) {
            int q0r = qw + mi * 16 + lm * 4;
#pragma unroll
            for (int r = 0; r < 4; ++r)
              if (c > q0r + r) sacc[mi][ni][r] = -1e30f;
          }
        }
      }

#pragma unroll
      for (int mi = 0; mi < 2; ++mi)
#pragma unroll
        for (int r = 0; r < 4; ++r) {
          float mx = fmaxf(fmaxf(sacc[mi][0][r], sacc[mi][1][r]),
                           fmaxf(sacc[mi][2][r], sacc[mi][3][r]));
          mx = fmaxf(mx, __shfl_xor(mx, 1, 64));
          mx = fmaxf(mx, __shfl_xor(mx, 2, 64));
          mx = fmaxf(mx, __shfl_xor(mx, 4, 64));
          mx = fmaxf(mx, __shfl_xor(mx, 8, 64));
          float mnew = fmaxf(mrow[mi][r], mx);
          float corr = __expf(mrow[mi][r] - mnew);
          mrow[mi][r] = mnew;
          float rs = 0.0f;
#pragma unroll
          for (int ni = 0; ni < 4; ++ni) {
            float p = __expf(sacc[mi][ni][r] - mnew);
            sacc[mi][ni][r] = p;
            rs += p;
          }
          lrow[mi][r] = lrow[mi][r] * corr + rs;
#pragma unroll
          for (int ni = 0; ni < 8; ++ni) Oa[mi][ni][r] *= corr;
        }

#pragma unroll
      for (int mi = 0; mi < 2; ++mi)
#pragma unroll
        for (int ni = 0; ni < 4; ++ni)
#pragma unroll
          for (int r = 0; r < 4; ++r) {
            int row = mi * 16 + lm * 4 + r;
            int bo = (row * 128 + (ni * 16 + ln) * 2) ^ ((row & 7) << 4);
            *reinterpret_cast<__bf16*>(pw + bo) = (__bf16)sacc[mi][ni][r];
          }

      asm volatile("s_waitcnt lgkmcnt(0)" ::: "memory");
      __builtin_amdgcn_sched_barrier(0);

#pragma unroll
      for (int kf = 0; kf < 2; ++kf) {
        bf16x8 pfr[2], vfr[8];
#pragma unroll
        for (int mi = 0; mi < 2; ++mi) {
          int row = mi * 16 + ln;
          int ch = (kf * 4 + lm) ^ (row & 7);
          pfr[mi] = *reinterpret_cast<const bf16x8*>(pw + row * 128 + ch * 16);
        }
#pragma unroll
        for (int ni = 0; ni < 8; ++ni) {
          int row = ni * 16 + ln;
          int ch = (kf * 4 + lm) ^ (row & 7);
          vfr[ni] = *reinterpret_cast<const bf16x8*>(Vb + row * 128 + ch * 16);
        }
        __builtin_amdgcn_s_setprio(1);
#pragma unroll
        for (int mi = 0; mi < 2; ++mi)
#pragma unroll
          for (int ni = 0; ni < 8; ++ni)
            Oa[mi][ni] = mfma16(pfr[mi], vfr[ni], Oa[mi][ni]);
        __builtin_amdgcn_s_setprio(0);
      }
    }

    asm volatile("s_waitcnt vmcnt(0) lgkmcnt(0)" ::: "memory");
    __builtin_amdgcn_s_barrier();
    __builtin_amdgcn_sched_barrier(0);
  }

#pragma unroll
  for (int mi = 0; mi < 2; ++mi)
#pragma unroll
    for (int r = 0; r < 4; ++r) {
      float ls = lrow[mi][r];
      ls += __shfl_xor(ls, 1, 64);
      ls += __shfl_xor(ls, 2, 64);
      ls += __shfl_xor(ls, 4, 64);
      ls += __shfl_xor(ls, 8, 64);
      lrow[mi][r] = 1.0f / ls;
    }
  const int b = bh >> 4, h = bh & 15;
#pragma unroll
  for (int mi = 0; mi < 2; ++mi)
#pragma unroll
    for (int ni = 0; ni < 8; ++ni) {
      int d = ni * 16 + ln;
#pragma unroll
      for (int r = 0; r < 4; ++r) {
        int qrow = qw + mi * 16 + lm * 4 + r;
        zb[(size_t)(b * S + qrow) * F + h * D + d] = (__bf16)(Oa[mi][ni][r] * lrow[mi][r]);
      }
    }
}

// ---------------- launch ----------------
extern "C" void kernel_launch(void* const* d_in, const int* in_sizes, int n_in,
                              void* d_out, int out_size, void* d_ws, size_t ws_size,
                              hipStream_t stream) {
  const float* x = (const float*)d_in[0];
  // d_in[1] = causal mask (implemented analytically)
  const float* w_attn = (const float*)d_in[2];
  const float* b_attn = (const float*)d_in[3];
  const float* w_proj = (const float*)d_in[4];
  const float* b_proj = (const float*)d_in[5];
  float* out = (float*)d_out;

  char* ws = (char*)d_ws;
  __bf16* xb    = (__bf16*)(ws + 0);          // 16 MB  [4096][2048] (reused as zb)
  __bf16* wqkv  = (__bf16*)(ws + 16777216);   // 24 MB  [6144][2048] (W^T)
  __bf16* wpro  = (__bf16*)(ws + 41943040);   //  8 MB  [2048][2048] (W^T)
  __bf16* qb    = (__bf16*)(ws + 50331648);   // 16 MB  [bh][s][d]
  __bf16* kb    = (__bf16*)(ws + 67108864);   // 16 MB  [bh][s][d]
  __bf16* vtb   = (__bf16*)(ws + 83886080);   // 16 MB  [bh][d][s]
  __bf16* zb    = xb;  // x fully consumed by QKV GEMM before attention writes z

  (void)hipFuncSetAttribute((const void*)k_gp<256, 384, 4, 0>,
                            hipFuncAttributeMaxDynamicSharedMemorySize, 163840);
  (void)hipFuncSetAttribute((const void*)k_gp<128, 256, 3, 1>,
                            hipFuncAttributeMaxDynamicSharedMemorySize, 98304);
  (void)hipFuncSetAttribute((const void*)k_attn,
                            hipFuncAttributeMaxDynamicSharedMemorySize, 81920);

  k_cvt<<<8192, 256, 0, stream>>>(x, xb);
  k_transpose<<<dim3(96, 32), 256, 0, stream>>>(w_attn, wqkv, 2048, 6144);
  k_transpose<<<dim3(32, 32), 256, 0, stream>>>(w_proj, wpro, 2048, 2048);
  // QKV: M=4096 (16 x 256), N=6144 (16 x 384) -> 256 blocks = 1/CU exact, tail-free
  k_gp<256, 384, 4, 0><<<256, 512, 163840, stream>>>(xb, wqkv, b_attn, qb, kb, vtb, nullptr);
  // attention: 512 blocks (complementary-qt balance + XCD affinity inside)
  k_attn<<<512, 256, 81920, stream>>>(qb, kb, vtb, zb);
  // out-proj: M=4096 (32 x 128), N=2048 (8 x 256) -> 256 blocks = 1/CU exact
  k_gp<128, 256, 3, 1><<<256, 512, 98304, stream>>>(zb, wpro, b_proj, nullptr, nullptr, nullptr, out);
}

// Round 13
// 294.461 us; speedup vs baseline: 1.3130x; 1.3130x over previous
//
#include <hip/hip_runtime.h>
#include <hip/hip_bf16.h>
#include <stdint.h>

typedef __attribute__((ext_vector_type(8))) __bf16 bf16x8;
typedef __attribute__((ext_vector_type(4))) __bf16 bf16x4;
typedef __attribute__((ext_vector_type(4))) float f32x4;

#define DEV __device__ __forceinline__

static constexpr int S = 2048, F = 2048, H = 16, D = 128;
static constexpr int KDIM = F;            // 2048
static constexpr float QSCALE = 0.08838834764831845f;  // 1/sqrt(128)

DEV void gll16(const void* g, void* l) {
  __builtin_amdgcn_global_load_lds(
      (const __attribute__((address_space(1))) void*)g,
      (__attribute__((address_space(3))) void*)l, 16, 0, 0);
}

DEV f32x4 mfma16(bf16x8 a, bf16x8 b, f32x4 c) {
  return __builtin_amdgcn_mfma_f32_16x16x32_bf16(a, b, c, 0, 0, 0);
}

extern __shared__ char smem[];

// ---------------- elementwise f32 -> bf16 ----------------
__global__ void k_cvt(const float* __restrict__ in, __bf16* __restrict__ out) {
  int i = blockIdx.x * 256 + threadIdx.x;
  float4 v = reinterpret_cast<const float4*>(in)[i];
  bf16x4 o = {(__bf16)v.x, (__bf16)v.y, (__bf16)v.z, (__bf16)v.w};
  reinterpret_cast<bf16x4*>(out)[i] = o;
}

// ---------------- transpose f32 [rows][cols] -> bf16 [cols][rows] ----------------
__global__ void k_transpose(const float* __restrict__ in, __bf16* __restrict__ out,
                            int rows, int cols) {
  __shared__ float t[64][65];
  const int c0 = blockIdx.x * 64, r0 = blockIdx.y * 64;
  const int tx = threadIdx.x & 63, ty = threadIdx.x >> 6;
#pragma unroll
  for (int i = 0; i < 64; i += 4)
    t[ty + i][tx] = in[(size_t)(r0 + ty + i) * cols + c0 + tx];
  __syncthreads();
#pragma unroll
  for (int i = 0; i < 64; i += 4)
    out[(size_t)(c0 + ty + i) * rows + r0 + tx] = (__bf16)t[tx][ty + i];
}

// ================= QKV: 4-wave fat-tile GEMM, 256x192, BK=64 =================
// R13 theory: per-CU LDS-read traffic = sum_waves(Mw+Nw)/(BM*BN) per FLOP.
// 8-wave configs cap at wave tiles ~64x96 (256-reg/wave limit with 8 resident
// waves; r12's acc=192 @ 8 waves spilled catastrophically) -> LDS ~= 98-150% of
// MFMA time -> the 37% MfmaUtil plateau. FIX: 4 waves (2x2) of 128x96 each at
// 1 block/CU -> 1 wave/SIMD -> 512-reg budget (no spill to ~450, m08):
// acc[8][6]=192 + frags 112 + addr ~= 340 regs OK; LDS traffic 109% of MFMA
// (vs 150% same-tile 8-wave). Grid 16x32 = 512 = 2 tail-free rounds @ 1/CU.
// Schedule = r9's grouped reads R0..R3 / MFMA quadrants M0..M3, counted vmcnt.
template <int EPI>
__global__ __launch_bounds__(256, 1) void k_qkv4(
    const __bf16* __restrict__ A, const __bf16* __restrict__ Bt,
    const float* __restrict__ bias,
    __bf16* __restrict__ qo, __bf16* __restrict__ ko, __bf16* __restrict__ vo) {
  constexpr int BM = 256, BN = 192;
  constexpr int MF = 8;              // A frags per ks (128/16)
  constexpr int NF = 6;              // B frags per ks (96/16)
  constexpr int NH = 3;
  constexpr int NLA = 8;             // A stage issues (32 rows each)
  constexpr int NLB = 6;             // B stage issues
  constexpr int AOFF = BM * 128;     // 32768
  constexpr int BUFSZ = (BM + BN) * 128;  // 57344
  constexpr int NT = KDIM / 64;      // 32

  const int tid = threadIdx.x;
  const int lane = tid & 63, wid = tid >> 6;     // 4 waves
  const int wm = wid >> 1, wn = wid & 1;         // 2x2
  const int ln = lane & 15, lm = lane >> 4;

  // T1: XCD swizzle (512 blocks, 64 consecutive lin per XCD)
  const int lin = (blockIdx.x & 7) * 64 + (blockIdx.x >> 3);
  const int by = lin >> 5, bx = lin & 31;
  const int mBase = by * BM, nBase = bx * BN;

  // stage source: chunk c = j*256+tid; row r = j*32 + (tid>>3); cc = tid&7.
  // swizzle invariant across j (j*32 % 8 == 0).
  const int r0 = tid >> 3, cc = tid & 7;
  const int src0 = r0 * KDIM + ((cc ^ (r0 & 7)) << 3);
  const __bf16* Ab = A + (size_t)mBase * KDIM + src0;
  const __bf16* Bb = Bt + (size_t)nBase * KDIM + src0;
  const int dstBase = wid * 1024;  // + lane*16 by HW (256 thr cover 4096 B/issue)

  auto stage = [&](char* buf, int t) {
    const __bf16* As = Ab + t * 64;
    const __bf16* Bs = Bb + t * 64;
#pragma unroll
    for (int j = 0; j < NLA; ++j)
      gll16(As + (size_t)j * 32 * KDIM, buf + j * 4096 + dstBase);
#pragma unroll
    for (int j = 0; j < NLB; ++j)
      gll16(Bs + (size_t)j * 32 * KDIM, buf + AOFF + j * 4096 + dstBase);
  };

  // ds_read byte offsets (slot = logical chunk ^ (row&7); row&7 == ln&7)
  int rA[2], rB[2];
#pragma unroll
  for (int ks = 0; ks < 2; ++ks) {
    const int slot = (ks * 4 + lm) ^ (ln & 7);
    rA[ks] = (wm * 128 + ln) * 128 + slot * 16;
    rB[ks] = AOFF + (wn * 96 + ln) * 128 + slot * 16;
  }

  f32x4 acc[MF][NF] = {};

  // prologue: stage tiles 0 and 1 (14 loads each)
  stage(smem, 0);
  stage(smem + BUFSZ, 1);
  asm volatile("s_waitcnt vmcnt(14)" ::: "memory");
  __builtin_amdgcn_s_barrier();
  __builtin_amdgcn_sched_barrier(0);

  for (int t = 0; t < NT; ++t) {
    char* cb = smem + (t & 1) * BUFSZ;
    bf16x8 a0[MF], a1[MF], b0[NF], b1[NF];

    // R0: A(ks0) + B(ks0, lower half)
#pragma unroll
    for (int mi = 0; mi < MF; ++mi)
      a0[mi] = *reinterpret_cast<const bf16x8*>(cb + rA[0] + mi * 2048);
#pragma unroll
    for (int ni = 0; ni < NH; ++ni)
      b0[ni] = *reinterpret_cast<const bf16x8*>(cb + rB[0] + ni * 2048);
    // R1: B(ks0, upper half)
#pragma unroll
    for (int ni = NH; ni < NF; ++ni)
      b0[ni] = *reinterpret_cast<const bf16x8*>(cb + rB[0] + ni * 2048);

    // M0: a0 x b0[0..NH)
    __builtin_amdgcn_s_setprio(1);
#pragma unroll
    for (int ni = 0; ni < NH; ++ni)
#pragma unroll
      for (int mi = 0; mi < MF; ++mi)
        acc[mi][ni] = mfma16(a0[mi], b0[ni], acc[mi][ni]);
    __builtin_amdgcn_s_setprio(0);

    // R2: A(ks1) + B(ks1, upper half)
#pragma unroll
    for (int mi = 0; mi < MF; ++mi)
      a1[mi] = *reinterpret_cast<const bf16x8*>(cb + rA[1] + mi * 2048);
#pragma unroll
    for (int ni = NH; ni < NF; ++ni)
      b1[ni] = *reinterpret_cast<const bf16x8*>(cb + rB[1] + ni * 2048);

    // M1: a0 x b0[NH..NF)
    __builtin_amdgcn_s_setprio(1);
#pragma unroll
    for (int ni = NH; ni < NF; ++ni)
#pragma unroll
      for (int mi = 0; mi < MF; ++mi)
        acc[mi][ni] = mfma16(a0[mi], b0[ni], acc[mi][ni]);
    __builtin_amdgcn_s_setprio(0);

    // R3: B(ks1, lower half)
#pragma unroll
    for (int ni = 0; ni < NH; ++ni)
      b1[ni] = *reinterpret_cast<const bf16x8*>(cb + rB[1] + ni * 2048);

    // M2: a1 x b1[NH..NF)
    __builtin_amdgcn_s_setprio(1);
#pragma unroll
    for (int ni = NH; ni < NF; ++ni)
#pragma unroll
      for (int mi = 0; mi < MF; ++mi)
        acc[mi][ni] = mfma16(a1[mi], b1[ni], acc[mi][ni]);
    __builtin_amdgcn_s_setprio(0);

    // all reads of cb issued; drain (cheap: R3 is ~24 MFMA old), rendezvous
    asm volatile("s_waitcnt lgkmcnt(0)" ::: "memory");
    __builtin_amdgcn_s_barrier();           // all waves done reading cb
    __builtin_amdgcn_sched_barrier(0);      // keep stage below the barrier (WAR)
    if (t + 2 < NT) stage(cb, t + 2);

    // M3: a1 x b1[0..NH)
    __builtin_amdgcn_s_setprio(1);
#pragma unroll
    for (int ni = 0; ni < NH; ++ni)
#pragma unroll
      for (int mi = 0; mi < MF; ++mi)
        acc[mi][ni] = mfma16(a1[mi], b1[ni], acc[mi][ni]);
    __builtin_amdgcn_s_setprio(0);

    // boundary: t+1 landed (counted), rendezvous
    if (t + 2 < NT) {
      asm volatile("s_waitcnt vmcnt(14)" ::: "memory");
    } else if (t + 1 < NT) {
      asm volatile("s_waitcnt vmcnt(0)" ::: "memory");
    }
    if (t + 1 < NT) {
      __builtin_amdgcn_s_barrier();
      __builtin_amdgcn_sched_barrier(0);
    }
  }

  // epilogue: route Q (scaled), K, V^T. 192-wide tile may straddle a section
  // boundary -> sec computed per 16-col group (gcol uniform across the group).
#pragma unroll
  for (int mi = 0; mi < MF; ++mi) {
    const int grow = mBase + wm * 128 + mi * 16 + lm * 4;
    const int b = grow >> 11, s0 = grow & 2047;
#pragma unroll
    for (int ni = 0; ni < NF; ++ni) {
      const int gcol = nBase + wn * 96 + ni * 16 + ln;
      const float bv = bias[gcol];
      const int sec = gcol >> 11;
      const int h = (gcol >> 7) & 15, d = gcol & 127;
      const int bh = b * H + h;
      if (sec == 0) {
#pragma unroll
        for (int r = 0; r < 4; ++r)
          qo[((size_t)bh * S + s0 + r) * D + d] = (__bf16)((acc[mi][ni][r] + bv) * QSCALE);
      } else if (sec == 1) {
#pragma unroll
        for (int r = 0; r < 4; ++r)
          ko[((size_t)bh * S + s0 + r) * D + d] = (__bf16)(acc[mi][ni][r] + bv);
      } else {
        bf16x4 pv = {(__bf16)(acc[mi][ni][0] + bv), (__bf16)(acc[mi][ni][1] + bv),
                     (__bf16)(acc[mi][ni][2] + bv), (__bf16)(acc[mi][ni][3] + bv)};
        *reinterpret_cast<bf16x4*>(vo + ((size_t)bh * D + d) * S + s0) = pv;  // V^T
      }
    }
  }
}

// ================= out-proj: 128x256 pipelined GEMM (r9 structure, unchanged) ====
template <int BM, int BN, int NBXL>
__global__ __launch_bounds__(512, 1) void k_gp(
    const __bf16* __restrict__ A, const __bf16* __restrict__ Bt,
    const float* __restrict__ bias, float* __restrict__ fo) {
  constexpr int MF = BM / 32;
  constexpr int NF = BN / 64;
  constexpr int NH = NF / 2;
  constexpr int NLA = BM / 64;
  constexpr int NLB = BN / 64;
  constexpr int NL = NLA + NLB;
  constexpr int AOFF = BM * 128;
  constexpr int BUFSZ = (BM + BN) * 128;
  constexpr int NT = KDIM / 64;

  const int tid = threadIdx.x;
  const int lane = tid & 63, wid = tid >> 6;
  const int wm = wid >> 2, wn = wid & 3;
  const int ln = lane & 15, lm = lane >> 4;

  const int q8 = gridDim.x >> 3;
  const int lin = (blockIdx.x & 7) * q8 + (blockIdx.x >> 3);
  const int by = lin >> NBXL, bx = lin & ((1 << NBXL) - 1);
  const int mBase = by * BM, nBase = bx * BN;

  const int r0 = tid >> 3, cc = tid & 7;
  const int src0 = r0 * KDIM + ((cc ^ (r0 & 7)) << 3);
  const __bf16* Ab = A + (size_t)mBase * KDIM + src0;
  const __bf16* Bb = Bt + (size_t)nBase * KDIM + src0;
  const int dstBase = wid * 1024;

  auto stage = [&](char* buf, int t) {
    const __bf16* As = Ab + t * 64;
    const __bf16* Bs = Bb + t * 64;
#pragma unroll
    for (int j = 0; j < NLA; ++j)
      gll16(As + (size_t)j * 64 * KDIM, buf + j * 8192 + dstBase);
#pragma unroll
    for (int j = 0; j < NLB; ++j)
      gll16(Bs + (size_t)j * 64 * KDIM, buf + AOFF + j * 8192 + dstBase);
  };
  auto wait_nl = [&]() {
    if constexpr (NL == 4)       asm volatile("s_waitcnt vmcnt(4)" ::: "memory");
    else if constexpr (NL == 6)  asm volatile("s_waitcnt vmcnt(6)" ::: "memory");
    else                         asm volatile("s_waitcnt vmcnt(8)" ::: "memory");
  };

  int rA[2], rB[2];
#pragma unroll
  for (int ks = 0; ks < 2; ++ks) {
    const int slot = (ks * 4 + lm) ^ (ln & 7);
    rA[ks] = (wm * (BM / 2) + ln) * 128 + slot * 16;
    rB[ks] = AOFF + (wn * (BN / 4) + ln) * 128 + slot * 16;
  }

  f32x4 acc[MF][NF] = {};

  stage(smem, 0);
  stage(smem + BUFSZ, 1);
  wait_nl();
  __builtin_amdgcn_s_barrier();
  __builtin_amdgcn_sched_barrier(0);

  for (int t = 0; t < NT; ++t) {
    char* cb = smem + (t & 1) * BUFSZ;
    bf16x8 a0[MF], a1[MF], b0[NF], b1[NF];

#pragma unroll
    for (int mi = 0; mi < MF; ++mi)
      a0[mi] = *reinterpret_cast<const bf16x8*>(cb + rA[0] + mi * 2048);
#pragma unroll
    for (int ni = 0; ni < NH; ++ni)
      b0[ni] = *reinterpret_cast<const bf16x8*>(cb + rB[0] + ni * 2048);
#pragma unroll
    for (int ni = NH; ni < NF; ++ni)
      b0[ni] = *reinterpret_cast<const bf16x8*>(cb + rB[0] + ni * 2048);

    __builtin_amdgcn_s_setprio(1);
#pragma unroll
    for (int ni = 0; ni < NH; ++ni)
#pragma unroll
      for (int mi = 0; mi < MF; ++mi)
        acc[mi][ni] = mfma16(a0[mi], b0[ni], acc[mi][ni]);
    __builtin_amdgcn_s_setprio(0);

#pragma unroll
    for (int mi = 0; mi < MF; ++mi)
      a1[mi] = *reinterpret_cast<const bf16x8*>(cb + rA[1] + mi * 2048);
#pragma unroll
    for (int ni = NH; ni < NF; ++ni)
      b1[ni] = *reinterpret_cast<const bf16x8*>(cb + rB[1] + ni * 2048);

    __builtin_amdgcn_s_setprio(1);
#pragma unroll
    for (int ni = NH; ni < NF; ++ni)
#pragma unroll
      for (int mi = 0; mi < MF; ++mi)
        acc[mi][ni] = mfma16(a0[mi], b0[ni], acc[mi][ni]);
    __builtin_amdgcn_s_setprio(0);

#pragma unroll
    for (int ni = 0; ni < NH; ++ni)
      b1[ni] = *reinterpret_cast<const bf16x8*>(cb + rB[1] + ni * 2048);

    __builtin_amdgcn_s_setprio(1);
#pragma unroll
    for (int ni = NH; ni < NF; ++ni)
#pragma unroll
      for (int mi = 0; mi < MF; ++mi)
        acc[mi][ni] = mfma16(a1[mi], b1[ni], acc[mi][ni]);
    __builtin_amdgcn_s_setprio(0);

    asm volatile("s_waitcnt lgkmcnt(0)" ::: "memory");
    __builtin_amdgcn_s_barrier();
    __builtin_amdgcn_sched_barrier(0);
    if (t + 2 < NT) stage(cb, t + 2);

    __builtin_amdgcn_s_setprio(1);
#pragma unroll
    for (int ni = 0; ni < NH; ++ni)
#pragma unroll
      for (int mi = 0; mi < MF; ++mi)
        acc[mi][ni] = mfma16(a1[mi], b1[ni], acc[mi][ni]);
    __builtin_amdgcn_s_setprio(0);

    if (t + 2 < NT) {
      wait_nl();
    } else if (t + 1 < NT) {
      asm volatile("s_waitcnt vmcnt(0)" ::: "memory");
    }
    if (t + 1 < NT) {
      __builtin_amdgcn_s_barrier();
      __builtin_amdgcn_sched_barrier(0);
    }
  }

#pragma unroll
  for (int mi = 0; mi < MF; ++mi) {
    const int grow = mBase + wm * (BM / 2) + mi * 16 + lm * 4;
#pragma unroll
    for (int ni = 0; ni < NF; ++ni) {
      const int gcol = nBase + wn * (BN / 4) + ni * 16 + ln;
      const float bv = bias[gcol];
#pragma unroll
      for (int r = 0; r < 4; ++r)
        fo[(size_t)(grow + r) * F + gcol] = acc[mi][ni][r] + bv;
    }
  }
}

// ---------------- flash attention: 4 waves x 32 q-rows, KVBLK=64 ----------------
// 2 blocks/CU (80 KiB LDS each). Complementary-qt pairing + per-bh XCD affinity.
__global__ __launch_bounds__(256, 2) void k_attn(
    const __bf16* __restrict__ qb, const __bf16* __restrict__ kb,
    const __bf16* __restrict__ vtb, __bf16* __restrict__ zb) {
  const int lane = threadIdx.x & 63, w = threadIdx.x >> 6;
  const int lm = lane >> 4, ln = lane & 15;
  const int blk = blockIdx.x;
  const int u = blk & 255, v = blk >> 8;
  const int qt = v ? (u >> 4) : 15 - (u >> 4);
  const int bh = ((u & 15) << 1) | v;
  const int qw = qt * 128 + w * 32;

  const __bf16* qp = qb + (size_t)bh * S * D;
  const __bf16* kp = kb + (size_t)bh * S * D;
  const __bf16* vp = vtb + (size_t)bh * D * S;
  char* pw = smem + 65536 + w * 4096;

  int ksrc[4], kdst[4], vsrc[4], vdst[4];
#pragma unroll
  for (int j = 0; j < 4; ++j) {
    int c = (w * 4 + j) * 64 + lane;
    int kr = c >> 4, kps = (c & 15) ^ (kr & 7);
    ksrc[j] = kr * D + kps * 8;
    kdst[j] = (w * 4 + j) * 1024;
    int vr = c >> 3, vps = (c & 7) ^ (vr & 7);
    vsrc[j] = vr * S + vps * 8;
    vdst[j] = 16384 + (w * 4 + j) * 1024;
  }

  bf16x8 qf[2][4];
#pragma unroll
  for (int mi = 0; mi < 2; ++mi)
#pragma unroll
    for (int kf = 0; kf < 4; ++kf)
      qf[mi][kf] = *reinterpret_cast<const bf16x8*>(qp + (qw + mi * 16 + ln) * D + kf * 32 + lm * 8);

  f32x4 Oa[2][8] = {};
  float mrow[2][4], lrow[2][4];
#pragma unroll
  for (int mi = 0; mi < 2; ++mi)
#pragma unroll
    for (int r = 0; r < 4; ++r) { mrow[mi][r] = -3.0e38f; lrow[mi][r] = 0.0f; }

  const int ktEnd = 2 * qt + 1;

#pragma unroll
  for (int j = 0; j < 4; ++j) gll16(kp + ksrc[j], smem + kdst[j]);
#pragma unroll
  for (int j = 0; j < 4; ++j) gll16(vp + vsrc[j], smem + vdst[j]);
  asm volatile("s_waitcnt vmcnt(0)" ::: "memory");
  __builtin_amdgcn_s_barrier();
  __builtin_amdgcn_sched_barrier(0);

  for (int kt = 0; kt <= ktEnd; ++kt) {
    const int kv0 = kt * 64;
    const int cur = kt & 1;

    if (kt < ktEnd) {
      const int nk = (kt + 1) * 64;
      char* nbuf = smem + (cur ^ 1) * 32768;
#pragma unroll
      for (int j = 0; j < 4; ++j) gll16(kp + (size_t)nk * D + ksrc[j], nbuf + kdst[j]);
#pragma unroll
      for (int j = 0; j < 4; ++j) gll16(vp + nk + vsrc[j], nbuf + vdst[j]);
    }

    if (kv0 <= qw + 31) {
      const char* Kb = smem + cur * 32768;
      const char* Vb = Kb + 16384;
      const bool diag = (kv0 + 63 > qw);

      f32x4 sacc[2][4] = {};
#pragma unroll
      for (int kf = 0; kf < 4; ++kf) {
        bf16x8 kfr[4];
#pragma unroll
        for (int ni = 0; ni < 4; ++ni) {
          int row = ni * 16 + ln;
          int ch = (kf * 4 + lm) ^ (row & 7);
          kfr[ni] = *reinterpret_cast<const bf16x8*>(Kb + row * 256 + ch * 16);
        }
        __builtin_amdgcn_s_setprio(1);
#pragma unroll
        for (int mi = 0; mi < 2; ++mi)
#pragma unroll
          for (int ni = 0; ni < 4; ++ni)
            sacc[mi][ni] = mfma16(qf[mi][kf], kfr[ni], sacc[mi][ni]);
        __builtin_amdgcn_s_setprio(0);
      }

      if (diag) {
#pragma unroll
        for (int ni = 0; ni < 4; ++ni) {
          int c = kv0 + ni * 16 + ln;
#pragma unroll
          for (int mi = 0; mi < 2; ++mi) {
            int q0r = qw + mi * 16 + lm * 4;
#pragma unroll
            for (int r = 0; r < 4; ++r)
              if (c > q0r + r) sacc[mi][ni][r] = -1e30f;
          }
        }
      }

#pragma unroll
      for (int mi = 0; mi < 2; ++mi)
#pragma unroll
        for (int r = 0; r < 4; ++r) {
          float mx = fmaxf(fmaxf(sacc[mi][0][r], sacc[mi][1][r]),
                           fmaxf(sacc[mi][2][r], sacc[mi][3][r]));
          mx = fmaxf(mx, __shfl_xor(mx, 1, 64));
          mx = fmaxf(mx, __shfl_xor(mx, 2, 64));
          mx = fmaxf(mx, __shfl_xor(mx, 4, 64));
          mx = fmaxf(mx, __shfl_xor(mx, 8, 64));
          float mnew = fmaxf(mrow[mi][r], mx);
          float corr = __expf(mrow[mi][r] - mnew);
          mrow[mi][r] = mnew;
          float rs = 0.0f;
#pragma unroll
          for (int ni = 0; ni < 4; ++ni) {
            float p = __expf(sacc[mi][ni][r] - mnew);
            sacc[mi][ni][r] = p;
            rs += p;
          }
          lrow[mi][r] = lrow[mi][r] * corr + rs;
#pragma unroll
          for (int ni = 0; ni < 8; ++ni) Oa[mi][ni][r] *= corr;
        }

#pragma unroll
      for (int mi = 0; mi < 2; ++mi)
#pragma unroll
        for (int ni = 0; ni < 4; ++ni)
#pragma unroll
          for (int r = 0; r < 4; ++r) {
            int row = mi * 16 + lm * 4 + r;
            int bo = (row * 128 + (ni * 16 + ln) * 2) ^ ((row & 7) << 4);
            *reinterpret_cast<__bf16*>(pw + bo) = (__bf16)sacc[mi][ni][r];
          }

      asm volatile("s_waitcnt lgkmcnt(0)" ::: "memory");
      __builtin_amdgcn_sched_barrier(0);

#pragma unroll
      for (int kf = 0; kf < 2; ++kf) {
        bf16x8 pfr[2], vfr[8];
#pragma unroll
        for (int mi = 0; mi < 2; ++mi) {
          int row = mi * 16 + ln;
          int ch = (kf * 4 + lm) ^ (row & 7);
          pfr[mi] = *reinterpret_cast<const bf16x8*>(pw + row * 128 + ch * 16);
        }
#pragma unroll
        for (int ni = 0; ni < 8; ++ni) {
          int row = ni * 16 + ln;
          int ch = (kf * 4 + lm) ^ (row & 7);
          vfr[ni] = *reinterpret_cast<const bf16x8*>(Vb + row * 128 + ch * 16);
        }
        __builtin_amdgcn_s_setprio(1);
#pragma unroll
        for (int mi = 0; mi < 2; ++mi)
#pragma unroll
          for (int ni = 0; ni < 8; ++ni)
            Oa[mi][ni] = mfma16(pfr[mi], vfr[ni], Oa[mi][ni]);
        __builtin_amdgcn_s_setprio(0);
      }
    }

    asm volatile("s_waitcnt vmcnt(0) lgkmcnt(0)" ::: "memory");
    __builtin_amdgcn_s_barrier();
    __builtin_amdgcn_sched_barrier(0);
  }

#pragma unroll
  for (int mi = 0; mi < 2; ++mi)
#pragma unroll
    for (int r = 0; r < 4; ++r) {
      float ls = lrow[mi][r];
      ls += __shfl_xor(ls, 1, 64);
      ls += __shfl_xor(ls, 2, 64);
      ls += __shfl_xor(ls, 4, 64);
      ls += __shfl_xor(ls, 8, 64);
      lrow[mi][r] = 1.0f / ls;
    }
  const int b = bh >> 4, h = bh & 15;
#pragma unroll
  for (int mi = 0; mi < 2; ++mi)
#pragma unroll
    for (int ni = 0; ni < 8; ++ni) {
      int d = ni * 16 + ln;
#pragma unroll
      for (int r = 0; r < 4; ++r) {
        int qrow = qw + mi * 16 + lm * 4 + r;
        zb[(size_t)(b * S + qrow) * F + h * D + d] = (__bf16)(Oa[mi][ni][r] * lrow[mi][r]);
      }
    }
}

// ---------------- launch ----------------
extern "C" void kernel_launch(void* const* d_in, const int* in_sizes, int n_in,
                              void* d_out, int out_size, void* d_ws, size_t ws_size,
                              hipStream_t stream) {
  const float* x = (const float*)d_in[0];
  // d_in[1] = causal mask (implemented analytically)
  const float* w_attn = (const float*)d_in[2];
  const float* b_attn = (const float*)d_in[3];
  const float* w_proj = (const float*)d_in[4];
  const float* b_proj = (const float*)d_in[5];
  float* out = (float*)d_out;

  char* ws = (char*)d_ws;
  __bf16* xb    = (__bf16*)(ws + 0);          // 16 MB  [4096][2048] (reused as zb)
  __bf16* wqkv  = (__bf16*)(ws + 16777216);   // 24 MB  [6144][2048] (W^T)
  __bf16* wpro  = (__bf16*)(ws + 41943040);   //  8 MB  [2048][2048] (W^T)
  __bf16* qb    = (__bf16*)(ws + 50331648);   // 16 MB  [bh][s][d]
  __bf16* kb    = (__bf16*)(ws + 67108864);   // 16 MB  [bh][s][d]
  __bf16* vtb   = (__bf16*)(ws + 83886080);   // 16 MB  [bh][d][s]
  __bf16* zb    = xb;  // x fully consumed by QKV GEMM before attention writes z

  (void)hipFuncSetAttribute((const void*)k_qkv4<0>,
                            hipFuncAttributeMaxDynamicSharedMemorySize, 114688);
  (void)hipFuncSetAttribute((const void*)k_gp<128, 256, 3>,
                            hipFuncAttributeMaxDynamicSharedMemorySize, 98304);
  (void)hipFuncSetAttribute((const void*)k_attn,
                            hipFuncAttributeMaxDynamicSharedMemorySize, 81920);

  k_cvt<<<8192, 256, 0, stream>>>(x, xb);
  k_transpose<<<dim3(96, 32), 256, 0, stream>>>(w_attn, wqkv, 2048, 6144);
  k_transpose<<<dim3(32, 32), 256, 0, stream>>>(w_proj, wpro, 2048, 2048);
  // QKV: M=4096 (16 x 256), N=6144 (32 x 192) -> 512 blocks = 2 tail-free rounds
  k_qkv4<0><<<512, 256, 114688, stream>>>(xb, wqkv, b_attn, qb, kb, vtb);
  // attention: 512 blocks (complementary-qt balance + XCD affinity inside)
  k_attn<<<512, 256, 81920, stream>>>(qb, kb, vtb, zb);
  // out-proj: M=4096 (32 x 128), N=2048 (8 x 256) -> 256 blocks = 1/CU exact
  k_gp<128, 256, 3><<<256, 512, 98304, stream>>>(zb, wpro, b_proj, out);
}

// Round 14
// 270.885 us; speedup vs baseline: 1.4273x; 1.0870x over previous
//
#include <hip/hip_runtime.h>
#include <hip/hip_bf16.h>
#include <stdint.h>

typedef __attribute__((ext_vector_type(8))) __bf16 bf16x8;
typedef __attribute__((ext_vector_type(4))) __bf16 bf16x4;
typedef __attribute__((ext_vector_type(4))) float f32x4;

#define DEV __device__ __forceinline__

static constexpr int S = 2048, F = 2048, H = 16, D = 128;
static constexpr int KDIM = F;            // 2048
static constexpr float QSCALE = 0.08838834764831845f;  // 1/sqrt(128)

DEV void gll16(const void* g, void* l) {
  __builtin_amdgcn_global_load_lds(
      (const __attribute__((address_space(1))) void*)g,
      (__attribute__((address_space(3))) void*)l, 16, 0, 0);
}

DEV f32x4 mfma16(bf16x8 a, bf16x8 b, f32x4 c) {
  return __builtin_amdgcn_mfma_f32_16x16x32_bf16(a, b, c, 0, 0, 0);
}

extern __shared__ char smem[];

// ---------------- elementwise f32 -> bf16 ----------------
__global__ void k_cvt(const float* __restrict__ in, __bf16* __restrict__ out) {
  int i = blockIdx.x * 256 + threadIdx.x;
  float4 v = reinterpret_cast<const float4*>(in)[i];
  bf16x4 o = {(__bf16)v.x, (__bf16)v.y, (__bf16)v.z, (__bf16)v.w};
  reinterpret_cast<bf16x4*>(out)[i] = o;
}

// ---------------- transpose f32 [rows][cols] -> bf16 [cols][rows] ----------------
__global__ void k_transpose(const float* __restrict__ in, __bf16* __restrict__ out,
                            int rows, int cols) {
  __shared__ float t[64][65];
  const int c0 = blockIdx.x * 64, r0 = blockIdx.y * 64;
  const int tx = threadIdx.x & 63, ty = threadIdx.x >> 6;
#pragma unroll
  for (int i = 0; i < 64; i += 4)
    t[ty + i][tx] = in[(size_t)(r0 + ty + i) * cols + c0 + tx];
  __syncthreads();
#pragma unroll
  for (int i = 0; i < 64; i += 4)
    out[(size_t)(c0 + ty + i) * rows + r0 + tx] = (__bf16)t[tx][ty + i];
}

template <int MH>
DEV void mmq(f32x4 (&acc)[8][4], const bf16x8 (&a)[4], const bf16x8 (&b)[4]) {
#pragma unroll
  for (int ni = 0; ni < 4; ++ni)
#pragma unroll
    for (int mi = 0; mi < 4; ++mi)
      acc[MH * 4 + mi][ni] = mfma16(a[mi], b[ni], acc[MH * 4 + mi][ni]);
}

#define QBAR()  __builtin_amdgcn_s_barrier()
#define QLGKM() asm volatile("s_waitcnt lgkmcnt(0)" ::: "memory")
#define QSCB()  __builtin_amdgcn_sched_barrier(0)

// ================= QKV: m201-style 8-phase 256x256 GEMM, BK=64 =================
// 8 waves (2M x 4N), wave tile 128x64, acc[8][4] (128 AGPR; ~100 VGPR; 2 waves/SIMD
// budget 256 OK — r2 proved this acc size spill-free). LDS 128 KiB = 2 bufs x
// {A[256][64] @0, B[256][64] @32K}, halves of 128 rows, chunk-XOR swizzled.
// Iteration = 2 K-tiles (t0=2i -> buf0, t1=2i+1 -> buf1), 8 phases of
// {ds-reads | stage 1 half-tile | barrier | lgkm(0) | 16 MFMA | [vmcnt] | barrier}.
// Stage slots (derived WAR-safe: region's last read retires >=1 barrier earlier):
//   q0: A-h0(t1)  q1: A-h1(t1)  q2: B-h1(t1)  q3: B-h0(t2)
//   q4: A-h0(t2)  q5: A-h1(t2)  q6: B-h1(t2)  q7: B-h0(t3)
// Counted waits (issue->use lag): end-q1: vmcnt(6) [B-h1(t0) for q2],
// end-q3: vmcnt(4) [A-h0/h1,B-h0 of t1 for q4] (vmcnt(0) last iter),
// end-q5: vmcnt(6) [B-h1(t1) for q6], end-q7: vmcnt(4) [t2 halves for next q0].
// MFMA quadrants rotate (mh0,ks0)->(mh1,ks0)->(mh0,ks1)->(mh1,ks1): consecutive
// phases write disjoint acc rows -> MFMA pipe never dep-stalls across phases.
__global__ __launch_bounds__(512, 1) void k_qkv8(
    const __bf16* __restrict__ A, const __bf16* __restrict__ Bt,
    const float* __restrict__ bias,
    __bf16* __restrict__ qo, __bf16* __restrict__ ko, __bf16* __restrict__ vo) {
  constexpr int NT = 32;

  const int tid = threadIdx.x;
  const int lane = tid & 63, wid = tid >> 6;
  const int wm = wid >> 2, wn = wid & 3;
  const int ln = lane & 15, lm = lane >> 4;

  // XCD swizzle over 384 blocks (48/XCD: 2 A-panel rows x 24 B-tiles)
  const int lin = (blockIdx.x & 7) * 48 + (blockIdx.x >> 3);
  const int by = lin / 24, bx = lin % 24;
  const int mBase = by * 256, nBase = bx * 256;

  // stage source: chunk c = j*512+tid; row r = j*64+(tid>>3); cc = tid&7
  const int r0 = tid >> 3, cc = tid & 7;
  const int src0 = r0 * KDIM + ((cc ^ (r0 & 7)) << 3);
  const __bf16* Ab = A + (size_t)mBase * KDIM + src0;
  const __bf16* Bb = Bt + (size_t)nBase * KDIM + src0;
  const int sDst = wid * 1024;  // + lane*16 by HW

  auto stA = [&](int t, int h) {  // stage A half h of tile t (2 x 8 KB)
    char* d = smem + (t & 1) * 65536 + h * 16384 + sDst;
    const __bf16* s = Ab + (size_t)(h * 128) * KDIM + t * 64;
    gll16(s, d);
    gll16(s + (size_t)64 * KDIM, d + 8192);
  };
  auto stB = [&](int t, int h) {
    char* d = smem + (t & 1) * 65536 + 32768 + h * 16384 + sDst;
    const __bf16* s = Bb + (size_t)(h * 128) * KDIM + t * 64;
    gll16(s, d);
    gll16(s + (size_t)64 * KDIM, d + 8192);
  };

  int aOff[2], bOff[2];
#pragma unroll
  for (int ks = 0; ks < 2; ++ks) {
    const int slot = (ks * 4 + lm) ^ (ln & 7);
    aOff[ks] = (wm * 128 + ln) * 128 + slot * 16;
    bOff[ks] = 32768 + (wn * 64 + ln) * 128 + slot * 16;
  }
  auto rdA = [&](bf16x8 (&a)[4], const char* rb, int mh, int ks) {
#pragma unroll
    for (int mi = 0; mi < 4; ++mi)
      a[mi] = *reinterpret_cast<const bf16x8*>(rb + aOff[ks] + (mh * 4 + mi) * 2048);
  };
  auto rdB = [&](bf16x8 (&b)[4], const char* rb, int ks) {
#pragma unroll
    for (int ni = 0; ni < 4; ++ni)
      b[ni] = *reinterpret_cast<const bf16x8*>(rb + bOff[ks] + ni * 2048);
  };

  f32x4 acc[8][4] = {};

  // prologue: tile0 full (8 loads) + B-h0(1) (2 loads); vmcnt(2) => tile0 landed
  stA(0, 0); stA(0, 1); stB(0, 0); stB(0, 1); stB(1, 0);
  asm volatile("s_waitcnt vmcnt(2)" ::: "memory");
  QBAR(); QSCB();

  for (int i = 0; i < 16; ++i) {
    const char* L = smem;           // tile 2i
    const char* R = smem + 65536;   // tile 2i+1
    const int t1 = 2 * i + 1, t2 = 2 * i + 2, t3 = 2 * i + 3;
    const bool last = (i == 15);
    bf16x8 a[4], b0[4], b1[4];

    // ---- q0: t0 a-lo ks0 + b ks0; stage A-h0(t1) ----
    rdA(a, L, 0, 0); rdB(b0, L, 0);
    stA(t1, 0);
    QBAR(); QLGKM(); QSCB();
    __builtin_amdgcn_s_setprio(1); mmq<0>(acc, a, b0); __builtin_amdgcn_s_setprio(0);
    QBAR(); QSCB();

    // ---- q1: a-hi ks0; stage A-h1(t1); vmcnt(6) ----
    rdA(a, L, 1, 0);
    stA(t1, 1);
    QBAR(); QLGKM(); QSCB();
    __builtin_amdgcn_s_setprio(1); mmq<1>(acc, a, b0); __builtin_amdgcn_s_setprio(0);
    asm volatile("s_waitcnt vmcnt(6)" ::: "memory");
    QBAR(); QSCB();

    // ---- q2: a-lo ks1 + b ks1; stage B-h1(t1) ----
    rdA(a, L, 0, 1); rdB(b1, L, 1);
    stB(t1, 1);
    QBAR(); QLGKM(); QSCB();
    __builtin_amdgcn_s_setprio(1); mmq<0>(acc, a, b1); __builtin_amdgcn_s_setprio(0);
    QBAR(); QSCB();

    // ---- q3: a-hi ks1; stage B-h0(t2); vmcnt(4) (0 on last iter) ----
    rdA(a, L, 1, 1);
    if (t2 < NT) stB(t2, 0);
    QBAR(); QLGKM(); QSCB();
    __builtin_amdgcn_s_setprio(1); mmq<1>(acc, a, b1); __builtin_amdgcn_s_setprio(0);
    if (last) asm volatile("s_waitcnt vmcnt(0)" ::: "memory");
    else      asm volatile("s_waitcnt vmcnt(4)" ::: "memory");
    QBAR(); QSCB();

    // ---- q4: t1 a-lo ks0 + b ks0; stage A-h0(t2) ----
    rdA(a, R, 0, 0); rdB(b0, R, 0);
    if (t2 < NT) stA(t2, 0);
    QBAR(); QLGKM(); QSCB();
    __builtin_amdgcn_s_setprio(1); mmq<0>(acc, a, b0); __builtin_amdgcn_s_setprio(0);
    QBAR(); QSCB();

    // ---- q5: a-hi ks0; stage A-h1(t2); vmcnt(6) ----
    rdA(a, R, 1, 0);
    if (t2 < NT) stA(t2, 1);
    QBAR(); QLGKM(); QSCB();
    __builtin_amdgcn_s_setprio(1); mmq<1>(acc, a, b0); __builtin_amdgcn_s_setprio(0);
    asm volatile("s_waitcnt vmcnt(6)" ::: "memory");
    QBAR(); QSCB();

    // ---- q6: a-lo ks1 + b ks1; stage B-h1(t2) ----
    rdA(a, R, 0, 1); rdB(b1, R, 1);
    if (t2 < NT) stB(t2, 1);
    QBAR(); QLGKM(); QSCB();
    __builtin_amdgcn_s_setprio(1); mmq<0>(acc, a, b1); __builtin_amdgcn_s_setprio(0);
    QBAR(); QSCB();

    // ---- q7: a-hi ks1; stage B-h0(t3); vmcnt(4) ----
    rdA(a, R, 1, 1);
    if (t3 < NT) stB(t3, 0);
    QBAR(); QLGKM(); QSCB();
    __builtin_amdgcn_s_setprio(1); mmq<1>(acc, a, b1); __builtin_amdgcn_s_setprio(0);
    if (!last) {
      asm volatile("s_waitcnt vmcnt(4)" ::: "memory");
      QBAR(); QSCB();
    }
  }

  // epilogue: route Q (scaled), K, V^T; sec uniform per tile (256 | 2048)
  const int sec = nBase >> 11;
#pragma unroll
  for (int mi = 0; mi < 8; ++mi) {
    const int grow = mBase + wm * 128 + mi * 16 + lm * 4;
    const int b = grow >> 11, s0 = grow & 2047;
#pragma unroll
    for (int ni = 0; ni < 4; ++ni) {
      const int gcol = nBase + wn * 64 + ni * 16 + ln;
      const float bv = bias[gcol];
      const int h = (gcol >> 7) & 15, d = gcol & 127;
      const int bh = b * H + h;
      if (sec == 0) {
#pragma unroll
        for (int r = 0; r < 4; ++r)
          qo[((size_t)bh * S + s0 + r) * D + d] = (__bf16)((acc[mi][ni][r] + bv) * QSCALE);
      } else if (sec == 1) {
#pragma unroll
        for (int r = 0; r < 4; ++r)
          ko[((size_t)bh * S + s0 + r) * D + d] = (__bf16)(acc[mi][ni][r] + bv);
      } else {
        bf16x4 pv = {(__bf16)(acc[mi][ni][0] + bv), (__bf16)(acc[mi][ni][1] + bv),
                     (__bf16)(acc[mi][ni][2] + bv), (__bf16)(acc[mi][ni][3] + bv)};
        *reinterpret_cast<bf16x4*>(vo + ((size_t)bh * D + d) * S + s0) = pv;  // V^T
      }
    }
  }
}

// ================= out-proj: 128x256 pipelined GEMM (r9 structure) =================
template <int BM, int BN, int NBXL>
__global__ __launch_bounds__(512, 1) void k_gp(
    const __bf16* __restrict__ A, const __bf16* __restrict__ Bt,
    const float* __restrict__ bias, float* __restrict__ fo) {
  constexpr int MF = BM / 32;
  constexpr int NF = BN / 64;
  constexpr int NH = NF / 2;
  constexpr int NLA = BM / 64;
  constexpr int NLB = BN / 64;
  constexpr int NL = NLA + NLB;
  constexpr int AOFF = BM * 128;
  constexpr int BUFSZ = (BM + BN) * 128;
  constexpr int NT = KDIM / 64;

  const int tid = threadIdx.x;
  const int lane = tid & 63, wid = tid >> 6;
  const int wm = wid >> 2, wn = wid & 3;
  const int ln = lane & 15, lm = lane >> 4;

  const int q8 = gridDim.x >> 3;
  const int lin = (blockIdx.x & 7) * q8 + (blockIdx.x >> 3);
  const int by = lin >> NBXL, bx = lin & ((1 << NBXL) - 1);
  const int mBase = by * BM, nBase = bx * BN;

  const int r0 = tid >> 3, cc = tid & 7;
  const int src0 = r0 * KDIM + ((cc ^ (r0 & 7)) << 3);
  const __bf16* Ab = A + (size_t)mBase * KDIM + src0;
  const __bf16* Bb = Bt + (size_t)nBase * KDIM + src0;
  const int dstBase = wid * 1024;

  auto stage = [&](char* buf, int t) {
    const __bf16* As = Ab + t * 64;
    const __bf16* Bs = Bb + t * 64;
#pragma unroll
    for (int j = 0; j < NLA; ++j)
      gll16(As + (size_t)j * 64 * KDIM, buf + j * 8192 + dstBase);
#pragma unroll
    for (int j = 0; j < NLB; ++j)
      gll16(Bs + (size_t)j * 64 * KDIM, buf + AOFF + j * 8192 + dstBase);
  };
  auto wait_nl = [&]() {
    if constexpr (NL == 4)       asm volatile("s_waitcnt vmcnt(4)" ::: "memory");
    else if constexpr (NL == 6)  asm volatile("s_waitcnt vmcnt(6)" ::: "memory");
    else                         asm volatile("s_waitcnt vmcnt(8)" ::: "memory");
  };

  int rA[2], rB[2];
#pragma unroll
  for (int ks = 0; ks < 2; ++ks) {
    const int slot = (ks * 4 + lm) ^ (ln & 7);
    rA[ks] = (wm * (BM / 2) + ln) * 128 + slot * 16;
    rB[ks] = AOFF + (wn * (BN / 4) + ln) * 128 + slot * 16;
  }

  f32x4 acc[MF][NF] = {};

  stage(smem, 0);
  stage(smem + BUFSZ, 1);
  wait_nl();
  QBAR(); QSCB();

  for (int t = 0; t < NT; ++t) {
    char* cb = smem + (t & 1) * BUFSZ;
    bf16x8 a0[MF], a1[MF], b0[NF], b1[NF];

#pragma unroll
    for (int mi = 0; mi < MF; ++mi)
      a0[mi] = *reinterpret_cast<const bf16x8*>(cb + rA[0] + mi * 2048);
#pragma unroll
    for (int ni = 0; ni < NF; ++ni)
      b0[ni] = *reinterpret_cast<const bf16x8*>(cb + rB[0] + ni * 2048);

    __builtin_amdgcn_s_setprio(1);
#pragma unroll
    for (int ni = 0; ni < NH; ++ni)
#pragma unroll
      for (int mi = 0; mi < MF; ++mi)
        acc[mi][ni] = mfma16(a0[mi], b0[ni], acc[mi][ni]);
    __builtin_amdgcn_s_setprio(0);

#pragma unroll
    for (int mi = 0; mi < MF; ++mi)
      a1[mi] = *reinterpret_cast<const bf16x8*>(cb + rA[1] + mi * 2048);
#pragma unroll
    for (int ni = NH; ni < NF; ++ni)
      b1[ni] = *reinterpret_cast<const bf16x8*>(cb + rB[1] + ni * 2048);

    __builtin_amdgcn_s_setprio(1);
#pragma unroll
    for (int ni = NH; ni < NF; ++ni)
#pragma unroll
      for (int mi = 0; mi < MF; ++mi)
        acc[mi][ni] = mfma16(a0[mi], b0[ni], acc[mi][ni]);
    __builtin_amdgcn_s_setprio(0);

#pragma unroll
    for (int ni = 0; ni < NH; ++ni)
      b1[ni] = *reinterpret_cast<const bf16x8*>(cb + rB[1] + ni * 2048);

    __builtin_amdgcn_s_setprio(1);
#pragma unroll
    for (int ni = NH; ni < NF; ++ni)
#pragma unroll
      for (int mi = 0; mi < MF; ++mi)
        acc[mi][ni] = mfma16(a1[mi], b1[ni], acc[mi][ni]);
    __builtin_amdgcn_s_setprio(0);

    QLGKM();
    QBAR(); QSCB();
    if (t + 2 < NT) stage(cb, t + 2);

    __builtin_amdgcn_s_setprio(1);
#pragma unroll
    for (int ni = 0; ni < NH; ++ni)
#pragma unroll
      for (int mi = 0; mi < MF; ++mi)
        acc[mi][ni] = mfma16(a1[mi], b1[ni], acc[mi][ni]);
    __builtin_amdgcn_s_setprio(0);

    if (t + 2 < NT) {
      wait_nl();
    } else if (t + 1 < NT) {
      asm volatile("s_waitcnt vmcnt(0)" ::: "memory");
    }
    if (t + 1 < NT) {
      QBAR(); QSCB();
    }
  }

#pragma unroll
  for (int mi = 0; mi < MF; ++mi) {
    const int grow = mBase + wm * (BM / 2) + mi * 16 + lm * 4;
#pragma unroll
    for (int ni = 0; ni < NF; ++ni) {
      const int gcol = nBase + wn * (BN / 4) + ni * 16 + ln;
      const float bv = bias[gcol];
#pragma unroll
      for (int r = 0; r < 4; ++r)
        fo[(size_t)(grow + r) * F + gcol] = acc[mi][ni][r] + bv;
    }
  }
}

// ---------------- flash attention: 4 waves x 32 q-rows, KVBLK=64 ----------------
__global__ __launch_bounds__(256, 2) void k_attn(
    const __bf16* __restrict__ qb, const __bf16* __restrict__ kb,
    const __bf16* __restrict__ vtb, __bf16* __restrict__ zb) {
  const int lane = threadIdx.x & 63, w = threadIdx.x >> 6;
  const int lm = lane >> 4, ln = lane & 15;
  const int blk = blockIdx.x;
  const int u = blk & 255, v = blk >> 8;
  const int qt = v ? (u >> 4) : 15 - (u >> 4);
  const int bh = ((u & 15) << 1) | v;
  const int qw = qt * 128 + w * 32;

  const __bf16* qp = qb + (size_t)bh * S * D;
  const __bf16* kp = kb + (size_t)bh * S * D;
  const __bf16* vp = vtb + (size_t)bh * D * S;
  char* pw = smem + 65536 + w * 4096;

  int ksrc[4], kdst[4], vsrc[4], vdst[4];
#pragma unroll
  for (int j = 0; j < 4; ++j) {
    int c = (w * 4 + j) * 64 + lane;
    int kr = c >> 4, kps = (c & 15) ^ (kr & 7);
    ksrc[j] = kr * D + kps * 8;
    kdst[j] = (w * 4 + j) * 1024;
    int vr = c >> 3, vps = (c & 7) ^ (vr & 7);
    vsrc[j] = vr * S + vps * 8;
    vdst[j] = 16384 + (w * 4 + j) * 1024;
  }

  bf16x8 qf[2][4];
#pragma unroll
  for (int mi = 0; mi < 2; ++mi)
#pragma unroll
    for (int kf = 0; kf < 4; ++kf)
      qf[mi][kf] = *reinterpret_cast<const bf16x8*>(qp + (qw + mi * 16 + ln) * D + kf * 32 + lm * 8);

  f32x4 Oa[2][8] = {};
  float mrow[2][4], lrow[2][4];
#pragma unroll
  for (int mi = 0; mi < 2; ++mi)
#pragma unroll
    for (int r = 0; r < 4; ++r) { mrow[mi][r] = -3.0e38f; lrow[mi][r] = 0.0f; }

  const int ktEnd = 2 * qt + 1;

#pragma unroll
  for (int j = 0; j < 4; ++j) gll16(kp + ksrc[j], smem + kdst[j]);
#pragma unroll
  for (int j = 0; j < 4; ++j) gll16(vp + vsrc[j], smem + vdst[j]);
  asm volatile("s_waitcnt vmcnt(0)" ::: "memory");
  QBAR(); QSCB();

  for (int kt = 0; kt <= ktEnd; ++kt) {
    const int kv0 = kt * 64;
    const int cur = kt & 1;

    if (kt < ktEnd) {
      const int nk = (kt + 1) * 64;
      char* nbuf = smem + (cur ^ 1) * 32768;
#pragma unroll
      for (int j = 0; j < 4; ++j) gll16(kp + (size_t)nk * D + ksrc[j], nbuf + kdst[j]);
#pragma unroll
      for (int j = 0; j < 4; ++j) gll16(vp + nk + vsrc[j], nbuf + vdst[j]);
    }

    if (kv0 <= qw + 31) {
      const char* Kb = smem + cur * 32768;
      const char* Vb = Kb + 16384;
      const bool diag = (kv0 + 63 > qw);

      f32x4 sacc[2][4] = {};
#pragma unroll
      for (int kf = 0; kf < 4; ++kf) {
        bf16x8 kfr[4];
#pragma unroll
        for (int ni = 0; ni < 4; ++ni) {
          int row = ni * 16 + ln;
          int ch = (kf * 4 + lm) ^ (row & 7);
          kfr[ni] = *reinterpret_cast<const bf16x8*>(Kb + row * 256 + ch * 16);
        }
        __builtin_amdgcn_s_setprio(1);
#pragma unroll
        for (int mi = 0; mi < 2; ++mi)
#pragma unroll
          for (int ni = 0; ni < 4; ++ni)
            sacc[mi][ni] = mfma16(qf[mi][kf], kfr[ni], sacc[mi][ni]);
        __builtin_amdgcn_s_setprio(0);
      }

      if (diag) {
#pragma unroll
        for (int ni = 0; ni < 4; ++ni) {
          int c = kv0 + ni * 16 + ln;
#pragma unroll
          for (int mi = 0; mi < 2; ++mi) {
            int q0r = qw + mi * 16 + lm * 4;
#pragma unroll
            for (int r = 0; r < 4; ++r)
              if (c > q0r + r) sacc[mi][ni][r] = -1e30f;
          }
        }
      }

#pragma unroll
      for (int mi = 0; mi < 2; ++mi)
#pragma unroll
        for (int r = 0; r < 4; ++r) {
          float mx = fmaxf(fmaxf(sacc[mi][0][r], sacc[mi][1][r]),
                           fmaxf(sacc[mi][2][r], sacc[mi][3][r]));
          mx = fmaxf(mx, __shfl_xor(mx, 1, 64));
          mx = fmaxf(mx, __shfl_xor(mx, 2, 64));
          mx = fmaxf(mx, __shfl_xor(mx, 4, 64));
          mx = fmaxf(mx, __shfl_xor(mx, 8, 64));
          float mnew = fmaxf(mrow[mi][r], mx);
          float corr = __expf(mrow[mi][r] - mnew);
          mrow[mi][r] = mnew;
          float rs = 0.0f;
#pragma unroll
          for (int ni = 0; ni < 4; ++ni) {
            float p = __expf(sacc[mi][ni][r] - mnew);
            sacc[mi][ni][r] = p;
            rs += p;
          }
          lrow[mi][r] = lrow[mi][r] * corr + rs;
#pragma unroll
          for (int ni = 0; ni < 8; ++ni) Oa[mi][ni][r] *= corr;
        }

#pragma unroll
      for (int mi = 0; mi < 2; ++mi)
#pragma unroll
        for (int ni = 0; ni < 4; ++ni)
#pragma unroll
          for (int r = 0; r < 4; ++r) {
            int row = mi * 16 + lm * 4 + r;
            int bo = (row * 128 + (ni * 16 + ln) * 2) ^ ((row & 7) << 4);
            *reinterpret_cast<__bf16*>(pw + bo) = (__bf16)sacc[mi][ni][r];
          }

      QLGKM(); QSCB();

#pragma unroll
      for (int kf = 0; kf < 2; ++kf) {
        bf16x8 pfr[2], vfr[8];
#pragma unroll
        for (int mi = 0; mi < 2; ++mi) {
          int row = mi * 16 + ln;
          int ch = (kf * 4 + lm) ^ (row & 7);
          pfr[mi] = *reinterpret_cast<const bf16x8*>(pw + row * 128 + ch * 16);
        }
#pragma unroll
        for (int ni = 0; ni < 8; ++ni) {
          int row = ni * 16 + ln;
          int ch = (kf * 4 + lm) ^ (row & 7);
          vfr[ni] = *reinterpret_cast<const bf16x8*>(Vb + row * 128 + ch * 16);
        }
        __builtin_amdgcn_s_setprio(1);
#pragma unroll
        for (int mi = 0; mi < 2; ++mi)
#pragma unroll
          for (int ni = 0; ni < 8; ++ni)
            Oa[mi][ni] = mfma16(pfr[mi], vfr[ni], Oa[mi][ni]);
        __builtin_amdgcn_s_setprio(0);
      }
    }

    asm volatile("s_waitcnt vmcnt(0) lgkmcnt(0)" ::: "memory");
    QBAR(); QSCB();
  }

#pragma unroll
  for (int mi = 0; mi < 2; ++mi)
#pragma unroll
    for (int r = 0; r < 4; ++r) {
      float ls = lrow[mi][r];
      ls += __shfl_xor(ls, 1, 64);
      ls += __shfl_xor(ls, 2, 64);
      ls += __shfl_xor(ls, 4, 64);
      ls += __shfl_xor(ls, 8, 64);
      lrow[mi][r] = 1.0f / ls;
    }
  const int b = bh >> 4, h = bh & 15;
#pragma unroll
  for (int mi = 0; mi < 2; ++mi)
#pragma unroll
    for (int ni = 0; ni < 8; ++ni) {
      int d = ni * 16 + ln;
#pragma unroll
      for (int r = 0; r < 4; ++r) {
        int qrow = qw + mi * 16 + lm * 4 + r;
        zb[(size_t)(b * S + qrow) * F + h * D + d] = (__bf16)(Oa[mi][ni][r] * lrow[mi][r]);
      }
    }
}

// ---------------- launch ----------------
extern "C" void kernel_launch(void* const* d_in, const int* in_sizes, int n_in,
                              void* d_out, int out_size, void* d_ws, size_t ws_size,
                              hipStream_t stream) {
  const float* x = (const float*)d_in[0];
  // d_in[1] = causal mask (implemented analytically)
  const float* w_attn = (const float*)d_in[2];
  const float* b_attn = (const float*)d_in[3];
  const float* w_proj = (const float*)d_in[4];
  const float* b_proj = (const float*)d_in[5];
  float* out = (float*)d_out;

  char* ws = (char*)d_ws;
  __bf16* xb    = (__bf16*)(ws + 0);          // 16 MB  [4096][2048] (reused as zb)
  __bf16* wqkv  = (__bf16*)(ws + 16777216);   // 24 MB  [6144][2048] (W^T)
  __bf16* wpro  = (__bf16*)(ws + 41943040);   //  8 MB  [2048][2048] (W^T)
  __bf16* qb    = (__bf16*)(ws + 50331648);   // 16 MB  [bh][s][d]
  __bf16* kb    = (__bf16*)(ws + 67108864);   // 16 MB  [bh][s][d]
  __bf16* vtb   = (__bf16*)(ws + 83886080);   // 16 MB  [bh][d][s]
  __bf16* zb    = xb;  // x fully consumed by QKV GEMM before attention writes z

  (void)hipFuncSetAttribute((const void*)k_qkv8,
                            hipFuncAttributeMaxDynamicSharedMemorySize, 131072);
  (void)hipFuncSetAttribute((const void*)k_gp<128, 256, 3>,
                            hipFuncAttributeMaxDynamicSharedMemorySize, 98304);
  (void)hipFuncSetAttribute((const void*)k_attn,
                            hipFuncAttributeMaxDynamicSharedMemorySize, 81920);

  k_cvt<<<8192, 256, 0, stream>>>(x, xb);
  k_transpose<<<dim3(96, 32), 256, 0, stream>>>(w_attn, wqkv, 2048, 6144);
  k_transpose<<<dim3(32, 32), 256, 0, stream>>>(w_proj, wpro, 2048, 2048);
  // QKV: M=4096 (16 x 256), N=6144 (24 x 256) -> 384 blocks (1.5 rounds @ 1/CU)
  k_qkv8<<<384, 512, 131072, stream>>>(xb, wqkv, b_attn, qb, kb, vtb);
  // attention: 512 blocks (complementary-qt balance + XCD affinity inside)
  k_attn<<<512, 256, 81920, stream>>>(qb, kb, vtb, zb);
  // out-proj: M=4096 (32 x 128), N=2048 (8 x 256) -> 256 blocks = 1/CU exact
  k_gp<128, 256, 3><<<256, 512, 98304, stream>>>(zb, wpro, b_proj, out);
}

// Round 15
// 262.854 us; speedup vs baseline: 1.4709x; 1.0306x over previous
//
#include <hip/hip_runtime.h>
#include <hip/hip_bf16.h>
#include <stdint.h>

typedef __attribute__((ext_vector_type(8))) __bf16 bf16x8;
typedef __attribute__((ext_vector_type(4))) __bf16 bf16x4;
typedef __attribute__((ext_vector_type(4))) float f32x4;

#define DEV __device__ __forceinline__

static constexpr int S = 2048, F = 2048, H = 16, D = 128;
static constexpr int KDIM = F;            // 2048
static constexpr float QSCALE = 0.08838834764831845f;  // 1/sqrt(128)

DEV void gll16(const void* g, void* l) {
  __builtin_amdgcn_global_load_lds(
      (const __attribute__((address_space(1))) void*)g,
      (__attribute__((address_space(3))) void*)l, 16, 0, 0);
}

DEV f32x4 mfma16(bf16x8 a, bf16x8 b, f32x4 c) {
  return __builtin_amdgcn_mfma_f32_16x16x32_bf16(a, b, c, 0, 0, 0);
}

extern __shared__ char smem[];

// ---------------- elementwise f32 -> bf16 ----------------
__global__ void k_cvt(const float* __restrict__ in, __bf16* __restrict__ out) {
  int i = blockIdx.x * 256 + threadIdx.x;
  float4 v = reinterpret_cast<const float4*>(in)[i];
  bf16x4 o = {(__bf16)v.x, (__bf16)v.y, (__bf16)v.z, (__bf16)v.w};
  reinterpret_cast<bf16x4*>(out)[i] = o;
}

// ---------------- transpose f32 [rows][cols] -> bf16 [cols][rows] ----------------
__global__ void k_transpose(const float* __restrict__ in, __bf16* __restrict__ out,
                            int rows, int cols) {
  __shared__ float t[64][65];
  const int c0 = blockIdx.x * 64, r0 = blockIdx.y * 64;
  const int tx = threadIdx.x & 63, ty = threadIdx.x >> 6;
#pragma unroll
  for (int i = 0; i < 64; i += 4)
    t[ty + i][tx] = in[(size_t)(r0 + ty + i) * cols + c0 + tx];
  __syncthreads();
#pragma unroll
  for (int i = 0; i < 64; i += 4)
    out[(size_t)(c0 + ty + i) * rows + r0 + tx] = (__bf16)t[tx][ty + i];
}

// ================= pipelined GEMM: BMxBN tile, BK=64, dbuf + counted vmcnt =========
// (r9/r10 structure — best measured QKV: 113.8 us, tail-free 512 blocks)
template <int BM, int BN, int NBXL, int EPI>
__global__ __launch_bounds__(512, 1) void k_gp(
    const __bf16* __restrict__ A, const __bf16* __restrict__ Bt,
    const float* __restrict__ bias,
    __bf16* __restrict__ qo, __bf16* __restrict__ ko, __bf16* __restrict__ vo,
    float* __restrict__ fo) {
  constexpr int MF = BM / 32;
  constexpr int NF = BN / 64;
  constexpr int NH = NF / 2;
  constexpr int NLA = BM / 64;
  constexpr int NLB = BN / 64;
  constexpr int NL = NLA + NLB;
  constexpr int AOFF = BM * 128;
  constexpr int BUFSZ = (BM + BN) * 128;
  constexpr int NT = KDIM / 64;

  const int tid = threadIdx.x;
  const int lane = tid & 63, wid = tid >> 6;
  const int wm = wid >> 2, wn = wid & 3;
  const int ln = lane & 15, lm = lane >> 4;

  const int q8 = gridDim.x >> 3;
  const int lin = (blockIdx.x & 7) * q8 + (blockIdx.x >> 3);
  const int by = lin >> NBXL, bx = lin & ((1 << NBXL) - 1);
  const int mBase = by * BM, nBase = bx * BN;

  const int r0 = tid >> 3, cc = tid & 7;
  const int src0 = r0 * KDIM + ((cc ^ (r0 & 7)) << 3);
  const __bf16* Ab = A + (size_t)mBase * KDIM + src0;
  const __bf16* Bb = Bt + (size_t)nBase * KDIM + src0;
  const int dstBase = wid * 1024;

  auto stage = [&](char* buf, int t) {
    const __bf16* As = Ab + t * 64;
    const __bf16* Bs = Bb + t * 64;
#pragma unroll
    for (int j = 0; j < NLA; ++j)
      gll16(As + (size_t)j * 64 * KDIM, buf + j * 8192 + dstBase);
#pragma unroll
    for (int j = 0; j < NLB; ++j)
      gll16(Bs + (size_t)j * 64 * KDIM, buf + AOFF + j * 8192 + dstBase);
  };
  auto wait_nl = [&]() {
    if constexpr (NL == 4)       asm volatile("s_waitcnt vmcnt(4)" ::: "memory");
    else if constexpr (NL == 6)  asm volatile("s_waitcnt vmcnt(6)" ::: "memory");
    else if constexpr (NL == 8)  asm volatile("s_waitcnt vmcnt(8)" ::: "memory");
    else                         asm volatile("s_waitcnt vmcnt(10)" ::: "memory");
  };

  int rA[2], rB[2];
#pragma unroll
  for (int ks = 0; ks < 2; ++ks) {
    const int slot = (ks * 4 + lm) ^ (ln & 7);
    rA[ks] = (wm * (BM / 2) + ln) * 128 + slot * 16;
    rB[ks] = AOFF + (wn * (BN / 4) + ln) * 128 + slot * 16;
  }

  f32x4 acc[MF][NF] = {};

  stage(smem, 0);
  stage(smem + BUFSZ, 1);
  wait_nl();
  __builtin_amdgcn_s_barrier();
  __builtin_amdgcn_sched_barrier(0);

  for (int t = 0; t < NT; ++t) {
    char* cb = smem + (t & 1) * BUFSZ;
    bf16x8 a0[MF], a1[MF], b0[NF], b1[NF];

#pragma unroll
    for (int mi = 0; mi < MF; ++mi)
      a0[mi] = *reinterpret_cast<const bf16x8*>(cb + rA[0] + mi * 2048);
#pragma unroll
    for (int ni = 0; ni < NH; ++ni)
      b0[ni] = *reinterpret_cast<const bf16x8*>(cb + rB[0] + ni * 2048);
#pragma unroll
    for (int ni = NH; ni < NF; ++ni)
      b0[ni] = *reinterpret_cast<const bf16x8*>(cb + rB[0] + ni * 2048);

    __builtin_amdgcn_s_setprio(1);
#pragma unroll
    for (int ni = 0; ni < NH; ++ni)
#pragma unroll
      for (int mi = 0; mi < MF; ++mi)
        acc[mi][ni] = mfma16(a0[mi], b0[ni], acc[mi][ni]);
    __builtin_amdgcn_s_setprio(0);

#pragma unroll
    for (int mi = 0; mi < MF; ++mi)
      a1[mi] = *reinterpret_cast<const bf16x8*>(cb + rA[1] + mi * 2048);
#pragma unroll
    for (int ni = NH; ni < NF; ++ni)
      b1[ni] = *reinterpret_cast<const bf16x8*>(cb + rB[1] + ni * 2048);

    __builtin_amdgcn_s_setprio(1);
#pragma unroll
    for (int ni = NH; ni < NF; ++ni)
#pragma unroll
      for (int mi = 0; mi < MF; ++mi)
        acc[mi][ni] = mfma16(a0[mi], b0[ni], acc[mi][ni]);
    __builtin_amdgcn_s_setprio(0);

#pragma unroll
    for (int ni = 0; ni < NH; ++ni)
      b1[ni] = *reinterpret_cast<const bf16x8*>(cb + rB[1] + ni * 2048);

    __builtin_amdgcn_s_setprio(1);
#pragma unroll
    for (int ni = NH; ni < NF; ++ni)
#pragma unroll
      for (int mi = 0; mi < MF; ++mi)
        acc[mi][ni] = mfma16(a1[mi], b1[ni], acc[mi][ni]);
    __builtin_amdgcn_s_setprio(0);

    asm volatile("s_waitcnt lgkmcnt(0)" ::: "memory");
    __builtin_amdgcn_s_barrier();
    __builtin_amdgcn_sched_barrier(0);
    if (t + 2 < NT) stage(cb, t + 2);

    __builtin_amdgcn_s_setprio(1);
#pragma unroll
    for (int ni = 0; ni < NH; ++ni)
#pragma unroll
      for (int mi = 0; mi < MF; ++mi)
        acc[mi][ni] = mfma16(a1[mi], b1[ni], acc[mi][ni]);
    __builtin_amdgcn_s_setprio(0);

    if (t + 2 < NT) {
      wait_nl();
    } else if (t + 1 < NT) {
      asm volatile("s_waitcnt vmcnt(0)" ::: "memory");
    }
    if (t + 1 < NT) {
      __builtin_amdgcn_s_barrier();
      __builtin_amdgcn_sched_barrier(0);
    }
  }

  if (EPI == 0) {
#pragma unroll
    for (int mi = 0; mi < MF; ++mi) {
      const int grow = mBase + wm * (BM / 2) + mi * 16 + lm * 4;
      const int b = grow >> 11, s0 = grow & 2047;
#pragma unroll
      for (int ni = 0; ni < NF; ++ni) {
        const int gcol = nBase + wn * (BN / 4) + ni * 16 + ln;
        const float bv = bias[gcol];
        const int sec = gcol >> 11;
        const int h = (gcol >> 7) & 15, d = gcol & 127;
        const int bh = b * H + h;
        if (sec == 0) {
#pragma unroll
          for (int r = 0; r < 4; ++r)
            qo[((size_t)bh * S + s0 + r) * D + d] = (__bf16)((acc[mi][ni][r] + bv) * QSCALE);
        } else if (sec == 1) {
#pragma unroll
          for (int r = 0; r < 4; ++r)
            ko[((size_t)bh * S + s0 + r) * D + d] = (__bf16)(acc[mi][ni][r] + bv);
        } else {
          bf16x4 pv = {(__bf16)(acc[mi][ni][0] + bv), (__bf16)(acc[mi][ni][1] + bv),
                       (__bf16)(acc[mi][ni][2] + bv), (__bf16)(acc[mi][ni][3] + bv)};
          *reinterpret_cast<bf16x4*>(vo + ((size_t)bh * D + d) * S + s0) = pv;  // V^T
        }
      }
    }
  } else {
#pragma unroll
    for (int mi = 0; mi < MF; ++mi) {
      const int grow = mBase + wm * (BM / 2) + mi * 16 + lm * 4;
#pragma unroll
      for (int ni = 0; ni < NF; ++ni) {
        const int gcol = nBase + wn * (BN / 4) + ni * 16 + ln;
        const float bv = bias[gcol];
#pragma unroll
        for (int r = 0; r < 4; ++r)
          fo[(size_t)(grow + r) * F + gcol] = acc[mi][ni][r] + bv;
      }
    }
  }
}

// ---------------- flash attention: 4 waves x 32 q-rows, KVBLK=64 ----------------
// R15: counted-wait tile loop. Stage moved AFTER compute (into the just-freed
// buffer, 2 tiles ahead): boundary = lgkm(0); barrier; stage(kt+2 -> cur);
// vmcnt(8); barrier. Never vmcnt(0) mid-loop (only at penultimate tile, where
// the data is ~2 tiles old -> free). Per-wave ledger: at the wait, outstanding
// newer loads = kt+2's 8 -> vmcnt(8) <=> kt+1's tile landed. WAR-safe: stage
// writes cur only after the barrier retiring all waves' reads of cur.
// + T13 defer-max (THR=8, __any-uniform): skip O-rescale when no row grew >8.
// 2 blocks/CU (80 KiB). Complementary-qt pairing + per-bh XCD affinity.
__global__ __launch_bounds__(256, 2) void k_attn(
    const __bf16* __restrict__ qb, const __bf16* __restrict__ kb,
    const __bf16* __restrict__ vtb, __bf16* __restrict__ zb) {
  const int lane = threadIdx.x & 63, w = threadIdx.x >> 6;
  const int lm = lane >> 4, ln = lane & 15;
  const int blk = blockIdx.x;
  const int u = blk & 255, v = blk >> 8;
  const int qt = v ? (u >> 4) : 15 - (u >> 4);
  const int bh = ((u & 15) << 1) | v;
  const int qw = qt * 128 + w * 32;

  const __bf16* qp = qb + (size_t)bh * S * D;
  const __bf16* kp = kb + (size_t)bh * S * D;
  const __bf16* vp = vtb + (size_t)bh * D * S;
  char* pw = smem + 65536 + w * 4096;

  int ksrc[4], kdst[4], vsrc[4], vdst[4];
#pragma unroll
  for (int j = 0; j < 4; ++j) {
    int c = (w * 4 + j) * 64 + lane;
    int kr = c >> 4, kps = (c & 15) ^ (kr & 7);
    ksrc[j] = kr * D + kps * 8;
    kdst[j] = (w * 4 + j) * 1024;
    int vr = c >> 3, vps = (c & 7) ^ (vr & 7);
    vsrc[j] = vr * S + vps * 8;
    vdst[j] = 16384 + (w * 4 + j) * 1024;
  }
  auto stage = [&](int kt) {  // 8 loads into buf (kt&1)
    char* buf = smem + (kt & 1) * 32768;
    const int kv = kt * 64;
#pragma unroll
    for (int j = 0; j < 4; ++j) gll16(kp + (size_t)kv * D + ksrc[j], buf + kdst[j]);
#pragma unroll
    for (int j = 0; j < 4; ++j) gll16(vp + kv + vsrc[j], buf + vdst[j]);
  };

  bf16x8 qf[2][4];
#pragma unroll
  for (int mi = 0; mi < 2; ++mi)
#pragma unroll
    for (int kf = 0; kf < 4; ++kf)
      qf[mi][kf] = *reinterpret_cast<const bf16x8*>(qp + (qw + mi * 16 + ln) * D + kf * 32 + lm * 8);

  f32x4 Oa[2][8] = {};
  float mrow[2][4], lrow[2][4];
#pragma unroll
  for (int mi = 0; mi < 2; ++mi)
#pragma unroll
    for (int r = 0; r < 4; ++r) { mrow[mi][r] = -3.0e38f; lrow[mi][r] = 0.0f; }

  const int ktEnd = 2 * qt + 1;

  // prologue: stage tiles 0 and 1 (ktEnd >= 1 always)
  stage(0);
  stage(1);
  asm volatile("s_waitcnt vmcnt(8)" ::: "memory");  // tile 0 landed (tile 1 newer)
  __builtin_amdgcn_s_barrier();
  __builtin_amdgcn_sched_barrier(0);

  for (int kt = 0; kt <= ktEnd; ++kt) {
    const int kv0 = kt * 64;
    const int cur = kt & 1;
    const char* Kb = smem + cur * 32768;
    const char* Vb = Kb + 16384;

    if (kv0 <= qw + 31) {  // wave has unmasked work in this tile
      const bool diag = (kv0 + 63 > qw);

      // S = Q K^T : M=32(q) N=64(kv) K=128(d)
      f32x4 sacc[2][4] = {};
#pragma unroll
      for (int kf = 0; kf < 4; ++kf) {
        bf16x8 kfr[4];
#pragma unroll
        for (int ni = 0; ni < 4; ++ni) {
          int row = ni * 16 + ln;
          int ch = (kf * 4 + lm) ^ (row & 7);
          kfr[ni] = *reinterpret_cast<const bf16x8*>(Kb + row * 256 + ch * 16);
        }
        __builtin_amdgcn_s_setprio(1);
#pragma unroll
        for (int mi = 0; mi < 2; ++mi)
#pragma unroll
          for (int ni = 0; ni < 4; ++ni)
            sacc[mi][ni] = mfma16(qf[mi][kf], kfr[ni], sacc[mi][ni]);
        __builtin_amdgcn_s_setprio(0);
      }

      if (diag) {
#pragma unroll
        for (int ni = 0; ni < 4; ++ni) {
          int c = kv0 + ni * 16 + ln;
#pragma unroll
          for (int mi = 0; mi < 2; ++mi) {
            int q0r = qw + mi * 16 + lm * 4;
#pragma unroll
            for (int r = 0; r < 4; ++r)
              if (c > q0r + r) sacc[mi][ni][r] = -1e30f;
          }
        }
      }

      // online softmax with defer-max (T13, THR=8)
      float mx_[2][4];
      bool big = false;
#pragma unroll
      for (int mi = 0; mi < 2; ++mi)
#pragma unroll
        for (int r = 0; r < 4; ++r) {
          float mx = fmaxf(fmaxf(sacc[mi][0][r], sacc[mi][1][r]),
                           fmaxf(sacc[mi][2][r], sacc[mi][3][r]));
          mx = fmaxf(mx, __shfl_xor(mx, 1, 64));
          mx = fmaxf(mx, __shfl_xor(mx, 2, 64));
          mx = fmaxf(mx, __shfl_xor(mx, 4, 64));
          mx = fmaxf(mx, __shfl_xor(mx, 8, 64));
          mx_[mi][r] = mx;
          big = big || (mx > mrow[mi][r] + 8.0f);
        }
      if (__any((int)big)) {  // rescale path (always taken on first live tile)
#pragma unroll
        for (int mi = 0; mi < 2; ++mi)
#pragma unroll
          for (int r = 0; r < 4; ++r) {
            float mnew = fmaxf(mrow[mi][r], mx_[mi][r]);
            float corr = __expf(mrow[mi][r] - mnew);
            mrow[mi][r] = mnew;
            lrow[mi][r] *= corr;
#pragma unroll
            for (int ni = 0; ni < 8; ++ni) Oa[mi][ni][r] *= corr;
          }
      }
#pragma unroll
      for (int mi = 0; mi < 2; ++mi)
#pragma unroll
        for (int r = 0; r < 4; ++r) {
          float rs = 0.0f;
#pragma unroll
          for (int ni = 0; ni < 4; ++ni) {
            float p = __expf(sacc[mi][ni][r] - mrow[mi][r]);  // bounded by e^8
            sacc[mi][ni][r] = p;
            rs += p;
          }
          lrow[mi][r] += rs;
        }

      // P (C-layout) -> per-wave LDS (swizzled) -> A-layout frags
#pragma unroll
      for (int mi = 0; mi < 2; ++mi)
#pragma unroll
        for (int ni = 0; ni < 4; ++ni)
#pragma unroll
          for (int r = 0; r < 4; ++r) {
            int row = mi * 16 + lm * 4 + r;
            int bo = (row * 128 + (ni * 16 + ln) * 2) ^ ((row & 7) << 4);
            *reinterpret_cast<__bf16*>(pw + bo) = (__bf16)sacc[mi][ni][r];
          }

      asm volatile("s_waitcnt lgkmcnt(0)" ::: "memory");
      __builtin_amdgcn_sched_barrier(0);

      // O += P V : M=32(q) N=128(d) K=64(kv)
#pragma unroll
      for (int kf = 0; kf < 2; ++kf) {
        bf16x8 pfr[2], vfr[8];
#pragma unroll
        for (int mi = 0; mi < 2; ++mi) {
          int row = mi * 16 + ln;
          int ch = (kf * 4 + lm) ^ (row & 7);
          pfr[mi] = *reinterpret_cast<const bf16x8*>(pw + row * 128 + ch * 16);
        }
#pragma unroll
        for (int ni = 0; ni < 8; ++ni) {
          int row = ni * 16 + ln;
          int ch = (kf * 4 + lm) ^ (row & 7);
          vfr[ni] = *reinterpret_cast<const bf16x8*>(Vb + row * 128 + ch * 16);
        }
        __builtin_amdgcn_s_setprio(1);
#pragma unroll
        for (int mi = 0; mi < 2; ++mi)
#pragma unroll
          for (int ni = 0; ni < 8; ++ni)
            Oa[mi][ni] = mfma16(pfr[mi], vfr[ni], Oa[mi][ni]);
        __builtin_amdgcn_s_setprio(0);
      }
    }

    // ---- tile boundary: counted waits, never drain mid-loop ----
    asm volatile("s_waitcnt lgkmcnt(0)" ::: "memory");
    __builtin_amdgcn_s_barrier();            // all waves done reading buf[cur]
    __builtin_amdgcn_sched_barrier(0);       // keep stage below the barrier (WAR)
    if (kt + 2 <= ktEnd) stage(kt + 2);      // into buf[cur], freed above
    if (kt + 1 <= ktEnd) {
      if (kt + 2 <= ktEnd)
        asm volatile("s_waitcnt vmcnt(8)" ::: "memory");  // kt+1 landed
      else
        asm volatile("s_waitcnt vmcnt(0)" ::: "memory");  // ~2 tiles old: free
      __builtin_amdgcn_s_barrier();
      __builtin_amdgcn_sched_barrier(0);
    }
  }

  // finish: reduce row sums across 16 lanes, normalize, write merged z
#pragma unroll
  for (int mi = 0; mi < 2; ++mi)
#pragma unroll
    for (int r = 0; r < 4; ++r) {
      float ls = lrow[mi][r];
      ls += __shfl_xor(ls, 1, 64);
      ls += __shfl_xor(ls, 2, 64);
      ls += __shfl_xor(ls, 4, 64);
      ls += __shfl_xor(ls, 8, 64);
      lrow[mi][r] = 1.0f / ls;
    }
  const int b = bh >> 4, h = bh & 15;
#pragma unroll
  for (int mi = 0; mi < 2; ++mi)
#pragma unroll
    for (int ni = 0; ni < 8; ++ni) {
      int d = ni * 16 + ln;
#pragma unroll
      for (int r = 0; r < 4; ++r) {
        int qrow = qw + mi * 16 + lm * 4 + r;
        zb[(size_t)(b * S + qrow) * F + h * D + d] = (__bf16)(Oa[mi][ni][r] * lrow[mi][r]);
      }
    }
}

// ---------------- launch ----------------
extern "C" void kernel_launch(void* const* d_in, const int* in_sizes, int n_in,
                              void* d_out, int out_size, void* d_ws, size_t ws_size,
                              hipStream_t stream) {
  const float* x = (const float*)d_in[0];
  // d_in[1] = causal mask (implemented analytically)
  const float* w_attn = (const float*)d_in[2];
  const float* b_attn = (const float*)d_in[3];
  const float* w_proj = (const float*)d_in[4];
  const float* b_proj = (const float*)d_in[5];
  float* out = (float*)d_out;

  char* ws = (char*)d_ws;
  __bf16* xb    = (__bf16*)(ws + 0);          // 16 MB  [4096][2048] (reused as zb)
  __bf16* wqkv  = (__bf16*)(ws + 16777216);   // 24 MB  [6144][2048] (W^T)
  __bf16* wpro  = (__bf16*)(ws + 41943040);   //  8 MB  [2048][2048] (W^T)
  __bf16* qb    = (__bf16*)(ws + 50331648);   // 16 MB  [bh][s][d]
  __bf16* kb    = (__bf16*)(ws + 67108864);   // 16 MB  [bh][s][d]
  __bf16* vtb   = (__bf16*)(ws + 83886080);   // 16 MB  [bh][d][s]
  __bf16* zb    = xb;  // x fully consumed by QKV GEMM before attention writes z

  (void)hipFuncSetAttribute((const void*)k_gp<128, 384, 4, 0>,
                            hipFuncAttributeMaxDynamicSharedMemorySize, 131072);
  (void)hipFuncSetAttribute((const void*)k_gp<128, 256, 3, 1>,
                            hipFuncAttributeMaxDynamicSharedMemorySize, 98304);
  (void)hipFuncSetAttribute((const void*)k_attn,
                            hipFuncAttributeMaxDynamicSharedMemorySize, 81920);

  k_cvt<<<8192, 256, 0, stream>>>(x, xb);
  k_transpose<<<dim3(96, 32), 256, 0, stream>>>(w_attn, wqkv, 2048, 6144);
  k_transpose<<<dim3(32, 32), 256, 0, stream>>>(w_proj, wpro, 2048, 2048);
  // QKV: M=4096 (32 x 128), N=6144 (16 x 384) -> 512 blocks = 2 exact rounds @ 1/CU
  k_gp<128, 384, 4, 0><<<512, 512, 131072, stream>>>(xb, wqkv, b_attn, qb, kb, vtb, nullptr);
  // attention: 512 blocks (complementary-qt balance + XCD affinity inside)
  k_attn<<<512, 256, 81920, stream>>>(qb, kb, vtb, zb);
  // out-proj: M=4096 (32 x 128), N=2048 (8 x 256) -> 256 blocks = 1/CU exact
  k_gp<128, 256, 3, 1><<<256, 512, 98304, stream>>>(zb, wpro, b_proj, nullptr, nullptr, nullptr, out);
}

// Round 16
// 237.121 us; speedup vs baseline: 1.6305x; 1.1085x over previous
//
#include <hip/hip_runtime.h>
#include <hip/hip_bf16.h>
#include <stdint.h>

typedef __attribute__((ext_vector_type(8))) __bf16 bf16x8;
typedef __attribute__((ext_vector_type(4))) __bf16 bf16x4;
typedef __attribute__((ext_vector_type(4))) float f32x4;

#define DEV __device__ __forceinline__

static constexpr int S = 2048, F = 2048, H = 16, D = 128;
static constexpr int KDIM = F;            // 2048
static constexpr float QSCALE = 0.08838834764831845f;  // 1/sqrt(128)

DEV void gll16(const void* g, void* l) {
  __builtin_amdgcn_global_load_lds(
      (const __attribute__((address_space(1))) void*)g,
      (__attribute__((address_space(3))) void*)l, 16, 0, 0);
}

DEV f32x4 mfma16(bf16x8 a, bf16x8 b, f32x4 c) {
  return __builtin_amdgcn_mfma_f32_16x16x32_bf16(a, b, c, 0, 0, 0);
}

extern __shared__ char smem[];

// ---------------- fused prep: x->bf16 cvt + both weight transposes ----------------
// blocks [0,8192): cvt x; [8192,11264): transpose w_attn (96x32); rest: w_proj (32x32)
__global__ void k_prep(const float* __restrict__ x, __bf16* __restrict__ xb,
                       const float* __restrict__ wa, __bf16* __restrict__ wat,
                       const float* __restrict__ wp, __bf16* __restrict__ wpt) {
  __shared__ float t[64][65];
  const int bid = blockIdx.x;
  if (bid < 8192) {
    int i = bid * 256 + threadIdx.x;
    float4 v = reinterpret_cast<const float4*>(x)[i];
    bf16x4 o = {(__bf16)v.x, (__bf16)v.y, (__bf16)v.z, (__bf16)v.w};
    reinterpret_cast<bf16x4*>(xb)[i] = o;
    return;
  }
  const float* in;
  __bf16* out;
  int rows, cols, c0, r0;
  if (bid < 11264) {
    int tb = bid - 8192;
    in = wa; out = wat; rows = 2048; cols = 6144;
    c0 = (tb % 96) * 64; r0 = (tb / 96) * 64;
  } else {
    int tb = bid - 11264;
    in = wp; out = wpt; rows = 2048; cols = 2048;
    c0 = (tb % 32) * 64; r0 = (tb / 32) * 64;
  }
  const int tx = threadIdx.x & 63, ty = threadIdx.x >> 6;
#pragma unroll
  for (int i = 0; i < 64; i += 4)
    t[ty + i][tx] = in[(size_t)(r0 + ty + i) * cols + c0 + tx];
  __syncthreads();
#pragma unroll
  for (int i = 0; i < 64; i += 4)
    out[(size_t)(c0 + ty + i) * rows + r0 + tx] = (__bf16)t[tx][ty + i];
}

// ================= pipelined GEMM: BMxBN tile, BK=64, dbuf + counted vmcnt =========
// (r9/r10 structure — best measured QKV: 113.8 us, tail-free 512 blocks)
template <int BM, int BN, int NBXL, int EPI>
__global__ __launch_bounds__(512, 1) void k_gp(
    const __bf16* __restrict__ A, const __bf16* __restrict__ Bt,
    const float* __restrict__ bias,
    __bf16* __restrict__ qo, __bf16* __restrict__ ko, __bf16* __restrict__ vo,
    float* __restrict__ fo) {
  constexpr int MF = BM / 32;
  constexpr int NF = BN / 64;
  constexpr int NH = NF / 2;
  constexpr int NLA = BM / 64;
  constexpr int NLB = BN / 64;
  constexpr int NL = NLA + NLB;
  constexpr int AOFF = BM * 128;
  constexpr int BUFSZ = (BM + BN) * 128;
  constexpr int NT = KDIM / 64;

  const int tid = threadIdx.x;
  const int lane = tid & 63, wid = tid >> 6;
  const int wm = wid >> 2, wn = wid & 3;
  const int ln = lane & 15, lm = lane >> 4;

  const int q8 = gridDim.x >> 3;
  const int lin = (blockIdx.x & 7) * q8 + (blockIdx.x >> 3);
  const int by = lin >> NBXL, bx = lin & ((1 << NBXL) - 1);
  const int mBase = by * BM, nBase = bx * BN;

  const int r0 = tid >> 3, cc = tid & 7;
  const int src0 = r0 * KDIM + ((cc ^ (r0 & 7)) << 3);
  const __bf16* Ab = A + (size_t)mBase * KDIM + src0;
  const __bf16* Bb = Bt + (size_t)nBase * KDIM + src0;
  const int dstBase = wid * 1024;

  auto stage = [&](char* buf, int t) {
    const __bf16* As = Ab + t * 64;
    const __bf16* Bs = Bb + t * 64;
#pragma unroll
    for (int j = 0; j < NLA; ++j)
      gll16(As + (size_t)j * 64 * KDIM, buf + j * 8192 + dstBase);
#pragma unroll
    for (int j = 0; j < NLB; ++j)
      gll16(Bs + (size_t)j * 64 * KDIM, buf + AOFF + j * 8192 + dstBase);
  };
  auto wait_nl = [&]() {
    if constexpr (NL == 4)       asm volatile("s_waitcnt vmcnt(4)" ::: "memory");
    else if constexpr (NL == 6)  asm volatile("s_waitcnt vmcnt(6)" ::: "memory");
    else if constexpr (NL == 8)  asm volatile("s_waitcnt vmcnt(8)" ::: "memory");
    else                         asm volatile("s_waitcnt vmcnt(10)" ::: "memory");
  };

  int rA[2], rB[2];
#pragma unroll
  for (int ks = 0; ks < 2; ++ks) {
    const int slot = (ks * 4 + lm) ^ (ln & 7);
    rA[ks] = (wm * (BM / 2) + ln) * 128 + slot * 16;
    rB[ks] = AOFF + (wn * (BN / 4) + ln) * 128 + slot * 16;
  }

  f32x4 acc[MF][NF] = {};

  stage(smem, 0);
  stage(smem + BUFSZ, 1);
  wait_nl();
  __builtin_amdgcn_s_barrier();
  __builtin_amdgcn_sched_barrier(0);

  for (int t = 0; t < NT; ++t) {
    char* cb = smem + (t & 1) * BUFSZ;
    bf16x8 a0[MF], a1[MF], b0[NF], b1[NF];

#pragma unroll
    for (int mi = 0; mi < MF; ++mi)
      a0[mi] = *reinterpret_cast<const bf16x8*>(cb + rA[0] + mi * 2048);
#pragma unroll
    for (int ni = 0; ni < NH; ++ni)
      b0[ni] = *reinterpret_cast<const bf16x8*>(cb + rB[0] + ni * 2048);
#pragma unroll
    for (int ni = NH; ni < NF; ++ni)
      b0[ni] = *reinterpret_cast<const bf16x8*>(cb + rB[0] + ni * 2048);

    __builtin_amdgcn_s_setprio(1);
#pragma unroll
    for (int ni = 0; ni < NH; ++ni)
#pragma unroll
      for (int mi = 0; mi < MF; ++mi)
        acc[mi][ni] = mfma16(a0[mi], b0[ni], acc[mi][ni]);
    __builtin_amdgcn_s_setprio(0);

#pragma unroll
    for (int mi = 0; mi < MF; ++mi)
      a1[mi] = *reinterpret_cast<const bf16x8*>(cb + rA[1] + mi * 2048);
#pragma unroll
    for (int ni = NH; ni < NF; ++ni)
      b1[ni] = *reinterpret_cast<const bf16x8*>(cb + rB[1] + ni * 2048);

    __builtin_amdgcn_s_setprio(1);
#pragma unroll
    for (int ni = NH; ni < NF; ++ni)
#pragma unroll
      for (int mi = 0; mi < MF; ++mi)
        acc[mi][ni] = mfma16(a0[mi], b0[ni], acc[mi][ni]);
    __builtin_amdgcn_s_setprio(0);

#pragma unroll
    for (int ni = 0; ni < NH; ++ni)
      b1[ni] = *reinterpret_cast<const bf16x8*>(cb + rB[1] + ni * 2048);

    __builtin_amdgcn_s_setprio(1);
#pragma unroll
    for (int ni = NH; ni < NF; ++ni)
#pragma unroll
      for (int mi = 0; mi < MF; ++mi)
        acc[mi][ni] = mfma16(a1[mi], b1[ni], acc[mi][ni]);
    __builtin_amdgcn_s_setprio(0);

    asm volatile("s_waitcnt lgkmcnt(0)" ::: "memory");
    __builtin_amdgcn_s_barrier();
    __builtin_amdgcn_sched_barrier(0);
    if (t + 2 < NT) stage(cb, t + 2);

    __builtin_amdgcn_s_setprio(1);
#pragma unroll
    for (int ni = 0; ni < NH; ++ni)
#pragma unroll
      for (int mi = 0; mi < MF; ++mi)
        acc[mi][ni] = mfma16(a1[mi], b1[ni], acc[mi][ni]);
    __builtin_amdgcn_s_setprio(0);

    if (t + 2 < NT) {
      wait_nl();
    } else if (t + 1 < NT) {
      asm volatile("s_waitcnt vmcnt(0)" ::: "memory");
    }
    if (t + 1 < NT) {
      __builtin_amdgcn_s_barrier();
      __builtin_amdgcn_sched_barrier(0);
    }
  }

  if (EPI == 0) {
#pragma unroll
    for (int mi = 0; mi < MF; ++mi) {
      const int grow = mBase + wm * (BM / 2) + mi * 16 + lm * 4;
      const int b = grow >> 11, s0 = grow & 2047;
#pragma unroll
      for (int ni = 0; ni < NF; ++ni) {
        const int gcol = nBase + wn * (BN / 4) + ni * 16 + ln;
        const float bv = bias[gcol];
        const int sec = gcol >> 11;
        const int h = (gcol >> 7) & 15, d = gcol & 127;
        const int bh = b * H + h;
        if (sec == 0) {
#pragma unroll
          for (int r = 0; r < 4; ++r)
            qo[((size_t)bh * S + s0 + r) * D + d] = (__bf16)((acc[mi][ni][r] + bv) * QSCALE);
        } else if (sec == 1) {
#pragma unroll
          for (int r = 0; r < 4; ++r)
            ko[((size_t)bh * S + s0 + r) * D + d] = (__bf16)(acc[mi][ni][r] + bv);
        } else {
          bf16x4 pv = {(__bf16)(acc[mi][ni][0] + bv), (__bf16)(acc[mi][ni][1] + bv),
                       (__bf16)(acc[mi][ni][2] + bv), (__bf16)(acc[mi][ni][3] + bv)};
          *reinterpret_cast<bf16x4*>(vo + ((size_t)bh * D + d) * S + s0) = pv;  // V^T
        }
      }
    }
  } else {
#pragma unroll
    for (int mi = 0; mi < MF; ++mi) {
      const int grow = mBase + wm * (BM / 2) + mi * 16 + lm * 4;
#pragma unroll
      for (int ni = 0; ni < NF; ++ni) {
        const int gcol = nBase + wn * (BN / 4) + ni * 16 + ln;
        const float bv = bias[gcol];
#pragma unroll
        for (int r = 0; r < 4; ++r)
          fo[(size_t)(grow + r) * F + gcol] = acc[mi][ni][r] + bv;
      }
    }
  }
}

// ---------------- flash attention: 4 waves x 32 q-rows, KVBLK=64 ----------------
// R16: softmax fast-path. Defer-check uses LANE-LOCAL 4-col max vs mrow+8 and one
// __any ballot — zero cross-lane shuffles in the common path (the 32 ds_swizzle
// ops per tile were ~25% of attn's LDS-pipe load). Full 4-shfl row-max reduce
// runs only when the ballot fires (first live tile + rare growth). Correct since
// every row's first tile (kt=0) has live cols -> mrow is real before any fully-
// masked diag rows appear. Counted-wait tile loop (r15). 2 blocks/CU.
__global__ __launch_bounds__(256, 2) void k_attn(
    const __bf16* __restrict__ qb, const __bf16* __restrict__ kb,
    const __bf16* __restrict__ vtb, __bf16* __restrict__ zb) {
  const int lane = threadIdx.x & 63, w = threadIdx.x >> 6;
  const int lm = lane >> 4, ln = lane & 15;
  const int blk = blockIdx.x;
  const int u = blk & 255, v = blk >> 8;
  const int qt = v ? (u >> 4) : 15 - (u >> 4);
  const int bh = ((u & 15) << 1) | v;
  const int qw = qt * 128 + w * 32;

  const __bf16* qp = qb + (size_t)bh * S * D;
  const __bf16* kp = kb + (size_t)bh * S * D;
  const __bf16* vp = vtb + (size_t)bh * D * S;
  char* pw = smem + 65536 + w * 4096;

  int ksrc[4], kdst[4], vsrc[4], vdst[4];
#pragma unroll
  for (int j = 0; j < 4; ++j) {
    int c = (w * 4 + j) * 64 + lane;
    int kr = c >> 4, kps = (c & 15) ^ (kr & 7);
    ksrc[j] = kr * D + kps * 8;
    kdst[j] = (w * 4 + j) * 1024;
    int vr = c >> 3, vps = (c & 7) ^ (vr & 7);
    vsrc[j] = vr * S + vps * 8;
    vdst[j] = 16384 + (w * 4 + j) * 1024;
  }
  auto stage = [&](int kt) {
    char* buf = smem + (kt & 1) * 32768;
    const int kv = kt * 64;
#pragma unroll
    for (int j = 0; j < 4; ++j) gll16(kp + (size_t)kv * D + ksrc[j], buf + kdst[j]);
#pragma unroll
    for (int j = 0; j < 4; ++j) gll16(vp + kv + vsrc[j], buf + vdst[j]);
  };

  bf16x8 qf[2][4];
#pragma unroll
  for (int mi = 0; mi < 2; ++mi)
#pragma unroll
    for (int kf = 0; kf < 4; ++kf)
      qf[mi][kf] = *reinterpret_cast<const bf16x8*>(qp + (qw + mi * 16 + ln) * D + kf * 32 + lm * 8);

  f32x4 Oa[2][8] = {};
  float mrow[2][4], lrow[2][4];
#pragma unroll
  for (int mi = 0; mi < 2; ++mi)
#pragma unroll
    for (int r = 0; r < 4; ++r) { mrow[mi][r] = -3.0e38f; lrow[mi][r] = 0.0f; }

  const int ktEnd = 2 * qt + 1;

  stage(0);
  stage(1);
  asm volatile("s_waitcnt vmcnt(8)" ::: "memory");
  __builtin_amdgcn_s_barrier();
  __builtin_amdgcn_sched_barrier(0);

  for (int kt = 0; kt <= ktEnd; ++kt) {
    const int kv0 = kt * 64;
    const int cur = kt & 1;
    const char* Kb = smem + cur * 32768;
    const char* Vb = Kb + 16384;

    if (kv0 <= qw + 31) {
      const bool diag = (kv0 + 63 > qw);

      // S = Q K^T : M=32(q) N=64(kv) K=128(d)
      f32x4 sacc[2][4] = {};
#pragma unroll
      for (int kf = 0; kf < 4; ++kf) {
        bf16x8 kfr[4];
#pragma unroll
        for (int ni = 0; ni < 4; ++ni) {
          int row = ni * 16 + ln;
          int ch = (kf * 4 + lm) ^ (row & 7);
          kfr[ni] = *reinterpret_cast<const bf16x8*>(Kb + row * 256 + ch * 16);
        }
        __builtin_amdgcn_s_setprio(1);
#pragma unroll
        for (int mi = 0; mi < 2; ++mi)
#pragma unroll
          for (int ni = 0; ni < 4; ++ni)
            sacc[mi][ni] = mfma16(qf[mi][kf], kfr[ni], sacc[mi][ni]);
        __builtin_amdgcn_s_setprio(0);
      }

      if (diag) {
#pragma unroll
        for (int ni = 0; ni < 4; ++ni) {
          int c = kv0 + ni * 16 + ln;
#pragma unroll
          for (int mi = 0; mi < 2; ++mi) {
            int q0r = qw + mi * 16 + lm * 4;
#pragma unroll
            for (int r = 0; r < 4; ++r)
              if (c > q0r + r) sacc[mi][ni][r] = -1e30f;
          }
        }
      }

      // softmax fast-path: lane-local defer check, no shuffles in common case
      float lmax[2][4];
      bool big = false;
#pragma unroll
      for (int mi = 0; mi < 2; ++mi)
#pragma unroll
        for (int r = 0; r < 4; ++r) {
          float m4 = fmaxf(fmaxf(sacc[mi][0][r], sacc[mi][1][r]),
                           fmaxf(sacc[mi][2][r], sacc[mi][3][r]));
          lmax[mi][r] = m4;
          big = big || (m4 > mrow[mi][r] + 8.0f);
        }
      if (__any((int)big)) {  // rare: full row-max reduce + rescale
#pragma unroll
        for (int mi = 0; mi < 2; ++mi)
#pragma unroll
          for (int r = 0; r < 4; ++r) {
            float mx = lmax[mi][r];
            mx = fmaxf(mx, __shfl_xor(mx, 1, 64));
            mx = fmaxf(mx, __shfl_xor(mx, 2, 64));
            mx = fmaxf(mx, __shfl_xor(mx, 4, 64));
            mx = fmaxf(mx, __shfl_xor(mx, 8, 64));
            float mnew = fmaxf(mrow[mi][r], mx);
            float corr = __expf(mrow[mi][r] - mnew);
            mrow[mi][r] = mnew;
            lrow[mi][r] *= corr;
#pragma unroll
            for (int ni = 0; ni < 8; ++ni) Oa[mi][ni][r] *= corr;
          }
      }
#pragma unroll
      for (int mi = 0; mi < 2; ++mi)
#pragma unroll
        for (int r = 0; r < 4; ++r) {
          float rs = 0.0f;
#pragma unroll
          for (int ni = 0; ni < 4; ++ni) {
            float p = __expf(sacc[mi][ni][r] - mrow[mi][r]);  // bounded by e^8
            sacc[mi][ni][r] = p;
            rs += p;
          }
          lrow[mi][r] += rs;  // lane-partial; reduced once at the end
        }

      // P (C-layout) -> per-wave LDS (swizzled) -> A-layout frags
#pragma unroll
      for (int mi = 0; mi < 2; ++mi)
#pragma unroll
        for (int ni = 0; ni < 4; ++ni)
#pragma unroll
          for (int r = 0; r < 4; ++r) {
            int row = mi * 16 + lm * 4 + r;
            int bo = (row * 128 + (ni * 16 + ln) * 2) ^ ((row & 7) << 4);
            *reinterpret_cast<__bf16*>(pw + bo) = (__bf16)sacc[mi][ni][r];
          }

      asm volatile("s_waitcnt lgkmcnt(0)" ::: "memory");
      __builtin_amdgcn_sched_barrier(0);

      // O += P V : M=32(q) N=128(d) K=64(kv)
#pragma unroll
      for (int kf = 0; kf < 2; ++kf) {
        bf16x8 pfr[2], vfr[8];
#pragma unroll
        for (int mi = 0; mi < 2; ++mi) {
          int row = mi * 16 + ln;
          int ch = (kf * 4 + lm) ^ (row & 7);
          pfr[mi] = *reinterpret_cast<const bf16x8*>(pw + row * 128 + ch * 16);
        }
#pragma unroll
        for (int ni = 0; ni < 8; ++ni) {
          int row = ni * 16 + ln;
          int ch = (kf * 4 + lm) ^ (row & 7);
          vfr[ni] = *reinterpret_cast<const bf16x8*>(Vb + row * 128 + ch * 16);
        }
        __builtin_amdgcn_s_setprio(1);
#pragma unroll
        for (int mi = 0; mi < 2; ++mi)
#pragma unroll
          for (int ni = 0; ni < 8; ++ni)
            Oa[mi][ni] = mfma16(pfr[mi], vfr[ni], Oa[mi][ni]);
        __builtin_amdgcn_s_setprio(0);
      }
    }

    // ---- tile boundary: counted waits, never drain mid-loop ----
    asm volatile("s_waitcnt lgkmcnt(0)" ::: "memory");
    __builtin_amdgcn_s_barrier();
    __builtin_amdgcn_sched_barrier(0);
    if (kt + 2 <= ktEnd) stage(kt + 2);
    if (kt + 1 <= ktEnd) {
      if (kt + 2 <= ktEnd)
        asm volatile("s_waitcnt vmcnt(8)" ::: "memory");
      else
        asm volatile("s_waitcnt vmcnt(0)" ::: "memory");
      __builtin_amdgcn_s_barrier();
      __builtin_amdgcn_sched_barrier(0);
    }
  }

  // finish: reduce row sums across 16 lanes, normalize, write merged z
#pragma unroll
  for (int mi = 0; mi < 2; ++mi)
#pragma unroll
    for (int r = 0; r < 4; ++r) {
      float ls = lrow[mi][r];
      ls += __shfl_xor(ls, 1, 64);
      ls += __shfl_xor(ls, 2, 64);
      ls += __shfl_xor(ls, 4, 64);
      ls += __shfl_xor(ls, 8, 64);
      lrow[mi][r] = 1.0f / ls;
    }
  const int b = bh >> 4, h = bh & 15;
#pragma unroll
  for (int mi = 0; mi < 2; ++mi)
#pragma unroll
    for (int ni = 0; ni < 8; ++ni) {
      int d = ni * 16 + ln;
#pragma unroll
      for (int r = 0; r < 4; ++r) {
        int qrow = qw + mi * 16 + lm * 4 + r;
        zb[(size_t)(b * S + qrow) * F + h * D + d] = (__bf16)(Oa[mi][ni][r] * lrow[mi][r]);
      }
    }
}

// ---------------- launch ----------------
extern "C" void kernel_launch(void* const* d_in, const int* in_sizes, int n_in,
                              void* d_out, int out_size, void* d_ws, size_t ws_size,
                              hipStream_t stream) {
  const float* x = (const float*)d_in[0];
  // d_in[1] = causal mask (implemented analytically)
  const float* w_attn = (const float*)d_in[2];
  const float* b_attn = (const float*)d_in[3];
  const float* w_proj = (const float*)d_in[4];
  const float* b_proj = (const float*)d_in[5];
  float* out = (float*)d_out;

  char* ws = (char*)d_ws;
  __bf16* xb    = (__bf16*)(ws + 0);          // 16 MB  [4096][2048] (reused as zb)
  __bf16* wqkv  = (__bf16*)(ws + 16777216);   // 24 MB  [6144][2048] (W^T)
  __bf16* wpro  = (__bf16*)(ws + 41943040);   //  8 MB  [2048][2048] (W^T)
  __bf16* qb    = (__bf16*)(ws + 50331648);   // 16 MB  [bh][s][d]
  __bf16* kb    = (__bf16*)(ws + 67108864);   // 16 MB  [bh][s][d]
  __bf16* vtb   = (__bf16*)(ws + 83886080);   // 16 MB  [bh][d][s]
  __bf16* zb    = xb;  // x fully consumed by QKV GEMM before attention writes z

  (void)hipFuncSetAttribute((const void*)k_gp<128, 384, 4, 0>,
                            hipFuncAttributeMaxDynamicSharedMemorySize, 131072);
  (void)hipFuncSetAttribute((const void*)k_gp<128, 256, 3, 1>,
                            hipFuncAttributeMaxDynamicSharedMemorySize, 98304);
  (void)hipFuncSetAttribute((const void*)k_attn,
                            hipFuncAttributeMaxDynamicSharedMemorySize, 81920);

  // fused prep: 8192 cvt + 3072 w_attn-transpose + 1024 w_proj-transpose
  k_prep<<<12288, 256, 0, stream>>>(x, xb, w_attn, wqkv, w_proj, wpro);
  // QKV: M=4096 (32 x 128), N=6144 (16 x 384) -> 512 blocks = 2 exact rounds @ 1/CU
  k_gp<128, 384, 4, 0><<<512, 512, 131072, stream>>>(xb, wqkv, b_attn, qb, kb, vtb, nullptr);
  // attention: 512 blocks (complementary-qt balance + XCD affinity inside)
  k_attn<<<512, 256, 81920, stream>>>(qb, kb, vtb, zb);
  // out-proj: M=4096 (32 x 128), N=2048 (8 x 256) -> 256 blocks = 1/CU exact
  k_gp<128, 256, 3, 1><<<256, 512, 98304, stream>>>(zb, wpro, b_proj, nullptr, nullptr, nullptr, out);
}

// Round 17
// 235.361 us; speedup vs baseline: 1.6427x; 1.0075x over previous
//
#include <hip/hip_runtime.h>
#include <hip/hip_bf16.h>
#include <stdint.h>

typedef __attribute__((ext_vector_type(8))) __bf16 bf16x8;
typedef __attribute__((ext_vector_type(4))) __bf16 bf16x4;
typedef __attribute__((ext_vector_type(4))) float f32x4;

#define DEV __device__ __forceinline__

static constexpr int S = 2048, F = 2048, H = 16, D = 128;
static constexpr int KDIM = F;            // 2048
static constexpr float QSCALE = 0.08838834764831845f;  // 1/sqrt(128)

DEV void gll16(const void* g, void* l) {
  __builtin_amdgcn_global_load_lds(
      (const __attribute__((address_space(1))) void*)g,
      (__attribute__((address_space(3))) void*)l, 16, 0, 0);
}

DEV f32x4 mfma16(bf16x8 a, bf16x8 b, f32x4 c) {
  return __builtin_amdgcn_mfma_f32_16x16x32_bf16(a, b, c, 0, 0, 0);
}

extern __shared__ char smem[];

#define QBAR()  __builtin_amdgcn_s_barrier()
#define QLGKM() asm volatile("s_waitcnt lgkmcnt(0)" ::: "memory")
#define QSCB()  __builtin_amdgcn_sched_barrier(0)

// ---------------- fused prep: x->bf16 cvt + both weight transposes ----------------
__global__ void k_prep(const float* __restrict__ x, __bf16* __restrict__ xb,
                       const float* __restrict__ wa, __bf16* __restrict__ wat,
                       const float* __restrict__ wp, __bf16* __restrict__ wpt) {
  __shared__ float t[64][65];
  const int bid = blockIdx.x;
  if (bid < 8192) {
    int i = bid * 256 + threadIdx.x;
    float4 v = reinterpret_cast<const float4*>(x)[i];
    bf16x4 o = {(__bf16)v.x, (__bf16)v.y, (__bf16)v.z, (__bf16)v.w};
    reinterpret_cast<bf16x4*>(xb)[i] = o;
    return;
  }
  const float* in;
  __bf16* out;
  int rows, cols, c0, r0;
  if (bid < 11264) {
    int tb = bid - 8192;
    in = wa; out = wat; rows = 2048; cols = 6144;
    c0 = (tb % 96) * 64; r0 = (tb / 96) * 64;
  } else {
    int tb = bid - 11264;
    in = wp; out = wpt; rows = 2048; cols = 2048;
    c0 = (tb % 32) * 64; r0 = (tb / 32) * 64;
  }
  const int tx = threadIdx.x & 63, ty = threadIdx.x >> 6;
#pragma unroll
  for (int i = 0; i < 64; i += 4)
    t[ty + i][tx] = in[(size_t)(r0 + ty + i) * cols + c0 + tx];
  __syncthreads();
#pragma unroll
  for (int i = 0; i < 64; i += 4)
    out[(size_t)(c0 + ty + i) * rows + r0 + tx] = (__bf16)t[tx][ty + i];
}

// ================= QKV: 8-phase barrier-dense GEMM, 128x384 tile, BK=64 ==========
// r2/r14 evidence: barrier-dense phases (each: reads | 2-load stage | barrier |
// lgkm(0) | MFMA quadrant | [counted vmcnt] | barrier) hit ~44-45% intrinsic
// MfmaUtil vs 36-38% for loose 4-phase — but both ran 1.5-round grids. This
// ports that structure to the tail-free 128x384 tile (512 blocks = 2 rounds).
// 8 waves (2M x 4N), wave tile 64x96, acc[4][6] (96 AGPR). LDS 128 KiB =
// 2 bufs x {A[128][64] @0 (2 loads), B[384][64] @16K (6 loads)}, chunk-XOR swz.
// Iteration = 2 tiles (tL=2i buf0, tR=2i+1 buf1), 8 phases; quadrant order per
// tile: (ks0,Blo),(ks0,Bhi),(ks1,Bhi),(ks1,Blo) — consecutive disjoint acc cols.
// Stage slots (WAR: region's last read >=1 barrier earlier):
//   q0-q2: B(tR) pairs [R-B last read prev q7]   q3: A(tN)   [L-A last read q2]
//   q4-q6: B(tN) pairs [L-B last read q3]        q7: A(tN+1) [R-A last read q6]
// Counted waits: end-q3 vmcnt(2) => tR landed (newer: q3's 2 A-loads);
// end-q7 vmcnt(2) => tN landed (newer: q7's 2). Never drains mid-loop.
__global__ __launch_bounds__(512, 1) void k_qkv8p(
    const __bf16* __restrict__ A, const __bf16* __restrict__ Bt,
    const float* __restrict__ bias,
    __bf16* __restrict__ qo, __bf16* __restrict__ ko, __bf16* __restrict__ vo) {
  constexpr int NT = 32;
  const int tid = threadIdx.x;
  const int lane = tid & 63, wid = tid >> 6;
  const int wm = wid >> 2, wn = wid & 3;
  const int ln = lane & 15, lm = lane >> 4;

  // XCD swizzle over 512 blocks
  const int lin = (blockIdx.x & 7) * 64 + (blockIdx.x >> 3);
  const int by = lin >> 4, bx = lin & 15;
  const int mBase = by * 128, nBase = bx * 384;

  const int r0 = tid >> 3, cc = tid & 7;
  const int src0 = r0 * KDIM + ((cc ^ (r0 & 7)) << 3);
  const __bf16* Ab = A + (size_t)mBase * KDIM + src0;
  const __bf16* Bb = Bt + (size_t)nBase * KDIM + src0;
  const int sDst = wid * 1024;

  auto stA2 = [&](int t) {  // both A loads of tile t
    char* d = smem + (t & 1) * 65536 + sDst;
    const __bf16* s = Ab + t * 64;
    gll16(s, d);
    gll16(s + (size_t)64 * KDIM, d + 8192);
  };
  auto stB2 = [&](int t, int j) {  // B loads j, j+1 of tile t
    char* d = smem + (t & 1) * 65536 + 16384 + j * 8192 + sDst;
    const __bf16* s = Bb + (size_t)j * 64 * KDIM + t * 64;
    gll16(s, d);
    gll16(s + (size_t)64 * KDIM, d + 8192);
  };

  int rA[2], rB[2];
#pragma unroll
  for (int ks = 0; ks < 2; ++ks) {
    const int slot = (ks * 4 + lm) ^ (ln & 7);
    rA[ks] = (wm * 64 + ln) * 128 + slot * 16;
    rB[ks] = 16384 + (wn * 96 + ln) * 128 + slot * 16;
  }
  auto rdA = [&](bf16x8 (&a)[4], const char* cb, int ks) {
#pragma unroll
    for (int mi = 0; mi < 4; ++mi)
      a[mi] = *reinterpret_cast<const bf16x8*>(cb + rA[ks] + mi * 2048);
  };
  auto rdBh = [&](bf16x8 (&b)[3], const char* cb, int ks, int h) {
#pragma unroll
    for (int k = 0; k < 3; ++k)
      b[k] = *reinterpret_cast<const bf16x8*>(cb + rB[ks] + (h * 3 + k) * 2048);
  };

  f32x4 acc[4][6] = {};
  auto mm = [&](const bf16x8 (&a)[4], const bf16x8 (&b)[3], int h) {
#pragma unroll
    for (int k = 0; k < 3; ++k)
#pragma unroll
      for (int mi = 0; mi < 4; ++mi)
        acc[mi][h * 3 + k] = mfma16(a[mi], b[k], acc[mi][h * 3 + k]);
  };

  // prologue: t0 full (8) + t1-A (2); vmcnt(2) => t0 landed
  stA2(0); stB2(0, 0); stB2(0, 2); stB2(0, 4); stA2(1);
  asm volatile("s_waitcnt vmcnt(2)" ::: "memory");
  QBAR(); QSCB();

  for (int i = 0; i < 16; ++i) {
    const char* L = smem;
    const char* R = smem + 65536;
    const int tR = 2 * i + 1, tN = 2 * i + 2, tN1 = 2 * i + 3;
    const bool last = (i == 15);
    bf16x8 a[4], b[3];

    // ---- q0: tL (ks0, Blo); stage B(tR) 0-1 ----
    rdA(a, L, 0); rdBh(b, L, 0, 0);
    stB2(tR, 0);
    QBAR(); QLGKM(); QSCB();
    __builtin_amdgcn_s_setprio(1); mm(a, b, 0); __builtin_amdgcn_s_setprio(0);
    QBAR(); QSCB();
    // ---- q1: (ks0, Bhi); stage B(tR) 2-3 ----
    rdBh(b, L, 0, 1);
    stB2(tR, 2);
    QBAR(); QLGKM(); QSCB();
    __builtin_amdgcn_s_setprio(1); mm(a, b, 1); __builtin_amdgcn_s_setprio(0);
    QBAR(); QSCB();
    // ---- q2: (ks1, Bhi); stage B(tR) 4-5 ----
    rdA(a, L, 1); rdBh(b, L, 1, 1);
    stB2(tR, 4);
    QBAR(); QLGKM(); QSCB();
    __builtin_amdgcn_s_setprio(1); mm(a, b, 1); __builtin_amdgcn_s_setprio(0);
    QBAR(); QSCB();
    // ---- q3: (ks1, Blo); stage A(tN); vmcnt(2) => tR landed ----
    rdBh(b, L, 1, 0);
    if (!last) stA2(tN);
    QBAR(); QLGKM(); QSCB();
    __builtin_amdgcn_s_setprio(1); mm(a, b, 0); __builtin_amdgcn_s_setprio(0);
    if (last) asm volatile("s_waitcnt vmcnt(0)" ::: "memory");
    else      asm volatile("s_waitcnt vmcnt(2)" ::: "memory");
    QBAR(); QSCB();

    // ---- q4: tR (ks0, Blo); stage B(tN) 0-1 ----
    rdA(a, R, 0); rdBh(b, R, 0, 0);
    if (!last) stB2(tN, 0);
    QBAR(); QLGKM(); QSCB();
    __builtin_amdgcn_s_setprio(1); mm(a, b, 0); __builtin_amdgcn_s_setprio(0);
    QBAR(); QSCB();
    // ---- q5: (ks0, Bhi); stage B(tN) 2-3 ----
    rdBh(b, R, 0, 1);
    if (!last) stB2(tN, 2);
    QBAR(); QLGKM(); QSCB();
    __builtin_amdgcn_s_setprio(1); mm(a, b, 1); __builtin_amdgcn_s_setprio(0);
    QBAR(); QSCB();
    // ---- q6: (ks1, Bhi); stage B(tN) 4-5 ----
    rdA(a, R, 1); rdBh(b, R, 1, 1);
    if (!last) stB2(tN, 4);
    QBAR(); QLGKM(); QSCB();
    __builtin_amdgcn_s_setprio(1); mm(a, b, 1); __builtin_amdgcn_s_setprio(0);
    QBAR(); QSCB();
    // ---- q7: (ks1, Blo); stage A(tN1); vmcnt(2) => tN landed ----
    rdBh(b, R, 1, 0);
    if (tN1 < NT) stA2(tN1);
    QBAR(); QLGKM(); QSCB();
    __builtin_amdgcn_s_setprio(1); mm(a, b, 0); __builtin_amdgcn_s_setprio(0);
    if (!last) {
      asm volatile("s_waitcnt vmcnt(2)" ::: "memory");
      QBAR(); QSCB();
    }
  }

  // epilogue: route Q (scaled), K, V^T; sec per 16-col group
#pragma unroll
  for (int mi = 0; mi < 4; ++mi) {
    const int grow = mBase + wm * 64 + mi * 16 + lm * 4;
    const int b = grow >> 11, s0 = grow & 2047;
#pragma unroll
    for (int ni = 0; ni < 6; ++ni) {
      const int gcol = nBase + wn * 96 + ni * 16 + ln;
      const float bv = bias[gcol];
      const int sec = gcol >> 11;
      const int h = (gcol >> 7) & 15, d = gcol & 127;
      const int bh = b * H + h;
      if (sec == 0) {
#pragma unroll
        for (int r = 0; r < 4; ++r)
          qo[((size_t)bh * S + s0 + r) * D + d] = (__bf16)((acc[mi][ni][r] + bv) * QSCALE);
      } else if (sec == 1) {
#pragma unroll
        for (int r = 0; r < 4; ++r)
          ko[((size_t)bh * S + s0 + r) * D + d] = (__bf16)(acc[mi][ni][r] + bv);
      } else {
        bf16x4 pv = {(__bf16)(acc[mi][ni][0] + bv), (__bf16)(acc[mi][ni][1] + bv),
                     (__bf16)(acc[mi][ni][2] + bv), (__bf16)(acc[mi][ni][3] + bv)};
        *reinterpret_cast<bf16x4*>(vo + ((size_t)bh * D + d) * S + s0) = pv;  // V^T
      }
    }
  }
}

// ================= out-proj: 128x256 pipelined GEMM (r10 structure) =================
__global__ __launch_bounds__(512, 1) void k_proj(
    const __bf16* __restrict__ A, const __bf16* __restrict__ Bt,
    const float* __restrict__ bias, float* __restrict__ fo) {
  constexpr int BM = 128, BN = 256;
  constexpr int MF = 4, NF = 4, NH = 2;
  constexpr int AOFF = BM * 128;
  constexpr int BUFSZ = (BM + BN) * 128;
  constexpr int NT = KDIM / 64;

  const int tid = threadIdx.x;
  const int lane = tid & 63, wid = tid >> 6;
  const int wm = wid >> 2, wn = wid & 3;
  const int ln = lane & 15, lm = lane >> 4;

  const int lin = (blockIdx.x & 7) * 32 + (blockIdx.x >> 3);
  const int by = lin >> 3, bx = lin & 7;
  const int mBase = by * BM, nBase = bx * BN;

  const int r0 = tid >> 3, cc = tid & 7;
  const int src0 = r0 * KDIM + ((cc ^ (r0 & 7)) << 3);
  const __bf16* Ab = A + (size_t)mBase * KDIM + src0;
  const __bf16* Bb = Bt + (size_t)nBase * KDIM + src0;
  const int dstBase = wid * 1024;

  auto stage = [&](char* buf, int t) {
    const __bf16* As = Ab + t * 64;
    const __bf16* Bs = Bb + t * 64;
#pragma unroll
    for (int j = 0; j < 2; ++j)
      gll16(As + (size_t)j * 64 * KDIM, buf + j * 8192 + dstBase);
#pragma unroll
    for (int j = 0; j < 4; ++j)
      gll16(Bs + (size_t)j * 64 * KDIM, buf + AOFF + j * 8192 + dstBase);
  };

  int rA[2], rB[2];
#pragma unroll
  for (int ks = 0; ks < 2; ++ks) {
    const int slot = (ks * 4 + lm) ^ (ln & 7);
    rA[ks] = (wm * 64 + ln) * 128 + slot * 16;
    rB[ks] = AOFF + (wn * 64 + ln) * 128 + slot * 16;
  }

  f32x4 acc[MF][NF] = {};

  stage(smem, 0);
  stage(smem + BUFSZ, 1);
  asm volatile("s_waitcnt vmcnt(6)" ::: "memory");
  QBAR(); QSCB();

  for (int t = 0; t < NT; ++t) {
    char* cb = smem + (t & 1) * BUFSZ;
    bf16x8 a0[MF], a1[MF], b0[NF], b1[NF];

#pragma unroll
    for (int mi = 0; mi < MF; ++mi)
      a0[mi] = *reinterpret_cast<const bf16x8*>(cb + rA[0] + mi * 2048);
#pragma unroll
    for (int ni = 0; ni < NF; ++ni)
      b0[ni] = *reinterpret_cast<const bf16x8*>(cb + rB[0] + ni * 2048);

    __builtin_amdgcn_s_setprio(1);
#pragma unroll
    for (int ni = 0; ni < NH; ++ni)
#pragma unroll
      for (int mi = 0; mi < MF; ++mi)
        acc[mi][ni] = mfma16(a0[mi], b0[ni], acc[mi][ni]);
    __builtin_amdgcn_s_setprio(0);

#pragma unroll
    for (int mi = 0; mi < MF; ++mi)
      a1[mi] = *reinterpret_cast<const bf16x8*>(cb + rA[1] + mi * 2048);
#pragma unroll
    for (int ni = NH; ni < NF; ++ni)
      b1[ni] = *reinterpret_cast<const bf16x8*>(cb + rB[1] + ni * 2048);

    __builtin_amdgcn_s_setprio(1);
#pragma unroll
    for (int ni = NH; ni < NF; ++ni)
#pragma unroll
      for (int mi = 0; mi < MF; ++mi)
        acc[mi][ni] = mfma16(a0[mi], b0[ni], acc[mi][ni]);
    __builtin_amdgcn_s_setprio(0);

#pragma unroll
    for (int ni = 0; ni < NH; ++ni)
      b1[ni] = *reinterpret_cast<const bf16x8*>(cb + rB[1] + ni * 2048);

    __builtin_amdgcn_s_setprio(1);
#pragma unroll
    for (int ni = NH; ni < NF; ++ni)
#pragma unroll
      for (int mi = 0; mi < MF; ++mi)
        acc[mi][ni] = mfma16(a1[mi], b1[ni], acc[mi][ni]);
    __builtin_amdgcn_s_setprio(0);

    QLGKM();
    QBAR(); QSCB();
    if (t + 2 < NT) stage(cb, t + 2);

    __builtin_amdgcn_s_setprio(1);
#pragma unroll
    for (int ni = 0; ni < NH; ++ni)
#pragma unroll
      for (int mi = 0; mi < MF; ++mi)
        acc[mi][ni] = mfma16(a1[mi], b1[ni], acc[mi][ni]);
    __builtin_amdgcn_s_setprio(0);

    if (t + 2 < NT) {
      asm volatile("s_waitcnt vmcnt(6)" ::: "memory");
    } else if (t + 1 < NT) {
      asm volatile("s_waitcnt vmcnt(0)" ::: "memory");
    }
    if (t + 1 < NT) {
      QBAR(); QSCB();
    }
  }

#pragma unroll
  for (int mi = 0; mi < MF; ++mi) {
    const int grow = mBase + wm * 64 + mi * 16 + lm * 4;
#pragma unroll
    for (int ni = 0; ni < NF; ++ni) {
      const int gcol = nBase + wn * 64 + ni * 16 + ln;
      const float bv = bias[gcol];
#pragma unroll
      for (int r = 0; r < 4; ++r)
        fo[(size_t)(grow + r) * F + gcol] = acc[mi][ni][r] + bv;
    }
  }
}

// ---------------- flash attention (r16: fast-path softmax + counted waits) --------
__global__ __launch_bounds__(256, 2) void k_attn(
    const __bf16* __restrict__ qb, const __bf16* __restrict__ kb,
    const __bf16* __restrict__ vtb, __bf16* __restrict__ zb) {
  const int lane = threadIdx.x & 63, w = threadIdx.x >> 6;
  const int lm = lane >> 4, ln = lane & 15;
  const int blk = blockIdx.x;
  const int u = blk & 255, v = blk >> 8;
  const int qt = v ? (u >> 4) : 15 - (u >> 4);
  const int bh = ((u & 15) << 1) | v;
  const int qw = qt * 128 + w * 32;

  const __bf16* qp = qb + (size_t)bh * S * D;
  const __bf16* kp = kb + (size_t)bh * S * D;
  const __bf16* vp = vtb + (size_t)bh * D * S;
  char* pw = smem + 65536 + w * 4096;

  int ksrc[4], kdst[4], vsrc[4], vdst[4];
#pragma unroll
  for (int j = 0; j < 4; ++j) {
    int c = (w * 4 + j) * 64 + lane;
    int kr = c >> 4, kps = (c & 15) ^ (kr & 7);
    ksrc[j] = kr * D + kps * 8;
    kdst[j] = (w * 4 + j) * 1024;
    int vr = c >> 3, vps = (c & 7) ^ (vr & 7);
    vsrc[j] = vr * S + vps * 8;
    vdst[j] = 16384 + (w * 4 + j) * 1024;
  }
  auto stage = [&](int kt) {
    char* buf = smem + (kt & 1) * 32768;
    const int kv = kt * 64;
#pragma unroll
    for (int j = 0; j < 4; ++j) gll16(kp + (size_t)kv * D + ksrc[j], buf + kdst[j]);
#pragma unroll
    for (int j = 0; j < 4; ++j) gll16(vp + kv + vsrc[j], buf + vdst[j]);
  };

  bf16x8 qf[2][4];
#pragma unroll
  for (int mi = 0; mi < 2; ++mi)
#pragma unroll
    for (int kf = 0; kf < 4; ++kf)
      qf[mi][kf] = *reinterpret_cast<const bf16x8*>(qp + (qw + mi * 16 + ln) * D + kf * 32 + lm * 8);

  f32x4 Oa[2][8] = {};
  float mrow[2][4], lrow[2][4];
#pragma unroll
  for (int mi = 0; mi < 2; ++mi)
#pragma unroll
    for (int r = 0; r < 4; ++r) { mrow[mi][r] = -3.0e38f; lrow[mi][r] = 0.0f; }

  const int ktEnd = 2 * qt + 1;

  stage(0);
  stage(1);
  asm volatile("s_waitcnt vmcnt(8)" ::: "memory");
  QBAR(); QSCB();

  for (int kt = 0; kt <= ktEnd; ++kt) {
    const int kv0 = kt * 64;
    const int cur = kt & 1;
    const char* Kb = smem + cur * 32768;
    const char* Vb = Kb + 16384;

    if (kv0 <= qw + 31) {
      const bool diag = (kv0 + 63 > qw);

      f32x4 sacc[2][4] = {};
#pragma unroll
      for (int kf = 0; kf < 4; ++kf) {
        bf16x8 kfr[4];
#pragma unroll
        for (int ni = 0; ni < 4; ++ni) {
          int row = ni * 16 + ln;
          int ch = (kf * 4 + lm) ^ (row & 7);
          kfr[ni] = *reinterpret_cast<const bf16x8*>(Kb + row * 256 + ch * 16);
        }
        __builtin_amdgcn_s_setprio(1);
#pragma unroll
        for (int mi = 0; mi < 2; ++mi)
#pragma unroll
          for (int ni = 0; ni < 4; ++ni)
            sacc[mi][ni] = mfma16(qf[mi][kf], kfr[ni], sacc[mi][ni]);
        __builtin_amdgcn_s_setprio(0);
      }

      if (diag) {
#pragma unroll
        for (int ni = 0; ni < 4; ++ni) {
          int c = kv0 + ni * 16 + ln;
#pragma unroll
          for (int mi = 0; mi < 2; ++mi) {
            int q0r = qw + mi * 16 + lm * 4;
#pragma unroll
            for (int r = 0; r < 4; ++r)
              if (c > q0r + r) sacc[mi][ni][r] = -1e30f;
          }
        }
      }

      float lmax[2][4];
      bool big = false;
#pragma unroll
      for (int mi = 0; mi < 2; ++mi)
#pragma unroll
        for (int r = 0; r < 4; ++r) {
          float m4 = fmaxf(fmaxf(sacc[mi][0][r], sacc[mi][1][r]),
                           fmaxf(sacc[mi][2][r], sacc[mi][3][r]));
          lmax[mi][r] = m4;
          big = big || (m4 > mrow[mi][r] + 8.0f);
        }
      if (__any((int)big)) {
#pragma unroll
        for (int mi = 0; mi < 2; ++mi)
#pragma unroll
          for (int r = 0; r < 4; ++r) {
            float mx = lmax[mi][r];
            mx = fmaxf(mx, __shfl_xor(mx, 1, 64));
            mx = fmaxf(mx, __shfl_xor(mx, 2, 64));
            mx = fmaxf(mx, __shfl_xor(mx, 4, 64));
            mx = fmaxf(mx, __shfl_xor(mx, 8, 64));
            float mnew = fmaxf(mrow[mi][r], mx);
            float corr = __expf(mrow[mi][r] - mnew);
            mrow[mi][r] = mnew;
            lrow[mi][r] *= corr;
#pragma unroll
            for (int ni = 0; ni < 8; ++ni) Oa[mi][ni][r] *= corr;
          }
      }
#pragma unroll
      for (int mi = 0; mi < 2; ++mi)
#pragma unroll
        for (int r = 0; r < 4; ++r) {
          float rs = 0.0f;
#pragma unroll
          for (int ni = 0; ni < 4; ++ni) {
            float p = __expf(sacc[mi][ni][r] - mrow[mi][r]);
            sacc[mi][ni][r] = p;
            rs += p;
          }
          lrow[mi][r] += rs;
        }

#pragma unroll
      for (int mi = 0; mi < 2; ++mi)
#pragma unroll
        for (int ni = 0; ni < 4; ++ni)
#pragma unroll
          for (int r = 0; r < 4; ++r) {
            int row = mi * 16 + lm * 4 + r;
            int bo = (row * 128 + (ni * 16 + ln) * 2) ^ ((row & 7) << 4);
            *reinterpret_cast<__bf16*>(pw + bo) = (__bf16)sacc[mi][ni][r];
          }

      QLGKM(); QSCB();

#pragma unroll
      for (int kf = 0; kf < 2; ++kf) {
        bf16x8 pfr[2], vfr[8];
#pragma unroll
        for (int mi = 0; mi < 2; ++mi) {
          int row = mi * 16 + ln;
          int ch = (kf * 4 + lm) ^ (row & 7);
          pfr[mi] = *reinterpret_cast<const bf16x8*>(pw + row * 128 + ch * 16);
        }
#pragma unroll
        for (int ni = 0; ni < 8; ++ni) {
          int row = ni * 16 + ln;
          int ch = (kf * 4 + lm) ^ (row & 7);
          vfr[ni] = *reinterpret_cast<const bf16x8*>(Vb + row * 128 + ch * 16);
        }
        __builtin_amdgcn_s_setprio(1);
#pragma unroll
        for (int mi = 0; mi < 2; ++mi)
#pragma unroll
          for (int ni = 0; ni < 8; ++ni)
            Oa[mi][ni] = mfma16(pfr[mi], vfr[ni], Oa[mi][ni]);
        __builtin_amdgcn_s_setprio(0);
      }
    }

    asm volatile("s_waitcnt lgkmcnt(0)" ::: "memory");
    QBAR(); QSCB();
    if (kt + 2 <= ktEnd) stage(kt + 2);
    if (kt + 1 <= ktEnd) {
      if (kt + 2 <= ktEnd)
        asm volatile("s_waitcnt vmcnt(8)" ::: "memory");
      else
        asm volatile("s_waitcnt vmcnt(0)" ::: "memory");
      QBAR(); QSCB();
    }
  }

#pragma unroll
  for (int mi = 0; mi < 2; ++mi)
#pragma unroll
    for (int r = 0; r < 4; ++r) {
      float ls = lrow[mi][r];
      ls += __shfl_xor(ls, 1, 64);
      ls += __shfl_xor(ls, 2, 64);
      ls += __shfl_xor(ls, 4, 64);
      ls += __shfl_xor(ls, 8, 64);
      lrow[mi][r] = 1.0f / ls;
    }
  const int b = bh >> 4, h = bh & 15;
#pragma unroll
  for (int mi = 0; mi < 2; ++mi)
#pragma unroll
    for (int ni = 0; ni < 8; ++ni) {
      int d = ni * 16 + ln;
#pragma unroll
      for (int r = 0; r < 4; ++r) {
        int qrow = qw + mi * 16 + lm * 4 + r;
        zb[(size_t)(b * S + qrow) * F + h * D + d] = (__bf16)(Oa[mi][ni][r] * lrow[mi][r]);
      }
    }
}

// ---------------- launch ----------------
extern "C" void kernel_launch(void* const* d_in, const int* in_sizes, int n_in,
                              void* d_out, int out_size, void* d_ws, size_t ws_size,
                              hipStream_t stream) {
  const float* x = (const float*)d_in[0];
  // d_in[1] = causal mask (implemented analytically)
  const float* w_attn = (const float*)d_in[2];
  const float* b_attn = (const float*)d_in[3];
  const float* w_proj = (const float*)d_in[4];
  const float* b_proj = (const float*)d_in[5];
  float* out = (float*)d_out;

  char* ws = (char*)d_ws;
  __bf16* xb    = (__bf16*)(ws + 0);          // 16 MB  [4096][2048] (reused as zb)
  __bf16* wqkv  = (__bf16*)(ws + 16777216);   // 24 MB  [6144][2048] (W^T)
  __bf16* wpro  = (__bf16*)(ws + 41943040);   //  8 MB  [2048][2048] (W^T)
  __bf16* qb    = (__bf16*)(ws + 50331648);   // 16 MB  [bh][s][d]
  __bf16* kb    = (__bf16*)(ws + 67108864);   // 16 MB  [bh][s][d]
  __bf16* vtb   = (__bf16*)(ws + 83886080);   // 16 MB  [bh][d][s]
  __bf16* zb    = xb;  // x fully consumed by QKV GEMM before attention writes z

  (void)hipFuncSetAttribute((const void*)k_qkv8p,
                            hipFuncAttributeMaxDynamicSharedMemorySize, 131072);
  (void)hipFuncSetAttribute((const void*)k_proj,
                            hipFuncAttributeMaxDynamicSharedMemorySize, 98304);
  (void)hipFuncSetAttribute((const void*)k_attn,
                            hipFuncAttributeMaxDynamicSharedMemorySize, 81920);

  // fused prep: 8192 cvt + 3072 w_attn-transpose + 1024 w_proj-transpose
  k_prep<<<12288, 256, 0, stream>>>(x, xb, w_attn, wqkv, w_proj, wpro);
  // QKV: M=4096 (32 x 128), N=6144 (16 x 384) -> 512 blocks = 2 exact rounds
  k_qkv8p<<<512, 512, 131072, stream>>>(xb, wqkv, b_attn, qb, kb, vtb);
  // attention: 512 blocks (complementary-qt balance + XCD affinity inside)
  k_attn<<<512, 256, 81920, stream>>>(qb, kb, vtb, zb);
  // out-proj: M=4096 (32 x 128), N=2048 (8 x 256) -> 256 blocks = 1/CU exact
  k_proj<<<256, 512, 98304, stream>>>(zb, wpro, b_proj, out);
}

// Round 18
// 233.416 us; speedup vs baseline: 1.6564x; 1.0083x over previous
//
#include <hip/hip_runtime.h>
#include <hip/hip_bf16.h>
#include <stdint.h>

typedef __attribute__((ext_vector_type(8))) __bf16 bf16x8;
typedef __attribute__((ext_vector_type(4))) __bf16 bf16x4;
typedef __attribute__((ext_vector_type(4))) float f32x4;

#define DEV __device__ __forceinline__

static constexpr int S = 2048, F = 2048, H = 16, D = 128;
static constexpr int KDIM = F;            // 2048
static constexpr float QSCALE = 0.08838834764831845f;  // 1/sqrt(128)

DEV void gll16(const void* g, void* l) {
  __builtin_amdgcn_global_load_lds(
      (const __attribute__((address_space(1))) void*)g,
      (__attribute__((address_space(3))) void*)l, 16, 0, 0);
}

DEV f32x4 mfma16(bf16x8 a, bf16x8 b, f32x4 c) {
  return __builtin_amdgcn_mfma_f32_16x16x32_bf16(a, b, c, 0, 0, 0);
}

extern __shared__ char smem[];

#define QBAR()  __builtin_amdgcn_s_barrier()
#define QLGKM() asm volatile("s_waitcnt lgkmcnt(0)" ::: "memory")
#define QSCB()  __builtin_amdgcn_sched_barrier(0)

// ---------------- fused prep: x->bf16 cvt + both weight transposes ----------------
__global__ void k_prep(const float* __restrict__ x, __bf16* __restrict__ xb,
                       const float* __restrict__ wa, __bf16* __restrict__ wat,
                       const float* __restrict__ wp, __bf16* __restrict__ wpt) {
  __shared__ float t[64][65];
  const int bid = blockIdx.x;
  if (bid < 8192) {
    int i = bid * 256 + threadIdx.x;
    float4 v = reinterpret_cast<const float4*>(x)[i];
    bf16x4 o = {(__bf16)v.x, (__bf16)v.y, (__bf16)v.z, (__bf16)v.w};
    reinterpret_cast<bf16x4*>(xb)[i] = o;
    return;
  }
  const float* in;
  __bf16* out;
  int rows, cols, c0, r0;
  if (bid < 11264) {
    int tb = bid - 8192;
    in = wa; out = wat; rows = 2048; cols = 6144;
    c0 = (tb % 96) * 64; r0 = (tb / 96) * 64;
  } else {
    int tb = bid - 11264;
    in = wp; out = wpt; rows = 2048; cols = 2048;
    c0 = (tb % 32) * 64; r0 = (tb / 32) * 64;
  }
  const int tx = threadIdx.x & 63, ty = threadIdx.x >> 6;
#pragma unroll
  for (int i = 0; i < 64; i += 4)
    t[ty + i][tx] = in[(size_t)(r0 + ty + i) * cols + c0 + tx];
  __syncthreads();
#pragma unroll
  for (int i = 0; i < 64; i += 4)
    out[(size_t)(c0 + ty + i) * rows + r0 + tx] = (__bf16)t[tx][ty + i];
}

// ================= QKV: 8-phase barrier-dense GEMM, 128x384 tile, BK=64 ==========
// (r17 — measured 105.3 us, MfmaUtil 42%, no spill, tail-free 512 blocks)
__global__ __launch_bounds__(512, 1) void k_qkv8p(
    const __bf16* __restrict__ A, const __bf16* __restrict__ Bt,
    const float* __restrict__ bias,
    __bf16* __restrict__ qo, __bf16* __restrict__ ko, __bf16* __restrict__ vo) {
  constexpr int NT = 32;
  const int tid = threadIdx.x;
  const int lane = tid & 63, wid = tid >> 6;
  const int wm = wid >> 2, wn = wid & 3;
  const int ln = lane & 15, lm = lane >> 4;

  const int lin = (blockIdx.x & 7) * 64 + (blockIdx.x >> 3);
  const int by = lin >> 4, bx = lin & 15;
  const int mBase = by * 128, nBase = bx * 384;

  const int r0 = tid >> 3, cc = tid & 7;
  const int src0 = r0 * KDIM + ((cc ^ (r0 & 7)) << 3);
  const __bf16* Ab = A + (size_t)mBase * KDIM + src0;
  const __bf16* Bb = Bt + (size_t)nBase * KDIM + src0;
  const int sDst = wid * 1024;

  auto stA2 = [&](int t) {
    char* d = smem + (t & 1) * 65536 + sDst;
    const __bf16* s = Ab + t * 64;
    gll16(s, d);
    gll16(s + (size_t)64 * KDIM, d + 8192);
  };
  auto stB2 = [&](int t, int j) {
    char* d = smem + (t & 1) * 65536 + 16384 + j * 8192 + sDst;
    const __bf16* s = Bb + (size_t)j * 64 * KDIM + t * 64;
    gll16(s, d);
    gll16(s + (size_t)64 * KDIM, d + 8192);
  };

  int rA[2], rB[2];
#pragma unroll
  for (int ks = 0; ks < 2; ++ks) {
    const int slot = (ks * 4 + lm) ^ (ln & 7);
    rA[ks] = (wm * 64 + ln) * 128 + slot * 16;
    rB[ks] = 16384 + (wn * 96 + ln) * 128 + slot * 16;
  }
  auto rdA = [&](bf16x8 (&a)[4], const char* cb, int ks) {
#pragma unroll
    for (int mi = 0; mi < 4; ++mi)
      a[mi] = *reinterpret_cast<const bf16x8*>(cb + rA[ks] + mi * 2048);
  };
  auto rdBh = [&](bf16x8 (&b)[3], const char* cb, int ks, int h) {
#pragma unroll
    for (int k = 0; k < 3; ++k)
      b[k] = *reinterpret_cast<const bf16x8*>(cb + rB[ks] + (h * 3 + k) * 2048);
  };

  f32x4 acc[4][6] = {};
  auto mm = [&](const bf16x8 (&a)[4], const bf16x8 (&b)[3], int h) {
#pragma unroll
    for (int k = 0; k < 3; ++k)
#pragma unroll
      for (int mi = 0; mi < 4; ++mi)
        acc[mi][h * 3 + k] = mfma16(a[mi], b[k], acc[mi][h * 3 + k]);
  };

  stA2(0); stB2(0, 0); stB2(0, 2); stB2(0, 4); stA2(1);
  asm volatile("s_waitcnt vmcnt(2)" ::: "memory");
  QBAR(); QSCB();

  for (int i = 0; i < 16; ++i) {
    const char* L = smem;
    const char* R = smem + 65536;
    const int tR = 2 * i + 1, tN = 2 * i + 2, tN1 = 2 * i + 3;
    const bool last = (i == 15);
    bf16x8 a[4], b[3];

    rdA(a, L, 0); rdBh(b, L, 0, 0);
    stB2(tR, 0);
    QBAR(); QLGKM(); QSCB();
    __builtin_amdgcn_s_setprio(1); mm(a, b, 0); __builtin_amdgcn_s_setprio(0);
    QBAR(); QSCB();

    rdBh(b, L, 0, 1);
    stB2(tR, 2);
    QBAR(); QLGKM(); QSCB();
    __builtin_amdgcn_s_setprio(1); mm(a, b, 1); __builtin_amdgcn_s_setprio(0);
    QBAR(); QSCB();

    rdA(a, L, 1); rdBh(b, L, 1, 1);
    stB2(tR, 4);
    QBAR(); QLGKM(); QSCB();
    __builtin_amdgcn_s_setprio(1); mm(a, b, 1); __builtin_amdgcn_s_setprio(0);
    QBAR(); QSCB();

    rdBh(b, L, 1, 0);
    if (!last) stA2(tN);
    QBAR(); QLGKM(); QSCB();
    __builtin_amdgcn_s_setprio(1); mm(a, b, 0); __builtin_amdgcn_s_setprio(0);
    if (last) asm volatile("s_waitcnt vmcnt(0)" ::: "memory");
    else      asm volatile("s_waitcnt vmcnt(2)" ::: "memory");
    QBAR(); QSCB();

    rdA(a, R, 0); rdBh(b, R, 0, 0);
    if (!last) stB2(tN, 0);
    QBAR(); QLGKM(); QSCB();
    __builtin_amdgcn_s_setprio(1); mm(a, b, 0); __builtin_amdgcn_s_setprio(0);
    QBAR(); QSCB();

    rdBh(b, R, 0, 1);
    if (!last) stB2(tN, 2);
    QBAR(); QLGKM(); QSCB();
    __builtin_amdgcn_s_setprio(1); mm(a, b, 1); __builtin_amdgcn_s_setprio(0);
    QBAR(); QSCB();

    rdA(a, R, 1); rdBh(b, R, 1, 1);
    if (!last) stB2(tN, 4);
    QBAR(); QLGKM(); QSCB();
    __builtin_amdgcn_s_setprio(1); mm(a, b, 1); __builtin_amdgcn_s_setprio(0);
    QBAR(); QSCB();

    rdBh(b, R, 1, 0);
    if (tN1 < NT) stA2(tN1);
    QBAR(); QLGKM(); QSCB();
    __builtin_amdgcn_s_setprio(1); mm(a, b, 0); __builtin_amdgcn_s_setprio(0);
    if (!last) {
      asm volatile("s_waitcnt vmcnt(2)" ::: "memory");
      QBAR(); QSCB();
    }
  }

#pragma unroll
  for (int mi = 0; mi < 4; ++mi) {
    const int grow = mBase + wm * 64 + mi * 16 + lm * 4;
    const int b = grow >> 11, s0 = grow & 2047;
#pragma unroll
    for (int ni = 0; ni < 6; ++ni) {
      const int gcol = nBase + wn * 96 + ni * 16 + ln;
      const float bv = bias[gcol];
      const int sec = gcol >> 11;
      const int h = (gcol >> 7) & 15, d = gcol & 127;
      const int bh = b * H + h;
      if (sec == 0) {
#pragma unroll
        for (int r = 0; r < 4; ++r)
          qo[((size_t)bh * S + s0 + r) * D + d] = (__bf16)((acc[mi][ni][r] + bv) * QSCALE);
      } else if (sec == 1) {
#pragma unroll
        for (int r = 0; r < 4; ++r)
          ko[((size_t)bh * S + s0 + r) * D + d] = (__bf16)(acc[mi][ni][r] + bv);
      } else {
        bf16x4 pv = {(__bf16)(acc[mi][ni][0] + bv), (__bf16)(acc[mi][ni][1] + bv),
                     (__bf16)(acc[mi][ni][2] + bv), (__bf16)(acc[mi][ni][3] + bv)};
        *reinterpret_cast<bf16x4*>(vo + ((size_t)bh * D + d) * S + s0) = pv;  // V^T
      }
    }
  }
}

// ================= out-proj: 8-phase barrier-dense GEMM, 128x256 tile =============
// R18: same phase/barrier/counted-vmcnt structure as k_qkv8p (42% MfmaUtil vs 37%
// for the loose 4-phase). 8 waves (2M x 4N), wave tile 64x64, acc[4][4] (64 AGPR).
// LDS 96 KiB = 2 bufs x {A[128][64] @0 (2 loads), B[256][64] @16K (4 loads)}.
// Quadrants (ks0,Blo),(ks0,Bhi),(ks1,Bhi),(ks1,Blo) = 8 MFMA each.
// Stage slots: q0/q1: B(tR) pairs [R-B last read prev q7]; q2: A(tN) [L-A q2-read
// precedes]; q4/q5: B(tN); q6: A(tN+1). q3/q7: no stage. Counted waits:
// end-q3 vmcnt(2) => tR landed (newer: q2's 2); end-q7 vmcnt(2) => tN landed
// (newer: q6's 2). Last iter: q3 waits vmcnt(0) (tR-B newest), no q7 wait.
__global__ __launch_bounds__(512, 1) void k_proj8p(
    const __bf16* __restrict__ A, const __bf16* __restrict__ Bt,
    const float* __restrict__ bias, float* __restrict__ fo) {
  constexpr int NT = 32;
  const int tid = threadIdx.x;
  const int lane = tid & 63, wid = tid >> 6;
  const int wm = wid >> 2, wn = wid & 3;
  const int ln = lane & 15, lm = lane >> 4;

  const int lin = (blockIdx.x & 7) * 32 + (blockIdx.x >> 3);
  const int by = lin >> 3, bx = lin & 7;
  const int mBase = by * 128, nBase = bx * 256;

  const int r0 = tid >> 3, cc = tid & 7;
  const int src0 = r0 * KDIM + ((cc ^ (r0 & 7)) << 3);
  const __bf16* Ab = A + (size_t)mBase * KDIM + src0;
  const __bf16* Bb = Bt + (size_t)nBase * KDIM + src0;
  const int sDst = wid * 1024;

  auto stA2 = [&](int t) {
    char* d = smem + (t & 1) * 49152 + sDst;
    const __bf16* s = Ab + t * 64;
    gll16(s, d);
    gll16(s + (size_t)64 * KDIM, d + 8192);
  };
  auto stB2 = [&](int t, int j) {
    char* d = smem + (t & 1) * 49152 + 16384 + j * 8192 + sDst;
    const __bf16* s = Bb + (size_t)j * 64 * KDIM + t * 64;
    gll16(s, d);
    gll16(s + (size_t)64 * KDIM, d + 8192);
  };

  int rA[2], rB[2];
#pragma unroll
  for (int ks = 0; ks < 2; ++ks) {
    const int slot = (ks * 4 + lm) ^ (ln & 7);
    rA[ks] = (wm * 64 + ln) * 128 + slot * 16;
    rB[ks] = 16384 + (wn * 64 + ln) * 128 + slot * 16;
  }
  auto rdA = [&](bf16x8 (&a)[4], const char* cb, int ks) {
#pragma unroll
    for (int mi = 0; mi < 4; ++mi)
      a[mi] = *reinterpret_cast<const bf16x8*>(cb + rA[ks] + mi * 2048);
  };
  auto rdBh = [&](bf16x8 (&b)[2], const char* cb, int ks, int h) {
#pragma unroll
    for (int k = 0; k < 2; ++k)
      b[k] = *reinterpret_cast<const bf16x8*>(cb + rB[ks] + (h * 2 + k) * 2048);
  };

  f32x4 acc[4][4] = {};
  auto mm = [&](const bf16x8 (&a)[4], const bf16x8 (&b)[2], int h) {
#pragma unroll
    for (int k = 0; k < 2; ++k)
#pragma unroll
      for (int mi = 0; mi < 4; ++mi)
        acc[mi][h * 2 + k] = mfma16(a[mi], b[k], acc[mi][h * 2 + k]);
  };

  // prologue: t0 full (6) + t1-A (2); vmcnt(2) => t0 landed
  stA2(0); stB2(0, 0); stB2(0, 2); stA2(1);
  asm volatile("s_waitcnt vmcnt(2)" ::: "memory");
  QBAR(); QSCB();

  for (int i = 0; i < 16; ++i) {
    const char* L = smem;
    const char* R = smem + 49152;
    const int tR = 2 * i + 1, tN = 2 * i + 2, tN1 = 2 * i + 3;
    const bool last = (i == 15);
    bf16x8 a[4], b[2];

    // q0: tL (ks0, Blo); stage B(tR) 0-1
    rdA(a, L, 0); rdBh(b, L, 0, 0);
    stB2(tR, 0);
    QBAR(); QLGKM(); QSCB();
    __builtin_amdgcn_s_setprio(1); mm(a, b, 0); __builtin_amdgcn_s_setprio(0);
    QBAR(); QSCB();
    // q1: (ks0, Bhi); stage B(tR) 2-3
    rdBh(b, L, 0, 1);
    stB2(tR, 2);
    QBAR(); QLGKM(); QSCB();
    __builtin_amdgcn_s_setprio(1); mm(a, b, 1); __builtin_amdgcn_s_setprio(0);
    QBAR(); QSCB();
    // q2: (ks1, Bhi); stage A(tN)
    rdA(a, L, 1); rdBh(b, L, 1, 1);
    if (!last) stA2(tN);
    QBAR(); QLGKM(); QSCB();
    __builtin_amdgcn_s_setprio(1); mm(a, b, 1); __builtin_amdgcn_s_setprio(0);
    QBAR(); QSCB();
    // q3: (ks1, Blo); vmcnt => tR landed
    rdBh(b, L, 1, 0);
    QBAR(); QLGKM(); QSCB();
    __builtin_amdgcn_s_setprio(1); mm(a, b, 0); __builtin_amdgcn_s_setprio(0);
    if (last) asm volatile("s_waitcnt vmcnt(0)" ::: "memory");
    else      asm volatile("s_waitcnt vmcnt(2)" ::: "memory");
    QBAR(); QSCB();

    // q4: tR (ks0, Blo); stage B(tN) 0-1
    rdA(a, R, 0); rdBh(b, R, 0, 0);
    if (!last) stB2(tN, 0);
    QBAR(); QLGKM(); QSCB();
    __builtin_amdgcn_s_setprio(1); mm(a, b, 0); __builtin_amdgcn_s_setprio(0);
    QBAR(); QSCB();
    // q5: (ks0, Bhi); stage B(tN) 2-3
    rdBh(b, R, 0, 1);
    if (!last) stB2(tN, 2);
    QBAR(); QLGKM(); QSCB();
    __builtin_amdgcn_s_setprio(1); mm(a, b, 1); __builtin_amdgcn_s_setprio(0);
    QBAR(); QSCB();
    // q6: (ks1, Bhi); stage A(tN1)
    rdA(a, R, 1); rdBh(b, R, 1, 1);
    if (tN1 < NT) stA2(tN1);
    QBAR(); QLGKM(); QSCB();
    __builtin_amdgcn_s_setprio(1); mm(a, b, 1); __builtin_amdgcn_s_setprio(0);
    QBAR(); QSCB();
    // q7: (ks1, Blo); vmcnt => tN landed
    rdBh(b, R, 1, 0);
    QBAR(); QLGKM(); QSCB();
    __builtin_amdgcn_s_setprio(1); mm(a, b, 0); __builtin_amdgcn_s_setprio(0);
    if (!last) {
      asm volatile("s_waitcnt vmcnt(2)" ::: "memory");
      QBAR(); QSCB();
    }
  }

#pragma unroll
  for (int mi = 0; mi < 4; ++mi) {
    const int grow = mBase + wm * 64 + mi * 16 + lm * 4;
#pragma unroll
    for (int ni = 0; ni < 4; ++ni) {
      const int gcol = nBase + wn * 64 + ni * 16 + ln;
      const float bv = bias[gcol];
#pragma unroll
      for (int r = 0; r < 4; ++r)
        fo[(size_t)(grow + r) * F + gcol] = acc[mi][ni][r] + bv;
    }
  }
}

// ---------------- flash attention (r16: fast-path softmax + counted waits) --------
__global__ __launch_bounds__(256, 2) void k_attn(
    const __bf16* __restrict__ qb, const __bf16* __restrict__ kb,
    const __bf16* __restrict__ vtb, __bf16* __restrict__ zb) {
  const int lane = threadIdx.x & 63, w = threadIdx.x >> 6;
  const int lm = lane >> 4, ln = lane & 15;
  const int blk = blockIdx.x;
  const int u = blk & 255, v = blk >> 8;
  const int qt = v ? (u >> 4) : 15 - (u >> 4);
  const int bh = ((u & 15) << 1) | v;
  const int qw = qt * 128 + w * 32;

  const __bf16* qp = qb + (size_t)bh * S * D;
  const __bf16* kp = kb + (size_t)bh * S * D;
  const __bf16* vp = vtb + (size_t)bh * D * S;
  char* pw = smem + 65536 + w * 4096;

  int ksrc[4], kdst[4], vsrc[4], vdst[4];
#pragma unroll
  for (int j = 0; j < 4; ++j) {
    int c = (w * 4 + j) * 64 + lane;
    int kr = c >> 4, kps = (c & 15) ^ (kr & 7);
    ksrc[j] = kr * D + kps * 8;
    kdst[j] = (w * 4 + j) * 1024;
    int vr = c >> 3, vps = (c & 7) ^ (vr & 7);
    vsrc[j] = vr * S + vps * 8;
    vdst[j] = 16384 + (w * 4 + j) * 1024;
  }
  auto stage = [&](int kt) {
    char* buf = smem + (kt & 1) * 32768;
    const int kv = kt * 64;
#pragma unroll
    for (int j = 0; j < 4; ++j) gll16(kp + (size_t)kv * D + ksrc[j], buf + kdst[j]);
#pragma unroll
    for (int j = 0; j < 4; ++j) gll16(vp + kv + vsrc[j], buf + vdst[j]);
  };

  bf16x8 qf[2][4];
#pragma unroll
  for (int mi = 0; mi < 2; ++mi)
#pragma unroll
    for (int kf = 0; kf < 4; ++kf)
      qf[mi][kf] = *reinterpret_cast<const bf16x8*>(qp + (qw + mi * 16 + ln) * D + kf * 32 + lm * 8);

  f32x4 Oa[2][8] = {};
  float mrow[2][4], lrow[2][4];
#pragma unroll
  for (int mi = 0; mi < 2; ++mi)
#pragma unroll
    for (int r = 0; r < 4; ++r) { mrow[mi][r] = -3.0e38f; lrow[mi][r] = 0.0f; }

  const int ktEnd = 2 * qt + 1;

  stage(0);
  stage(1);
  asm volatile("s_waitcnt vmcnt(8)" ::: "memory");
  QBAR(); QSCB();

  for (int kt = 0; kt <= ktEnd; ++kt) {
    const int kv0 = kt * 64;
    const int cur = kt & 1;
    const char* Kb = smem + cur * 32768;
    const char* Vb = Kb + 16384;

    if (kv0 <= qw + 31) {
      const bool diag = (kv0 + 63 > qw);

      f32x4 sacc[2][4] = {};
#pragma unroll
      for (int kf = 0; kf < 4; ++kf) {
        bf16x8 kfr[4];
#pragma unroll
        for (int ni = 0; ni < 4; ++ni) {
          int row = ni * 16 + ln;
          int ch = (kf * 4 + lm) ^ (row & 7);
          kfr[ni] = *reinterpret_cast<const bf16x8*>(Kb + row * 256 + ch * 16);
        }
        __builtin_amdgcn_s_setprio(1);
#pragma unroll
        for (int mi = 0; mi < 2; ++mi)
#pragma unroll
          for (int ni = 0; ni < 4; ++ni)
            sacc[mi][ni] = mfma16(qf[mi][kf], kfr[ni], sacc[mi][ni]);
        __builtin_amdgcn_s_setprio(0);
      }

      if (diag) {
#pragma unroll
        for (int ni = 0; ni < 4; ++ni) {
          int c = kv0 + ni * 16 + ln;
#pragma unroll
          for (int mi = 0; mi < 2; ++mi) {
            int q0r = qw + mi * 16 + lm * 4;
#pragma unroll
            for (int r = 0; r < 4; ++r)
              if (c > q0r + r) sacc[mi][ni][r] = -1e30f;
          }
        }
      }

      float lmax[2][4];
      bool big = false;
#pragma unroll
      for (int mi = 0; mi < 2; ++mi)
#pragma unroll
        for (int r = 0; r < 4; ++r) {
          float m4 = fmaxf(fmaxf(sacc[mi][0][r], sacc[mi][1][r]),
                           fmaxf(sacc[mi][2][r], sacc[mi][3][r]));
          lmax[mi][r] = m4;
          big = big || (m4 > mrow[mi][r] + 8.0f);
        }
      if (__any((int)big)) {
#pragma unroll
        for (int mi = 0; mi < 2; ++mi)
#pragma unroll
          for (int r = 0; r < 4; ++r) {
            float mx = lmax[mi][r];
            mx = fmaxf(mx, __shfl_xor(mx, 1, 64));
            mx = fmaxf(mx, __shfl_xor(mx, 2, 64));
            mx = fmaxf(mx, __shfl_xor(mx, 4, 64));
            mx = fmaxf(mx, __shfl_xor(mx, 8, 64));
            float mnew = fmaxf(mrow[mi][r], mx);
            float corr = __expf(mrow[mi][r] - mnew);
            mrow[mi][r] = mnew;
            lrow[mi][r] *= corr;
#pragma unroll
            for (int ni = 0; ni < 8; ++ni) Oa[mi][ni][r] *= corr;
          }
      }
#pragma unroll
      for (int mi = 0; mi < 2; ++mi)
#pragma unroll
        for (int r = 0; r < 4; ++r) {
          float rs = 0.0f;
#pragma unroll
          for (int ni = 0; ni < 4; ++ni) {
            float p = __expf(sacc[mi][ni][r] - mrow[mi][r]);
            sacc[mi][ni][r] = p;
            rs += p;
          }
          lrow[mi][r] += rs;
        }

#pragma unroll
      for (int mi = 0; mi < 2; ++mi)
#pragma unroll
        for (int ni = 0; ni < 4; ++ni)
#pragma unroll
          for (int r = 0; r < 4; ++r) {
            int row = mi * 16 + lm * 4 + r;
            int bo = (row * 128 + (ni * 16 + ln) * 2) ^ ((row & 7) << 4);
            *reinterpret_cast<__bf16*>(pw + bo) = (__bf16)sacc[mi][ni][r];
          }

      QLGKM(); QSCB();

#pragma unroll
      for (int kf = 0; kf < 2; ++kf) {
        bf16x8 pfr[2], vfr[8];
#pragma unroll
        for (int mi = 0; mi < 2; ++mi) {
          int row = mi * 16 + ln;
          int ch = (kf * 4 + lm) ^ (row & 7);
          pfr[mi] = *reinterpret_cast<const bf16x8*>(pw + row * 128 + ch * 16);
        }
#pragma unroll
        for (int ni = 0; ni < 8; ++ni) {
          int row = ni * 16 + ln;
          int ch = (kf * 4 + lm) ^ (row & 7);
          vfr[ni] = *reinterpret_cast<const bf16x8*>(Vb + row * 128 + ch * 16);
        }
        __builtin_amdgcn_s_setprio(1);
#pragma unroll
        for (int mi = 0; mi < 2; ++mi)
#pragma unroll
          for (int ni = 0; ni < 8; ++ni)
            Oa[mi][ni] = mfma16(pfr[mi], vfr[ni], Oa[mi][ni]);
        __builtin_amdgcn_s_setprio(0);
      }
    }

    asm volatile("s_waitcnt lgkmcnt(0)" ::: "memory");
    QBAR(); QSCB();
    if (kt + 2 <= ktEnd) stage(kt + 2);
    if (kt + 1 <= ktEnd) {
      if (kt + 2 <= ktEnd)
        asm volatile("s_waitcnt vmcnt(8)" ::: "memory");
      else
        asm volatile("s_waitcnt vmcnt(0)" ::: "memory");
      QBAR(); QSCB();
    }
  }

#pragma unroll
  for (int mi = 0; mi < 2; ++mi)
#pragma unroll
    for (int r = 0; r < 4; ++r) {
      float ls = lrow[mi][r];
      ls += __shfl_xor(ls, 1, 64);
      ls += __shfl_xor(ls, 2, 64);
      ls += __shfl_xor(ls, 4, 64);
      ls += __shfl_xor(ls, 8, 64);
      lrow[mi][r] = 1.0f / ls;
    }
  const int b = bh >> 4, h = bh & 15;
#pragma unroll
  for (int mi = 0; mi < 2; ++mi)
#pragma unroll
    for (int ni = 0; ni < 8; ++ni) {
      int d = ni * 16 + ln;
#pragma unroll
      for (int r = 0; r < 4; ++r) {
        int qrow = qw + mi * 16 + lm * 4 + r;
        zb[(size_t)(b * S + qrow) * F + h * D + d] = (__bf16)(Oa[mi][ni][r] * lrow[mi][r]);
      }
    }
}

// ---------------- launch ----------------
extern "C" void kernel_launch(void* const* d_in, const int* in_sizes, int n_in,
                              void* d_out, int out_size, void* d_ws, size_t ws_size,
                              hipStream_t stream) {
  const float* x = (const float*)d_in[0];
  // d_in[1] = causal mask (implemented analytically)
  const float* w_attn = (const float*)d_in[2];
  const float* b_attn = (const float*)d_in[3];
  const float* w_proj = (const float*)d_in[4];
  const float* b_proj = (const float*)d_in[5];
  float* out = (float*)d_out;

  char* ws = (char*)d_ws;
  __bf16* xb    = (__bf16*)(ws + 0);          // 16 MB  [4096][2048] (reused as zb)
  __bf16* wqkv  = (__bf16*)(ws + 16777216);   // 24 MB  [6144][2048] (W^T)
  __bf16* wpro  = (__bf16*)(ws + 41943040);   //  8 MB  [2048][2048] (W^T)
  __bf16* qb    = (__bf16*)(ws + 50331648);   // 16 MB  [bh][s][d]
  __bf16* kb    = (__bf16*)(ws + 67108864);   // 16 MB  [bh][s][d]
  __bf16* vtb   = (__bf16*)(ws + 83886080);   // 16 MB  [bh][d][s]
  __bf16* zb    = xb;  // x fully consumed by QKV GEMM before attention writes z

  (void)hipFuncSetAttribute((const void*)k_qkv8p,
                            hipFuncAttributeMaxDynamicSharedMemorySize, 131072);
  (void)hipFuncSetAttribute((const void*)k_proj8p,
                            hipFuncAttributeMaxDynamicSharedMemorySize, 98304);
  (void)hipFuncSetAttribute((const void*)k_attn,
                            hipFuncAttributeMaxDynamicSharedMemorySize, 81920);

  // fused prep: 8192 cvt + 3072 w_attn-transpose + 1024 w_proj-transpose
  k_prep<<<12288, 256, 0, stream>>>(x, xb, w_attn, wqkv, w_proj, wpro);
  // QKV: M=4096 (32 x 128), N=6144 (16 x 384) -> 512 blocks = 2 exact rounds
  k_qkv8p<<<512, 512, 131072, stream>>>(xb, wqkv, b_attn, qb, kb, vtb);
  // attention: 512 blocks (complementary-qt balance + XCD affinity inside)
  k_attn<<<512, 256, 81920, stream>>>(qb, kb, vtb, zb);
  // out-proj: M=4096 (32 x 128), N=2048 (8 x 256) -> 256 blocks = 1/CU exact
  k_proj8p<<<256, 512, 98304, stream>>>(zb, wpro, b_proj, out);
}

// Round 19
// 224.336 us; speedup vs baseline: 1.7234x; 1.0405x over previous
//
#include <hip/hip_runtime.h>
#include <hip/hip_bf16.h>
#include <stdint.h>

typedef __attribute__((ext_vector_type(8))) __bf16 bf16x8;
typedef __attribute__((ext_vector_type(4))) __bf16 bf16x4;
typedef __attribute__((ext_vector_type(4))) float f32x4;

#define DEV __device__ __forceinline__

static constexpr int S = 2048, F = 2048, H = 16, D = 128;
static constexpr int KDIM = F;            // 2048
static constexpr float QSCALE = 0.08838834764831845f;  // 1/sqrt(128)

DEV void gll16(const void* g, void* l) {
  __builtin_amdgcn_global_load_lds(
      (const __attribute__((address_space(1))) void*)g,
      (__attribute__((address_space(3))) void*)l, 16, 0, 0);
}

DEV f32x4 mfma16(bf16x8 a, bf16x8 b, f32x4 c) {
  return __builtin_amdgcn_mfma_f32_16x16x32_bf16(a, b, c, 0, 0, 0);
}

extern __shared__ char smem[];

#define QBAR()  __builtin_amdgcn_s_barrier()
#define QLGKM() asm volatile("s_waitcnt lgkmcnt(0)" ::: "memory")
#define QSCB()  __builtin_amdgcn_sched_barrier(0)

// ---------------- fused prep: x->bf16 cvt + both weight transposes ----------------
__global__ void k_prep(const float* __restrict__ x, __bf16* __restrict__ xb,
                       const float* __restrict__ wa, __bf16* __restrict__ wat,
                       const float* __restrict__ wp, __bf16* __restrict__ wpt) {
  __shared__ float t[64][65];
  const int bid = blockIdx.x;
  if (bid < 8192) {
    int i = bid * 256 + threadIdx.x;
    float4 v = reinterpret_cast<const float4*>(x)[i];
    bf16x4 o = {(__bf16)v.x, (__bf16)v.y, (__bf16)v.z, (__bf16)v.w};
    reinterpret_cast<bf16x4*>(xb)[i] = o;
    return;
  }
  const float* in;
  __bf16* out;
  int rows, cols, c0, r0;
  if (bid < 11264) {
    int tb = bid - 8192;
    in = wa; out = wat; rows = 2048; cols = 6144;
    c0 = (tb % 96) * 64; r0 = (tb / 96) * 64;
  } else {
    int tb = bid - 11264;
    in = wp; out = wpt; rows = 2048; cols = 2048;
    c0 = (tb % 32) * 64; r0 = (tb / 32) * 64;
  }
  const int tx = threadIdx.x & 63, ty = threadIdx.x >> 6;
#pragma unroll
  for (int i = 0; i < 64; i += 4)
    t[ty + i][tx] = in[(size_t)(r0 + ty + i) * cols + c0 + tx];
  __syncthreads();
#pragma unroll
  for (int i = 0; i < 64; i += 4)
    out[(size_t)(c0 + ty + i) * rows + r0 + tx] = (__bf16)t[tx][ty + i];
}

// ================= QKV: 8-phase barrier-dense GEMM, 128x384 tile, BK=64 ==========
// (r17 — measured 105.3 us, MfmaUtil 42%, no spill, tail-free 512 blocks)
__global__ __launch_bounds__(512, 1) void k_qkv8p(
    const __bf16* __restrict__ A, const __bf16* __restrict__ Bt,
    const float* __restrict__ bias,
    __bf16* __restrict__ qo, __bf16* __restrict__ ko, __bf16* __restrict__ vo) {
  constexpr int NT = 32;
  const int tid = threadIdx.x;
  const int lane = tid & 63, wid = tid >> 6;
  const int wm = wid >> 2, wn = wid & 3;
  const int ln = lane & 15, lm = lane >> 4;

  const int lin = (blockIdx.x & 7) * 64 + (blockIdx.x >> 3);
  const int by = lin >> 4, bx = lin & 15;
  const int mBase = by * 128, nBase = bx * 384;

  const int r0 = tid >> 3, cc = tid & 7;
  const int src0 = r0 * KDIM + ((cc ^ (r0 & 7)) << 3);
  const __bf16* Ab = A + (size_t)mBase * KDIM + src0;
  const __bf16* Bb = Bt + (size_t)nBase * KDIM + src0;
  const int sDst = wid * 1024;

  auto stA2 = [&](int t) {
    char* d = smem + (t & 1) * 65536 + sDst;
    const __bf16* s = Ab + t * 64;
    gll16(s, d);
    gll16(s + (size_t)64 * KDIM, d + 8192);
  };
  auto stB2 = [&](int t, int j) {
    char* d = smem + (t & 1) * 65536 + 16384 + j * 8192 + sDst;
    const __bf16* s = Bb + (size_t)j * 64 * KDIM + t * 64;
    gll16(s, d);
    gll16(s + (size_t)64 * KDIM, d + 8192);
  };

  int rA[2], rB[2];
#pragma unroll
  for (int ks = 0; ks < 2; ++ks) {
    const int slot = (ks * 4 + lm) ^ (ln & 7);
    rA[ks] = (wm * 64 + ln) * 128 + slot * 16;
    rB[ks] = 16384 + (wn * 96 + ln) * 128 + slot * 16;
  }
  auto rdA = [&](bf16x8 (&a)[4], const char* cb, int ks) {
#pragma unroll
    for (int mi = 0; mi < 4; ++mi)
      a[mi] = *reinterpret_cast<const bf16x8*>(cb + rA[ks] + mi * 2048);
  };
  auto rdBh = [&](bf16x8 (&b)[3], const char* cb, int ks, int h) {
#pragma unroll
    for (int k = 0; k < 3; ++k)
      b[k] = *reinterpret_cast<const bf16x8*>(cb + rB[ks] + (h * 3 + k) * 2048);
  };

  f32x4 acc[4][6] = {};
  auto mm = [&](const bf16x8 (&a)[4], const bf16x8 (&b)[3], int h) {
#pragma unroll
    for (int k = 0; k < 3; ++k)
#pragma unroll
      for (int mi = 0; mi < 4; ++mi)
        acc[mi][h * 3 + k] = mfma16(a[mi], b[k], acc[mi][h * 3 + k]);
  };

  stA2(0); stB2(0, 0); stB2(0, 2); stB2(0, 4); stA2(1);
  asm volatile("s_waitcnt vmcnt(2)" ::: "memory");
  QBAR(); QSCB();

  for (int i = 0; i < 16; ++i) {
    const char* L = smem;
    const char* R = smem + 65536;
    const int tR = 2 * i + 1, tN = 2 * i + 2, tN1 = 2 * i + 3;
    const bool last = (i == 15);
    bf16x8 a[4], b[3];

    rdA(a, L, 0); rdBh(b, L, 0, 0);
    stB2(tR, 0);
    QBAR(); QLGKM(); QSCB();
    __builtin_amdgcn_s_setprio(1); mm(a, b, 0); __builtin_amdgcn_s_setprio(0);
    QBAR(); QSCB();

    rdBh(b, L, 0, 1);
    stB2(tR, 2);
    QBAR(); QLGKM(); QSCB();
    __builtin_amdgcn_s_setprio(1); mm(a, b, 1); __builtin_amdgcn_s_setprio(0);
    QBAR(); QSCB();

    rdA(a, L, 1); rdBh(b, L, 1, 1);
    stB2(tR, 4);
    QBAR(); QLGKM(); QSCB();
    __builtin_amdgcn_s_setprio(1); mm(a, b, 1); __builtin_amdgcn_s_setprio(0);
    QBAR(); QSCB();

    rdBh(b, L, 1, 0);
    if (!last) stA2(tN);
    QBAR(); QLGKM(); QSCB();
    __builtin_amdgcn_s_setprio(1); mm(a, b, 0); __builtin_amdgcn_s_setprio(0);
    if (last) asm volatile("s_waitcnt vmcnt(0)" ::: "memory");
    else      asm volatile("s_waitcnt vmcnt(2)" ::: "memory");
    QBAR(); QSCB();

    rdA(a, R, 0); rdBh(b, R, 0, 0);
    if (!last) stB2(tN, 0);
    QBAR(); QLGKM(); QSCB();
    __builtin_amdgcn_s_setprio(1); mm(a, b, 0); __builtin_amdgcn_s_setprio(0);
    QBAR(); QSCB();

    rdBh(b, R, 0, 1);
    if (!last) stB2(tN, 2);
    QBAR(); QLGKM(); QSCB();
    __builtin_amdgcn_s_setprio(1); mm(a, b, 1); __builtin_amdgcn_s_setprio(0);
    QBAR(); QSCB();

    rdA(a, R, 1); rdBh(b, R, 1, 1);
    if (!last) stB2(tN, 4);
    QBAR(); QLGKM(); QSCB();
    __builtin_amdgcn_s_setprio(1); mm(a, b, 1); __builtin_amdgcn_s_setprio(0);
    QBAR(); QSCB();

    rdBh(b, R, 1, 0);
    if (tN1 < NT) stA2(tN1);
    QBAR(); QLGKM(); QSCB();
    __builtin_amdgcn_s_setprio(1); mm(a, b, 0); __builtin_amdgcn_s_setprio(0);
    if (!last) {
      asm volatile("s_waitcnt vmcnt(2)" ::: "memory");
      QBAR(); QSCB();
    }
  }

#pragma unroll
  for (int mi = 0; mi < 4; ++mi) {
    const int grow = mBase + wm * 64 + mi * 16 + lm * 4;
    const int b = grow >> 11, s0 = grow & 2047;
#pragma unroll
    for (int ni = 0; ni < 6; ++ni) {
      const int gcol = nBase + wn * 96 + ni * 16 + ln;
      const float bv = bias[gcol];
      const int sec = gcol >> 11;
      const int h = (gcol >> 7) & 15, d = gcol & 127;
      const int bh = b * H + h;
      if (sec == 0) {
#pragma unroll
        for (int r = 0; r < 4; ++r)
          qo[((size_t)bh * S + s0 + r) * D + d] = (__bf16)((acc[mi][ni][r] + bv) * QSCALE);
      } else if (sec == 1) {
#pragma unroll
        for (int r = 0; r < 4; ++r)
          ko[((size_t)bh * S + s0 + r) * D + d] = (__bf16)(acc[mi][ni][r] + bv);
      } else {
        bf16x4 pv = {(__bf16)(acc[mi][ni][0] + bv), (__bf16)(acc[mi][ni][1] + bv),
                     (__bf16)(acc[mi][ni][2] + bv), (__bf16)(acc[mi][ni][3] + bv)};
        *reinterpret_cast<bf16x4*>(vo + ((size_t)bh * D + d) * S + s0) = pv;  // V^T
      }
    }
  }
}

// ================= out-proj: 8-phase barrier-dense GEMM, 128x256 tile =============
// (r18 — best proj)
__global__ __launch_bounds__(512, 1) void k_proj8p(
    const __bf16* __restrict__ A, const __bf16* __restrict__ Bt,
    const float* __restrict__ bias, float* __restrict__ fo) {
  constexpr int NT = 32;
  const int tid = threadIdx.x;
  const int lane = tid & 63, wid = tid >> 6;
  const int wm = wid >> 2, wn = wid & 3;
  const int ln = lane & 15, lm = lane >> 4;

  const int lin = (blockIdx.x & 7) * 32 + (blockIdx.x >> 3);
  const int by = lin >> 3, bx = lin & 7;
  const int mBase = by * 128, nBase = bx * 256;

  const int r0 = tid >> 3, cc = tid & 7;
  const int src0 = r0 * KDIM + ((cc ^ (r0 & 7)) << 3);
  const __bf16* Ab = A + (size_t)mBase * KDIM + src0;
  const __bf16* Bb = Bt + (size_t)nBase * KDIM + src0;
  const int sDst = wid * 1024;

  auto stA2 = [&](int t) {
    char* d = smem + (t & 1) * 49152 + sDst;
    const __bf16* s = Ab + t * 64;
    gll16(s, d);
    gll16(s + (size_t)64 * KDIM, d + 8192);
  };
  auto stB2 = [&](int t, int j) {
    char* d = smem + (t & 1) * 49152 + 16384 + j * 8192 + sDst;
    const __bf16* s = Bb + (size_t)j * 64 * KDIM + t * 64;
    gll16(s, d);
    gll16(s + (size_t)64 * KDIM, d + 8192);
  };

  int rA[2], rB[2];
#pragma unroll
  for (int ks = 0; ks < 2; ++ks) {
    const int slot = (ks * 4 + lm) ^ (ln & 7);
    rA[ks] = (wm * 64 + ln) * 128 + slot * 16;
    rB[ks] = 16384 + (wn * 64 + ln) * 128 + slot * 16;
  }
  auto rdA = [&](bf16x8 (&a)[4], const char* cb, int ks) {
#pragma unroll
    for (int mi = 0; mi < 4; ++mi)
      a[mi] = *reinterpret_cast<const bf16x8*>(cb + rA[ks] + mi * 2048);
  };
  auto rdBh = [&](bf16x8 (&b)[2], const char* cb, int ks, int h) {
#pragma unroll
    for (int k = 0; k < 2; ++k)
      b[k] = *reinterpret_cast<const bf16x8*>(cb + rB[ks] + (h * 2 + k) * 2048);
  };

  f32x4 acc[4][4] = {};
  auto mm = [&](const bf16x8 (&a)[4], const bf16x8 (&b)[2], int h) {
#pragma unroll
    for (int k = 0; k < 2; ++k)
#pragma unroll
      for (int mi = 0; mi < 4; ++mi)
        acc[mi][h * 2 + k] = mfma16(a[mi], b[k], acc[mi][h * 2 + k]);
  };

  stA2(0); stB2(0, 0); stB2(0, 2); stA2(1);
  asm volatile("s_waitcnt vmcnt(2)" ::: "memory");
  QBAR(); QSCB();

  for (int i = 0; i < 16; ++i) {
    const char* L = smem;
    const char* R = smem + 49152;
    const int tR = 2 * i + 1, tN = 2 * i + 2, tN1 = 2 * i + 3;
    const bool last = (i == 15);
    bf16x8 a[4], b[2];

    rdA(a, L, 0); rdBh(b, L, 0, 0);
    stB2(tR, 0);
    QBAR(); QLGKM(); QSCB();
    __builtin_amdgcn_s_setprio(1); mm(a, b, 0); __builtin_amdgcn_s_setprio(0);
    QBAR(); QSCB();

    rdBh(b, L, 0, 1);
    stB2(tR, 2);
    QBAR(); QLGKM(); QSCB();
    __builtin_amdgcn_s_setprio(1); mm(a, b, 1); __builtin_amdgcn_s_setprio(0);
    QBAR(); QSCB();

    rdA(a, L, 1); rdBh(b, L, 1, 1);
    if (!last) stA2(tN);
    QBAR(); QLGKM(); QSCB();
    __builtin_amdgcn_s_setprio(1); mm(a, b, 1); __builtin_amdgcn_s_setprio(0);
    QBAR(); QSCB();

    rdBh(b, L, 1, 0);
    QBAR(); QLGKM(); QSCB();
    __builtin_amdgcn_s_setprio(1); mm(a, b, 0); __builtin_amdgcn_s_setprio(0);
    if (last) asm volatile("s_waitcnt vmcnt(0)" ::: "memory");
    else      asm volatile("s_waitcnt vmcnt(2)" ::: "memory");
    QBAR(); QSCB();

    rdA(a, R, 0); rdBh(b, R, 0, 0);
    if (!last) stB2(tN, 0);
    QBAR(); QLGKM(); QSCB();
    __builtin_amdgcn_s_setprio(1); mm(a, b, 0); __builtin_amdgcn_s_setprio(0);
    QBAR(); QSCB();

    rdBh(b, R, 0, 1);
    if (!last) stB2(tN, 2);
    QBAR(); QLGKM(); QSCB();
    __builtin_amdgcn_s_setprio(1); mm(a, b, 1); __builtin_amdgcn_s_setprio(0);
    QBAR(); QSCB();

    rdA(a, R, 1); rdBh(b, R, 1, 1);
    if (tN1 < NT) stA2(tN1);
    QBAR(); QLGKM(); QSCB();
    __builtin_amdgcn_s_setprio(1); mm(a, b, 1); __builtin_amdgcn_s_setprio(0);
    QBAR(); QSCB();

    rdBh(b, R, 1, 0);
    QBAR(); QLGKM(); QSCB();
    __builtin_amdgcn_s_setprio(1); mm(a, b, 0); __builtin_amdgcn_s_setprio(0);
    if (!last) {
      asm volatile("s_waitcnt vmcnt(2)" ::: "memory");
      QBAR(); QSCB();
    }
  }

#pragma unroll
  for (int mi = 0; mi < 4; ++mi) {
    const int grow = mBase + wm * 64 + mi * 16 + lm * 4;
#pragma unroll
    for (int ni = 0; ni < 4; ++ni) {
      const int gcol = nBase + wn * 64 + ni * 16 + ln;
      const float bv = bias[gcol];
#pragma unroll
      for (int r = 0; r < 4; ++r)
        fo[(size_t)(grow + r) * F + gcol] = acc[mi][ni][r] + bv;
    }
  }
}

// ---------------- flash attention: SWAPPED-OPERAND (R19) ----------------
// S^T = mfma(A=K, B=Q): C col=lane&15 = q-row (one q-row per lane), row = kv.
// K/Q/V reads byte-identical to r18 (A/B frag lane-mappings are symmetric).
// Softmax: lane owns 16 kv of q=nj*16+ln -> slow-path reduce = 2 shuffles (lm
// group, xor 16/32); fast-path lane-partial trigger unchanged.
// P: lane packs each kv-quad (mi*16+lm*4+{0..3}) as bf16x4 -> ONE b64 LDS write
// (8 total vs 32 b16) into P^T[32q][64kv] (row q, XOR-swz ^((row&7)<<4)).
// PV = mfma(A=V^T, B=P^T) -> O^T acc[8][2]; B-frag reads 4 b128 (col=q=ln).
// Epilogue: d = mi*16+lm*4+{0..3} contiguous -> bf16x4 8B stores (was scalar).
__global__ __launch_bounds__(256, 2) void k_attn(
    const __bf16* __restrict__ qb, const __bf16* __restrict__ kb,
    const __bf16* __restrict__ vtb, __bf16* __restrict__ zb) {
  const int lane = threadIdx.x & 63, w = threadIdx.x >> 6;
  const int lm = lane >> 4, ln = lane & 15;
  const int blk = blockIdx.x;
  const int u = blk & 255, v = blk >> 8;
  const int qt = v ? (u >> 4) : 15 - (u >> 4);
  const int bh = ((u & 15) << 1) | v;
  const int qw = qt * 128 + w * 32;

  const __bf16* qp = qb + (size_t)bh * S * D;
  const __bf16* kp = kb + (size_t)bh * S * D;
  const __bf16* vp = vtb + (size_t)bh * D * S;
  char* pw = smem + 65536 + w * 4096;

  int ksrc[4], kdst[4], vsrc[4], vdst[4];
#pragma unroll
  for (int j = 0; j < 4; ++j) {
    int c = (w * 4 + j) * 64 + lane;
    int kr = c >> 4, kps = (c & 15) ^ (kr & 7);
    ksrc[j] = kr * D + kps * 8;
    kdst[j] = (w * 4 + j) * 1024;
    int vr = c >> 3, vps = (c & 7) ^ (vr & 7);
    vsrc[j] = vr * S + vps * 8;
    vdst[j] = 16384 + (w * 4 + j) * 1024;
  }
  auto stage = [&](int kt) {
    char* buf = smem + (kt & 1) * 32768;
    const int kv = kt * 64;
#pragma unroll
    for (int j = 0; j < 4; ++j) gll16(kp + (size_t)kv * D + ksrc[j], buf + kdst[j]);
#pragma unroll
    for (int j = 0; j < 4; ++j) gll16(vp + kv + vsrc[j], buf + vdst[j]);
  };

  // Q frags (B-operand now): col=q=qw+nj*16+ln, k-elems d=kf*32+lm*8..
  bf16x8 qf[2][4];
#pragma unroll
  for (int nj = 0; nj < 2; ++nj)
#pragma unroll
    for (int kf = 0; kf < 4; ++kf)
      qf[nj][kf] = *reinterpret_cast<const bf16x8*>(qp + (qw + nj * 16 + ln) * D + kf * 32 + lm * 8);

  f32x4 Oa[8][2] = {};            // O^T: [d-frag][q-frag]
  float mrow[2], lrow[2];         // per q-frag (q = nj*16+ln)
#pragma unroll
  for (int nj = 0; nj < 2; ++nj) { mrow[nj] = -3.0e38f; lrow[nj] = 0.0f; }

  const int ktEnd = 2 * qt + 1;

  stage(0);
  stage(1);
  asm volatile("s_waitcnt vmcnt(8)" ::: "memory");
  QBAR(); QSCB();

  for (int kt = 0; kt <= ktEnd; ++kt) {
    const int kv0 = kt * 64;
    const int cur = kt & 1;
    const char* Kb = smem + cur * 32768;
    const char* Vb = Kb + 16384;

    if (kv0 <= qw + 31) {
      const bool diag = (kv0 + 63 > qw);

      // S^T = K Q^T : M=64(kv) N=32(q) K=128(d); sacc[mi=kv-frag][nj=q-frag]
      f32x4 sacc[4][2] = {};
#pragma unroll
      for (int kf = 0; kf < 4; ++kf) {
        bf16x8 kfr[4];  // A-operand: row=kv=mi*16+ln, k=d=kf*32+lm*8..
#pragma unroll
        for (int mi = 0; mi < 4; ++mi) {
          int row = mi * 16 + ln;
          int ch = (kf * 4 + lm) ^ (row & 7);
          kfr[mi] = *reinterpret_cast<const bf16x8*>(Kb + row * 256 + ch * 16);
        }
        __builtin_amdgcn_s_setprio(1);
#pragma unroll
        for (int mi = 0; mi < 4; ++mi)
#pragma unroll
          for (int nj = 0; nj < 2; ++nj)
            sacc[mi][nj] = mfma16(kfr[mi], qf[nj][kf], sacc[mi][nj]);
        __builtin_amdgcn_s_setprio(0);
      }

      if (diag) {
#pragma unroll
        for (int nj = 0; nj < 2; ++nj) {
          int q = qw + nj * 16 + ln;
#pragma unroll
          for (int mi = 0; mi < 4; ++mi) {
            int kvb = kv0 + mi * 16 + lm * 4;
#pragma unroll
            for (int r = 0; r < 4; ++r)
              if (kvb + r > q) sacc[mi][nj][r] = -1e30f;
          }
        }
      }

      // softmax: lane owns 16 kv of its q-row; fast-path lane-partial trigger
      float lmax[2];
      bool big = false;
#pragma unroll
      for (int nj = 0; nj < 2; ++nj) {
        float m4 = -3.0e38f;
#pragma unroll
        for (int mi = 0; mi < 4; ++mi)
#pragma unroll
          for (int r = 0; r < 4; ++r) m4 = fmaxf(m4, sacc[mi][nj][r]);
        lmax[nj] = m4;
        big = big || (m4 > mrow[nj] + 8.0f);
      }
      if (__any((int)big)) {  // rare: 2-shuffle row reduce + rescale
#pragma unroll
        for (int nj = 0; nj < 2; ++nj) {
          float mx = lmax[nj];
          mx = fmaxf(mx, __shfl_xor(mx, 16, 64));
          mx = fmaxf(mx, __shfl_xor(mx, 32, 64));
          float mnew = fmaxf(mrow[nj], mx);
          float corr = __expf(mrow[nj] - mnew);
          mrow[nj] = mnew;
          lrow[nj] *= corr;
#pragma unroll
          for (int ni = 0; ni < 8; ++ni)
#pragma unroll
            for (int r = 0; r < 4; ++r) Oa[ni][nj][r] *= corr;
        }
      }
#pragma unroll
      for (int nj = 0; nj < 2; ++nj) {
        float rs = 0.0f;
#pragma unroll
        for (int mi = 0; mi < 4; ++mi)
#pragma unroll
          for (int r = 0; r < 4; ++r) {
            float p = __expf(sacc[mi][nj][r] - mrow[nj]);  // bounded by e^8
            sacc[mi][nj][r] = p;
            rs += p;
          }
        lrow[nj] += rs;  // lane-partial over 16 kv; reduced at the end
      }

      // P^T -> per-wave LDS: 8 b64 writes (row q=nj*16+ln, kv-quad at mi*32+lm*8)
#pragma unroll
      for (int nj = 0; nj < 2; ++nj) {
        int row = nj * 16 + ln;
        int rb = row * 128;
        int swz = (row & 7) << 4;
#pragma unroll
        for (int mi = 0; mi < 4; ++mi) {
          bf16x4 pq = {(__bf16)sacc[mi][nj][0], (__bf16)sacc[mi][nj][1],
                       (__bf16)sacc[mi][nj][2], (__bf16)sacc[mi][nj][3]};
          *reinterpret_cast<bf16x4*>(pw + rb + ((mi * 32 + lm * 8) ^ swz)) = pq;
        }
      }

      QLGKM(); QSCB();

      // O^T += V^T P^T : M=128(d) N=32(q) K=64(kv)
#pragma unroll
      for (int kf = 0; kf < 2; ++kf) {
        bf16x8 pfr[2], vfr[8];
#pragma unroll
        for (int nj = 0; nj < 2; ++nj) {  // B: col=q=nj*16+ln, k=kv=kf*32+lm*8..
          int row = nj * 16 + ln;
          pfr[nj] = *reinterpret_cast<const bf16x8*>(
              pw + row * 128 + ((kf * 64 + lm * 16) ^ ((row & 7) << 4)));
        }
#pragma unroll
        for (int ni = 0; ni < 8; ++ni) {  // A: row=d=ni*16+ln, k=kv
          int row = ni * 16 + ln;
          int ch = (kf * 4 + lm) ^ (row & 7);
          vfr[ni] = *reinterpret_cast<const bf16x8*>(Vb + row * 128 + ch * 16);
        }
        __builtin_amdgcn_s_setprio(1);
#pragma unroll
        for (int ni = 0; ni < 8; ++ni)
#pragma unroll
          for (int nj = 0; nj < 2; ++nj)
            Oa[ni][nj] = mfma16(vfr[ni], pfr[nj], Oa[ni][nj]);
        __builtin_amdgcn_s_setprio(0);
      }
    }

    // ---- tile boundary: counted waits, never drain mid-loop ----
    asm volatile("s_waitcnt lgkmcnt(0)" ::: "memory");
    QBAR(); QSCB();
    if (kt + 2 <= ktEnd) stage(kt + 2);
    if (kt + 1 <= ktEnd) {
      if (kt + 2 <= ktEnd)
        asm volatile("s_waitcnt vmcnt(8)" ::: "memory");
      else
        asm volatile("s_waitcnt vmcnt(0)" ::: "memory");
      QBAR(); QSCB();
    }
  }

  // finish: 2-shuffle row-sum reduce, normalize, packed 8B stores of d-quads
#pragma unroll
  for (int nj = 0; nj < 2; ++nj) {
    float ls = lrow[nj];
    ls += __shfl_xor(ls, 16, 64);
    ls += __shfl_xor(ls, 32, 64);
    lrow[nj] = 1.0f / ls;
  }
  const int b = bh >> 4, h = bh & 15;
#pragma unroll
  for (int nj = 0; nj < 2; ++nj) {
    const int qrow = qw + nj * 16 + ln;
    __bf16* zrow = zb + (size_t)(b * S + qrow) * F + h * D + lm * 4;
#pragma unroll
    for (int ni = 0; ni < 8; ++ni) {
      bf16x4 oq = {(__bf16)(Oa[ni][nj][0] * lrow[nj]), (__bf16)(Oa[ni][nj][1] * lrow[nj]),
                   (__bf16)(Oa[ni][nj][2] * lrow[nj]), (__bf16)(Oa[ni][nj][3] * lrow[nj])};
      *reinterpret_cast<bf16x4*>(zrow + ni * 16) = oq;
    }
  }
}

// ---------------- launch ----------------
extern "C" void kernel_launch(void* const* d_in, const int* in_sizes, int n_in,
                              void* d_out, int out_size, void* d_ws, size_t ws_size,
                              hipStream_t stream) {
  const float* x = (const float*)d_in[0];
  // d_in[1] = causal mask (implemented analytically)
  const float* w_attn = (const float*)d_in[2];
  const float* b_attn = (const float*)d_in[3];
  const float* w_proj = (const float*)d_in[4];
  const float* b_proj = (const float*)d_in[5];
  float* out = (float*)d_out;

  char* ws = (char*)d_ws;
  __bf16* xb    = (__bf16*)(ws + 0);          // 16 MB  [4096][2048] (reused as zb)
  __bf16* wqkv  = (__bf16*)(ws + 16777216);   // 24 MB  [6144][2048] (W^T)
  __bf16* wpro  = (__bf16*)(ws + 41943040);   //  8 MB  [2048][2048] (W^T)
  __bf16* qb    = (__bf16*)(ws + 50331648);   // 16 MB  [bh][s][d]
  __bf16* kb    = (__bf16*)(ws + 67108864);   // 16 MB  [bh][s][d]
  __bf16* vtb   = (__bf16*)(ws + 83886080);   // 16 MB  [bh][d][s]
  __bf16* zb    = xb;  // x fully consumed by QKV GEMM before attention writes z

  (void)hipFuncSetAttribute((const void*)k_qkv8p,
                            hipFuncAttributeMaxDynamicSharedMemorySize, 131072);
  (void)hipFuncSetAttribute((const void*)k_proj8p,
                            hipFuncAttributeMaxDynamicSharedMemorySize, 98304);
  (void)hipFuncSetAttribute((const void*)k_attn,
                            hipFuncAttributeMaxDynamicSharedMemorySize, 81920);

  // fused prep: 8192 cvt + 3072 w_attn-transpose + 1024 w_proj-transpose
  k_prep<<<12288, 256, 0, stream>>>(x, xb, w_attn, wqkv, w_proj, wpro);
  // QKV: M=4096 (32 x 128), N=6144 (16 x 384) -> 512 blocks = 2 exact rounds
  k_qkv8p<<<512, 512, 131072, stream>>>(xb, wqkv, b_attn, qb, kb, vtb);
  // attention: 512 blocks (complementary-qt balance + XCD affinity inside)
  k_attn<<<512, 256, 81920, stream>>>(qb, kb, vtb, zb);
  // out-proj: M=4096 (32 x 128), N=2048 (8 x 256) -> 256 blocks = 1/CU exact
  k_proj8p<<<256, 512, 98304, stream>>>(zb, wpro, b_proj, out);
}